// Round 13
// baseline (396.125 us; speedup 1.0000x reference)
//
#include <hip/hip_runtime.h>
#include <hip/hip_bf16.h>

#define CDIM 256
#define EPS 1e-5f
#define SLOPE 0.01f

using f32x4  = __attribute__((ext_vector_type(4))) float;
typedef __bf16 bf16x8 __attribute__((ext_vector_type(8)));
typedef unsigned short u16x8 __attribute__((ext_vector_type(8)));

// ---------------- workspace layout ----------------
enum : size_t {
  OFF_WS_HF   = 0,
  OFF_WS_LF   = 9216,
  OFF_WP_HF   = 20480,
  OFF_BS_HF   = 21504,
  OFF_WP_LF   = 22528,
  OFF_BS_LF   = 23552,
  OFF_MEAN_HF = 24576,
  OFF_RSTD_HF = 25600,
  OFF_MEAN_LF = 26624,
  OFF_RSTD_LF = 27648,
  OFF_U16     = 32768,          // start of ushort region (float units)
};
// ushort offsets relative to u16 base
enum : size_t {
  U_YH  = 0,          // [4][128][128][256] bf16
  U_YL  = 16777216,   // [4][64][64][256]
  U_HFA = 20971520,   // [4][128][128][256]
  U_LFA = 37748736,   // [4][64][64][256]
  U_HFP = 41943040,   // [4][64][64][256]
  U_PK  = 46137344,   // 6 packed weight slots, each 589824 (slot2 unused)
  PK_SZ = 589824,
  U_PKPH = U_PK + 6 * PK_SZ,    // phase-packed l2h: 4ph x 4tap x 8icc x 16mf x 64 x 8
  PH_SZ  = 1048576,
  U_PHB  = U_PKPH + PH_SZ,      // phase buffer [4][256][4][64][64] bf16
  U_END  = U_PHB + 16777216,
};
enum : size_t { TOTAL_F = OFF_U16 + (U_END + 1) / 2 };

__device__ float g_scratch[TOTAL_F];

__device__ __forceinline__ int refl(int q, int n) {
  return q < 0 ? -q : (q >= n ? 2 * n - 2 - q : q);
}
__device__ __forceinline__ float lrelu(float v) { return v >= 0.f ? v : SLOPE * v; }
__device__ __forceinline__ unsigned short f2bf(float f) {
  unsigned int u = __float_as_uint(f);
  u += 0x7fffu + ((u >> 16) & 1u);
  return (unsigned short)(u >> 16);
}
__device__ __forceinline__ float bf2f(unsigned short h) {
  return __uint_as_float(((unsigned int)h) << 16);
}
__device__ __forceinline__ void gload_lds16(const void* g, void* l) {
  __builtin_amdgcn_global_load_lds(
      (const __attribute__((address_space(1))) unsigned int*)g,
      (__attribute__((address_space(3))) unsigned int*)l, 16, 0, 0);
}

// ---------------- kernel_predict: spatial weights (hf & lf in one launch) ----------------
__global__ __launch_bounds__(256) void k_ws(const float* __restrict__ s_hf,
                                            const float* __restrict__ sw_hf,
                                            const float* __restrict__ sb_hf,
                                            float* __restrict__ ws_hf,
                                            const float* __restrict__ s_lf,
                                            const float* __restrict__ sw_lf,
                                            const float* __restrict__ sb_lf,
                                            float* __restrict__ ws_lf) {
  const bool lf = blockIdx.y != 0;
  const float* s  = lf ? s_lf : s_hf;
  const float* sw = lf ? sw_lf : sw_hf;
  const float* sb = lf ? sb_lf : sb_hf;
  float* ws_out   = lf ? ws_lf : ws_hf;
  int bo = blockIdx.x;
  int o = bo & (CDIM - 1);
  int c = threadIdx.x;
  int b = bo >> 8;
  float sv[9], wv[9];
  const float* sp = s + (size_t)(b * CDIM + c) * 9;
  const float* wp = sw + (size_t)(o * CDIM + c) * 9;
#pragma unroll
  for (int i = 0; i < 9; i++) { sv[i] = sp[i]; wv[i] = wp[i]; }
  float out9[9];
#pragma unroll
  for (int i = 0; i < 3; i++)
#pragma unroll
    for (int j = 0; j < 3; j++) {
      float a = 0.f;
#pragma unroll
      for (int dy = 0; dy < 3; dy++) {
        int u = i + dy - 1; u = (u < 0) ? 1 : (u > 2 ? 1 : u);
#pragma unroll
        for (int dx = 0; dx < 3; dx++) {
          int v = j + dx - 1; v = (v < 0) ? 1 : (v > 2 ? 1 : v);
          a += sv[u * 3 + v] * wv[dy * 3 + dx];
        }
      }
      out9[i * 3 + j] = a;
    }
  __shared__ float red[256 * 9];
#pragma unroll
  for (int i = 0; i < 9; i++) red[c * 9 + i] = out9[i];
  __syncthreads();
  for (int st = 128; st > 0; st >>= 1) {
    if (c < st)
#pragma unroll
      for (int i = 0; i < 9; i++) red[c * 9 + i] += red[(c + st) * 9 + i];
    __syncthreads();
  }
  if (c < 9) ws_out[(size_t)bo * 9 + c] = red[c] + sb[o];
}

// ---------------- pooled + w_point / bias (hf & lf in one launch, float4) ----------------
__global__ __launch_bounds__(256) void k_point(const float* __restrict__ s_hf,
                                               const float* __restrict__ pw_hf,
                                               const float* __restrict__ pb_hf,
                                               const float* __restrict__ bw_hf,
                                               const float* __restrict__ bb_hf,
                                               float* __restrict__ wp_hf,
                                               float* __restrict__ bs_hf,
                                               const float* __restrict__ s_lf,
                                               const float* __restrict__ pw_lf,
                                               const float* __restrict__ pb_lf,
                                               const float* __restrict__ bw_lf,
                                               const float* __restrict__ bb_lf,
                                               float* __restrict__ wp_lf,
                                               float* __restrict__ bs_lf) {
  const bool lf = blockIdx.y != 0;
  const float* s  = lf ? s_lf : s_hf;
  const float* pw = lf ? pw_lf : pw_hf;
  const float* pb = lf ? pb_lf : pb_hf;
  const float* bw = lf ? bw_lf : bw_hf;
  const float* bb = lf ? bb_lf : bb_hf;
  float* wp_out = lf ? wp_lf : wp_hf;
  float* bs_out = lf ? bs_lf : bs_hf;
  int b = blockIdx.x, o = threadIdx.x;
  __shared__ float pl[CDIM];
  const float* sp = s + (size_t)(b * CDIM + o) * 9;
  float a9 = 0.f;
#pragma unroll
  for (int j = 0; j < 9; j++) a9 += sp[j];
  pl[o] = a9 * (1.f / 9.f);
  __syncthreads();
  float a = pb[o], d = bb[o];
  const float4* pw4 = (const float4*)(pw + (size_t)o * CDIM);
  const float4* bw4 = (const float4*)(bw + (size_t)o * CDIM);
  const float4* pl4 = (const float4*)pl;
  for (int c4 = 0; c4 < CDIM / 4; c4++) {
    float4 p = pl4[c4];
    float4 w1 = pw4[c4], w2 = bw4[c4];
    a += p.x * w1.x + p.y * w1.y + p.z * w1.z + p.w * w1.w;
    d += p.x * w2.x + p.y * w2.y + p.z * w2.z + p.w * w2.w;
  }
  wp_out[b * CDIM + o] = a;
  bs_out[b * CDIM + o] = d;
}

// ---------------- instance norm stats (hf & lf in one launch) ----------------
__global__ __launch_bounds__(256) void k_istats(const float* __restrict__ xh,
                                                float* __restrict__ mh, float* __restrict__ rh,
                                                const float* __restrict__ xl,
                                                float* __restrict__ ml, float* __restrict__ rl) {
  const bool lf = blockIdx.x >= 1024;
  int plane = lf ? blockIdx.x - 1024 : blockIdx.x;
  const float* x = lf ? xl : xh;
  float* mean = lf ? ml : mh;
  float* rstd = lf ? rl : rh;
  const int HW = lf ? 4096 : 16384;
  const float4* p = (const float4*)(x + (size_t)plane * HW);
  int n4 = HW >> 2;
  float s = 0.f, q = 0.f;
  for (int i = threadIdx.x; i < n4; i += 256) {
    float4 v = p[i];
    s += v.x + v.y + v.z + v.w;
    q += v.x * v.x + v.y * v.y + v.z * v.z + v.w * v.w;
  }
  __shared__ float rs[256], rq[256];
  rs[threadIdx.x] = s; rq[threadIdx.x] = q;
  __syncthreads();
  for (int st = 128; st > 0; st >>= 1) {
    if (threadIdx.x < st) {
      rs[threadIdx.x] += rs[threadIdx.x + st];
      rq[threadIdx.x] += rq[threadIdx.x + st];
    }
    __syncthreads();
  }
  if (threadIdx.x == 0) {
    float m = rs[0] / HW;
    float v = rq[0] / HW - m * m;
    mean[plane] = m;
    rstd[plane] = rsqrtf(v + EPS);
  }
}

// ---------------- all weight packing in one launch ----------------
__global__ void k_packall(const float* __restrict__ w_adah, const float* __restrict__ w_h2h,
                          const float* __restrict__ w_adal, const float* __restrict__ w_l2l,
                          const float* __restrict__ w_h2l, const float* __restrict__ w_l2h,
                          unsigned short* __restrict__ pk, unsigned short* __restrict__ pkph) {
  int seg = blockIdx.y;
  int i = blockIdx.x * 256 + threadIdx.x;
  if (seg < 5) {
    if (i >= 589824) return;
    const float* srcs[5] = {w_adah, w_h2h, w_adal, w_l2l, w_h2l};
    const int slot[5] = {0, 1, 3, 4, 5};
    const float* w = srcs[seg];
    int j = i & 7, l = (i >> 3) & 63, mf = (i >> 9) & 15, icc = (i >> 13) & 7, tap = i >> 16;
    int oc = mf * 16 + (l & 15);
    int ic = icc * 32 + (l >> 4) * 8 + j;
    pk[(size_t)slot[seg] * PK_SZ + i] = f2bf(w[((size_t)oc * 256 + ic) * 9 + tap]);
  } else {
    // phase pack: i < 1048576
    int j = i & 7, l = (i >> 3) & 63, mf = (i >> 9) & 15, icc = (i >> 13) & 7, tapph = i >> 16;
    int tap = tapph & 3, phase = tapph >> 2;
    int tx = tap & 1, ty = tap >> 1;
    int a = phase >> 1, bp = phase & 1;
    int oc = mf * 16 + (l & 15);
    int ic = icc * 32 + (l >> 4) * 8 + j;
    int ys = (a == 0) ? (ty == 0 ? 0 : 1) : (ty == 0 ? 0 : 2);
    int yc = (a == 0) ? (ty == 0 ? 1 : 2) : (ty == 0 ? 2 : 1);
    int xs = (bp == 0) ? (tx == 0 ? 0 : 1) : (tx == 0 ? 0 : 2);
    int xc = (bp == 0) ? (tx == 0 ? 1 : 2) : (tx == 0 ? 2 : 1);
    const float* wb = w_l2h + ((size_t)oc * 256 + ic) * 9;
    float acc = 0.f;
    for (int dy = ys; dy < ys + yc; dy++)
      for (int dx = xs; dx < xs + xc; dx++) acc += wb[dy * 3 + dx];
    pkph[i] = f2bf(acc);
  }
}

// ---------------- fused IN + dynamic depthwise + pointwise -> NHWC bf16 ----------------
template <int LW>
__global__ __launch_bounds__(256) void k_dwt(const float* __restrict__ x,
                                             const float* __restrict__ ws,
                                             const float* __restrict__ mean,
                                             const float* __restrict__ rstd,
                                             const float* __restrict__ wp,
                                             const float* __restrict__ bs,
                                             unsigned short* __restrict__ out) {
  constexpr int W = 1 << LW, H = W, HW = W * W;
  int t = threadIdx.x;
  int xt = (LW > 6) ? (blockIdx.x & ((W >> 6) - 1)) : 0;
  int icb = (LW > 6) ? (blockIdx.x >> (LW - 6)) : blockIdx.x;
  int y = blockIdx.y, b = blockIdx.z;
  __shared__ unsigned short tr[64][66];
  const int xg = t & 15;                 // 16 groups of 4 px -> 64 px
  const int chq = t >> 4;                // 0..15
  const int x0 = xt * 64 + xg * 4;
  const int sy0 = refl(y - 1, H), sy2 = refl(y + 1, H);
  const int xm = refl(x0 - 1, W);        // left edge neighbor
  const int xq = refl(x0 + 4, W);        // right edge neighbor
#pragma unroll
  for (int rr = 0; rr < 4; ++rr) {
    int icl = rr * 16 + chq;
    int plane = b * CDIM + icb * 64 + icl;
    const float* xpb = x + (size_t)plane * HW;
    float m = mean[plane], r = rstd[plane], sc = wp[plane], bi = bs[plane];
    const float* w9p = ws + (size_t)plane * 9;
    float w9[9];
#pragma unroll
    for (int i = 0; i < 9; i++) w9[i] = w9p[i];
    float sumw = w9[0] + w9[1] + w9[2] + w9[3] + w9[4] + w9[5] + w9[6] + w9[7] + w9[8];
    const float* r0 = xpb + sy0 * W;
    const float* r1 = xpb + y * W;
    const float* r2 = xpb + sy2 * W;
    float4 v0 = *(const float4*)(r0 + x0);
    float4 v1 = *(const float4*)(r1 + x0);
    float4 v2 = *(const float4*)(r2 + x0);
    float e0[6] = {r0[xm], v0.x, v0.y, v0.z, v0.w, r0[xq]};
    float e1[6] = {r1[xm], v1.x, v1.y, v1.z, v1.w, r1[xq]};
    float e2[6] = {r2[xm], v2.x, v2.y, v2.z, v2.w, r2[xq]};
    float mterm = m * sumw;
#pragma unroll
    for (int j = 0; j < 4; ++j) {
      float a = w9[0] * e0[j] + w9[1] * e0[j + 1] + w9[2] * e0[j + 2] +
                w9[3] * e1[j] + w9[4] * e1[j + 1] + w9[5] * e1[j + 2] +
                w9[6] * e2[j] + w9[7] * e2[j + 1] + w9[8] * e2[j + 2];
      a -= mterm;
      tr[icl][xg * 4 + j] = f2bf(a * r * sc + bi);
    }
  }
  __syncthreads();
  // vectorized NHWC store: 64 px x 64 ch, u16x8 per store
#pragma unroll
  for (int it2 = 0; it2 < 2; ++it2) {
    int s2 = it2 * 256 + t;          // 0..511
    int xl2 = s2 >> 3;               // 0..63
    int cg = s2 & 7;                 // 0..7
    u16x8 v;
#pragma unroll
    for (int j = 0; j < 8; j++) v[j] = tr[cg * 8 + j][xl2];
    *(u16x8*)&out[((size_t)((b * H + y) * W + xt * 64 + xl2)) * CDIM + icb * 64 + cg * 8] = v;
  }
}

// ---------------- 2x2 avg pool on NHWC bf16 (vectorized: 8 ch / thread) ----------------
__global__ __launch_bounds__(256) void k_pool_nhwc(const unsigned short* __restrict__ in,
                                                   unsigned short* __restrict__ out) {
  int i = blockIdx.x * 256 + threadIdx.x;   // < 4*64*64*32
  int cg = i & 31;
  int p = i >> 5;                            // (b*64+Y)*64+X
  int X = p & 63, Y = (p >> 6) & 63, b = p >> 12;
  const unsigned short* s =
      in + ((size_t)(b * 128 + 2 * Y) * 128 + 2 * X) * CDIM + cg * 8;
  u16x8 v0 = *(const u16x8*)(s);
  u16x8 v1 = *(const u16x8*)(s + CDIM);
  u16x8 v2 = *(const u16x8*)(s + 128 * CDIM);
  u16x8 v3 = *(const u16x8*)(s + 128 * CDIM + CDIM);
  u16x8 r;
#pragma unroll
  for (int j = 0; j < 8; j++)
    r[j] = f2bf(0.25f * (bf2f(v0[j]) + bf2f(v1[j]) + bf2f(v2[j]) + bf2f(v3[j])));
  *(u16x8*)(out + (size_t)p * CDIM + cg * 8) = r;
}

// ---------------- MFMA implicit-GEMM 3x3 reflect conv (R5 structure + ACC) ----------------
// 256 threads, 64 oc x 256 px; used for lf convs (keeps 256-CU fill at small grids).
template <int LW, bool DUAL, bool UPSB, bool NCHWOUT, bool ACC>
__global__ __launch_bounds__(256, 2) void k_conv_mfma(
    const unsigned short* __restrict__ srcA, const unsigned short* __restrict__ srcB,
    const unsigned short* __restrict__ wpkA, const unsigned short* __restrict__ wpkB,
    const float* __restrict__ bias, const unsigned short* __restrict__ accsrc,
    void* __restrict__ outp) {
  constexpr int W = 1 << LW, H = W, HW = W * W;
  constexpr int ROWS = 256 >> LW;       // pixel rows per block
  constexpr int R = ROWS + 2, Cw = W + 2;
  constexpr int RC = R * Cw;
  constexpr int RCPAD = (RC + 63) & ~63;
  constexpr int NIT = RCPAD / 64;
  __shared__ __align__(16) unsigned short tin[RCPAD * 32];        // input tile, 32 ic
  __shared__ __align__(16) unsigned short wlds[9 * 4 * 64 * 8];   // 9 taps x 4 mi frags

  const int t = threadIdx.x;
  const int l = t & 63, wv = t >> 6;
  const int l15 = l & 15, l4 = l >> 4;

  // XCD-chunked bijective swizzle (nwg divisible by 8)
  const int hwid = blockIdx.x;
  const int nwg = gridDim.x;
  const int wk = (hwid & 7) * (nwg >> 3) + (hwid >> 3);
  const int mb = wk & 3;
  const int pixbase = (wk >> 2) * 256;
  const int b = pixbase >> (2 * LW);
  const int y0 = (pixbase >> LW) & (H - 1);

  f32x4 acc[4][4];
#pragma unroll
  for (int mi = 0; mi < 4; mi++)
#pragma unroll
    for (int nf = 0; nf < 4; nf++) acc[mi][nf] = (f32x4){0.f, 0.f, 0.f, 0.f};

  const int nsrc = DUAL ? 2 : 1;
  for (int src = 0; src < nsrc; ++src) {
    const unsigned short* ysrc = src ? srcB : srcA;
    const unsigned short* wpk = src ? wpkB : wpkA;
    const bool ups = UPSB && (src == 1);

    // hoist staging addresses out of the K loop
    const unsigned short* inptr[NIT];
#pragma unroll
    for (int it = 0; it < NIT; ++it) {
      int rc = it * 64 + (t >> 2);
      int rcc = rc < RC - 1 ? rc : RC - 1;
      int r = rcc / Cw, tc = rcc - r * Cw;
      int gy = refl(y0 - 1 + r, H);
      int gx = refl(tc - 1, W);
      int sy, sx, sw;
      if (ups) { sy = gy >> 1; sx = gx >> 1; sw = W >> 1; }
      else     { sy = gy;      sx = gx;      sw = W; }
      int gsrc = (t & 3) ^ (tc & 3);   // ic-slot XOR swizzle (source side)
      inptr[it] = ysrc + (((size_t)(b * sw + sy) * sw + sx) * CDIM + gsrc * 8);
    }
    const unsigned short* wsrc = wpk + ((size_t)(mb * 4 + wv) * 64 + l) * 8;

    for (int icc = 0; icc < 8; ++icc) {
      __syncthreads();
#pragma unroll
      for (int it = 0; it < NIT; ++it)
        gload_lds16(inptr[it] + icc * 32, &tin[(size_t)(it * 256 + t) * 8]);
#pragma unroll
      for (int tap = 0; tap < 9; ++tap)
        gload_lds16(wsrc + ((size_t)tap * 8 + (size_t)icc) * 8192,
                    &wlds[(size_t)(tap * 256 + t) * 8]);
      __syncthreads();

      __builtin_amdgcn_s_setprio(1);
#pragma unroll
      for (int tap = 0; tap < 9; ++tap) {
        const int dy = tap / 3, dx = tap - 3 * (tap / 3);
        bf16x8 af[4];
#pragma unroll
        for (int mi = 0; mi < 4; mi++)
          af[mi] = *(const bf16x8*)&wlds[(size_t)((tap * 4 + mi) * 64 + l) * 8];
#pragma unroll
        for (int nf = 0; nf < 4; nf++) {
          int pl = wv * 64 + nf * 16 + l15;
          int py = pl >> LW;
          int c = pl & (W - 1);
          int tcol = c + dx;
          int idx16 = ((py + dy) * Cw + tcol) * 4 + (l4 ^ (tcol & 3));
          bf16x8 bfv = *(const bf16x8*)&tin[(size_t)idx16 * 8];
#pragma unroll
          for (int mi = 0; mi < 4; mi++)
            acc[mi][nf] = __builtin_amdgcn_mfma_f32_16x16x32_bf16(af[mi], bfv, acc[mi][nf], 0, 0, 0);
        }
      }
      __builtin_amdgcn_s_setprio(0);
    }
  }

  // epilogue
#pragma unroll
  for (int mi = 0; mi < 4; mi++) {
    int oc0 = mb * 64 + mi * 16 + l4 * 4;
    float bv[4];
#pragma unroll
    for (int rr = 0; rr < 4; rr++) bv[rr] = bias ? bias[oc0 + rr] : 0.f;
#pragma unroll
    for (int nf = 0; nf < 4; nf++) {
      int p = pixbase + wv * 64 + nf * 16 + l15;
      if (NCHWOUT) {
        float* o = (float*)outp;
        int pin = p & (HW - 1);
        int bb2 = p >> (2 * LW);
        int yy = pin >> LW, xx = pin & (W - 1);
        int ph = ((yy & 1) << 1) | (xx & 1);
        int q = (yy >> 1) * (W / 2) + (xx >> 1);
#pragma unroll
        for (int rr = 0; rr < 4; rr++) {
          float v = acc[mi][nf][rr] + bv[rr];
          if (ACC)
            v += bf2f(accsrc[((size_t)(bb2 * CDIM + oc0 + rr) * 4 + ph) * (HW / 4) + q]);
          o[((size_t)(bb2 * CDIM + oc0 + rr)) * HW + pin] = lrelu(v);
        }
      } else {
        unsigned short* o = (unsigned short*)outp;
        ushort4 pk;
        pk.x = f2bf(lrelu(acc[mi][nf][0] + bv[0]));
        pk.y = f2bf(lrelu(acc[mi][nf][1] + bv[1]));
        pk.z = f2bf(lrelu(acc[mi][nf][2] + bv[2]));
        pk.w = f2bf(lrelu(acc[mi][nf][3] + bv[3]));
        *(ushort4*)&o[(size_t)p * CDIM + oc0] = pk;
      }
    }
  }
}

// ---------------- wide conv: 512 threads, 128 oc x 256 px, tin dbuf + counted vmcnt ----------
// tin double-buffered (prefetch next icc under compute); wlds single-buffered.
// s_waitcnt vmcnt(NIT) drains prev-tin + cur-wlds, keeps next-tin in flight
// across both barriers (no vmcnt(0) in main loop). LDS 152KB -> 1 block/CU
// = 8 waves = 2/SIMD (same occupancy as two 256-thread blocks).
template <int LW, bool NCHWOUT, bool ACC>
__global__ __launch_bounds__(512, 2) void k_conv_w(
    const unsigned short* __restrict__ src, const unsigned short* __restrict__ wpk,
    const float* __restrict__ bias, const unsigned short* __restrict__ accsrc,
    void* __restrict__ outp) {
  constexpr int W = 1 << LW, H = W, HW = W * W;
  constexpr int ROWS = 256 >> LW;            // pixel rows per block (2 at LW=7)
  constexpr int R = ROWS + 2, Cw = W + 2;
  constexpr int RC = R * Cw;                 // 520
  constexpr int NIT = (RC + 127) / 128;      // 5 staging rounds (128 slots each)
  constexpr int RCPAD = NIT * 128;           // 640
  __shared__ __align__(16) unsigned short tin[2][RCPAD * 32];     // dbuf input tile
  __shared__ __align__(16) unsigned short wlds[9 * 8 * 64 * 8];   // 9 taps x 8 mi frags

  const int t = threadIdx.x;
  const int l = t & 63, wv = t >> 6;
  const int og = wv >> 2, pq = wv & 3;       // oc-half, px-quarter
  const int l15 = l & 15, l4 = l >> 4;

  // XCD-chunked bijective swizzle; mb fastest so tile-pairs share an XCD
  const int hwid = blockIdx.x;
  const int nwg = gridDim.x;
  const int wk = (hwid & 7) * (nwg >> 3) + (hwid >> 3);
  const int mb = wk & 1;
  const int pixbase = (wk >> 1) * 256;
  const int b = pixbase >> (2 * LW);
  const int y0 = (pixbase >> LW) & (H - 1);

  f32x4 acc[4][4];
#pragma unroll
  for (int mi = 0; mi < 4; mi++)
#pragma unroll
    for (int nf = 0; nf < 4; nf++) acc[mi][nf] = (f32x4){0.f, 0.f, 0.f, 0.f};

  // staging addresses (4 threads per slot, 8 ic each)
  const unsigned short* inptr[NIT];
#pragma unroll
  for (int it = 0; it < NIT; ++it) {
    int rc = it * 128 + (t >> 2);
    int rcc = rc < RC - 1 ? rc : RC - 1;
    int r = rcc / Cw, tc = rcc - r * Cw;
    int gy = refl(y0 - 1 + r, H);
    int gx = refl(tc - 1, W);
    int gsrc = (t & 3) ^ (tc & 3);       // ic-slot XOR swizzle (source side)
    inptr[it] = src + (((size_t)(b * W + gy) * W + gx) * CDIM + gsrc * 8);
  }
  // weight source: frag (tap, icc, mi = mb*8 + wv) lane l
  const unsigned short* wsrc = wpk + ((size_t)(mb * 8 + wv) * 64 + l) * 8;

  // prologue: stage tin[0] for icc=0
#pragma unroll
  for (int it = 0; it < NIT; ++it)
    gload_lds16(inptr[it], &tin[0][(size_t)(it * 512 + t) * 8]);

#pragma unroll 1
  for (int icc = 0; icc < 8; ++icc) {
    const int buf = icc & 1;
    // stage wlds[icc] (9 loads/thread); per-(tap,icc) stride in pack = 8192 ushorts
#pragma unroll
    for (int tap = 0; tap < 9; ++tap)
      gload_lds16(wsrc + ((size_t)tap * 8 + (size_t)icc) * 8192,
                  &wlds[(size_t)(tap * 512 + t) * 8]);
    // prefetch tin for next icc into the other buffer (5 loads/thread)
    if (icc < 7) {
#pragma unroll
      for (int it = 0; it < NIT; ++it)
        gload_lds16(inptr[it] + (icc + 1) * 32, &tin[buf ^ 1][(size_t)(it * 512 + t) * 8]);
      asm volatile("s_waitcnt vmcnt(%0)" ::"n"(NIT) : "memory");  // keep next-tin in flight
    } else {
      asm volatile("s_waitcnt vmcnt(0)" ::: "memory");
    }
    __builtin_amdgcn_s_barrier();

    __builtin_amdgcn_s_setprio(1);
#pragma unroll
    for (int tap = 0; tap < 9; ++tap) {
      const int dy = tap / 3, dx = tap - 3 * (tap / 3);
      bf16x8 af[4];
#pragma unroll
      for (int mi = 0; mi < 4; mi++)
        af[mi] = *(const bf16x8*)&wlds[(size_t)((tap * 8 + og * 4 + mi) * 64 + l) * 8];
#pragma unroll
      for (int nf = 0; nf < 4; nf++) {
        int pl = pq * 64 + nf * 16 + l15;
        int py = pl >> LW;
        int c = pl & (W - 1);
        int tcol = c + dx;
        int idx16 = ((py + dy) * Cw + tcol) * 4 + (l4 ^ (tcol & 3));
        bf16x8 bfv = *(const bf16x8*)&tin[buf][(size_t)idx16 * 8];
#pragma unroll
        for (int mi = 0; mi < 4; mi++)
          acc[mi][nf] = __builtin_amdgcn_mfma_f32_16x16x32_bf16(af[mi], bfv, acc[mi][nf], 0, 0, 0);
      }
    }
    __builtin_amdgcn_s_setprio(0);
    __builtin_amdgcn_s_barrier();   // all waves done reading before overwrite
  }

  // epilogue
#pragma unroll
  for (int mi = 0; mi < 4; mi++) {
    int oc0 = mb * 128 + og * 64 + mi * 16 + l4 * 4;
    float bv[4];
#pragma unroll
    for (int rr = 0; rr < 4; rr++) bv[rr] = bias ? bias[oc0 + rr] : 0.f;
#pragma unroll
    for (int nf = 0; nf < 4; nf++) {
      int p = pixbase + pq * 64 + nf * 16 + l15;
      if (NCHWOUT) {
        float* o = (float*)outp;
        int pin = p & (HW - 1);
        int bb2 = p >> (2 * LW);
        int yy = pin >> LW, xx = pin & (W - 1);
        int ph = ((yy & 1) << 1) | (xx & 1);
        int q = (yy >> 1) * (W / 2) + (xx >> 1);
#pragma unroll
        for (int rr = 0; rr < 4; rr++) {
          float v = acc[mi][nf][rr] + bv[rr];
          if (ACC)
            v += bf2f(accsrc[((size_t)(bb2 * CDIM + oc0 + rr) * 4 + ph) * (HW / 4) + q]);
          o[((size_t)(bb2 * CDIM + oc0 + rr)) * HW + pin] = lrelu(v);
        }
      } else {
        unsigned short* o = (unsigned short*)outp;
        ushort4 pk;
        pk.x = f2bf(lrelu(acc[mi][nf][0] + bv[0]));
        pk.y = f2bf(lrelu(acc[mi][nf][1] + bv[1]));
        pk.z = f2bf(lrelu(acc[mi][nf][2] + bv[2]));
        pk.w = f2bf(lrelu(acc[mi][nf][3] + bv[3]));
        *(ushort4*)&o[(size_t)p * CDIM + oc0] = pk;
      }
    }
  }
}

// ---------------- phase-collapsed upsample-conv: 4-tap GEMM on lf grid ----------------
__global__ __launch_bounds__(256, 3) void k_conv_up(
    const unsigned short* __restrict__ lf, const unsigned short* __restrict__ wph,
    unsigned short* __restrict__ phb) {
  constexpr int NIT = 5;                      // 5 rows x 64 cols staged
  __shared__ __align__(16) unsigned short tin[320 * 64 / 2];      // 320 slots x 32ic x 2B
  __shared__ __align__(16) unsigned short wlds[4 * 256 * 8];      // 4 taps

  const int t = threadIdx.x;
  const int l = t & 63, wv = t >> 6;
  const int l15 = l & 15, l4 = l >> 4;

  const int hwid = blockIdx.x;
  const int wk = (hwid & 7) * 128 + (hwid >> 3);   // nwg = 1024
  const int mb = wk & 3;
  const int phase = (wk >> 2) & 3;
  const int tile = (wk >> 4) & 15;
  const int b = wk >> 8;
  const int a = phase >> 1, bp = phase & 1;
  const int Y0 = tile * 4;

  f32x4 acc[4][4];
#pragma unroll
  for (int mi = 0; mi < 4; mi++)
#pragma unroll
    for (int nf = 0; nf < 4; nf++) acc[mi][nf] = (f32x4){0.f, 0.f, 0.f, 0.f};

  const unsigned short* inptr[NIT];
#pragma unroll
  for (int it = 0; it < NIT; ++it) {
    int s = it * 64 + (t >> 2);
    int row = s >> 6, col = s & 63;
    int ly = Y0 - 1 + a + row;
    ly = ly < 0 ? 0 : (ly > 63 ? 63 : ly);
    int gsrc = (t & 3) ^ (col & 3);
    inptr[it] = lf + (((size_t)(b * 64 + ly) * 64 + col) * CDIM + gsrc * 8);
  }
  const unsigned short* wsrc = wph + ((size_t)(mb * 4 + wv) * 64 + l) * 8;

  for (int icc = 0; icc < 8; ++icc) {
    __syncthreads();
#pragma unroll
    for (int it = 0; it < NIT; ++it)
      gload_lds16(inptr[it] + icc * 32, &tin[(size_t)(it * 256 + t) * 8]);
#pragma unroll
    for (int tap = 0; tap < 4; ++tap)
      gload_lds16(wsrc + ((size_t)(phase * 4 + tap) * 8 + (size_t)icc) * 8192,
                  &wlds[(size_t)(tap * 256 + t) * 8]);
    __syncthreads();

    __builtin_amdgcn_s_setprio(1);
#pragma unroll
    for (int tap = 0; tap < 4; ++tap) {
      const int ty = tap >> 1, tx = tap & 1;
      bf16x8 af[4];
#pragma unroll
      for (int mi = 0; mi < 4; mi++)
        af[mi] = *(const bf16x8*)&wlds[(size_t)((tap * 4 + mi) * 64 + l) * 8];
#pragma unroll
      for (int nf = 0; nf < 4; nf++) {
        int pl = wv * 64 + nf * 16 + l15;
        int py = pl >> 6;
        int col = pl & 63;
        int tcol = col - 1 + bp + tx;
        tcol = tcol < 0 ? 0 : (tcol > 63 ? 63 : tcol);
        int idx16 = ((py + ty) * 64 + tcol) * 4 + (l4 ^ (tcol & 3));
        bf16x8 bfv = *(const bf16x8*)&tin[(size_t)idx16 * 8];
#pragma unroll
        for (int mi = 0; mi < 4; mi++)
          acc[mi][nf] = __builtin_amdgcn_mfma_f32_16x16x32_bf16(af[mi], bfv, acc[mi][nf], 0, 0, 0);
      }
    }
    __builtin_amdgcn_s_setprio(0);
  }

  // coalesced write into bf16 phase buffer
#pragma unroll
  for (int mi = 0; mi < 4; mi++) {
    int oc0 = mb * 64 + mi * 16 + l4 * 4;
#pragma unroll
    for (int nf = 0; nf < 4; nf++) {
      int pl = wv * 64 + nf * 16 + l15;
      int py = pl >> 6, col = pl & 63;
      size_t base = ((size_t)(b * CDIM + oc0) * 4 + phase) * 4096 + (Y0 + py) * 64 + col;
#pragma unroll
      for (int rr = 0; rr < 4; rr++)
        phb[base + (size_t)rr * 4 * 4096] = f2bf(acc[mi][nf][rr]);
    }
  }
}

// ---------------- host ----------------
extern "C" void kernel_launch(void* const* d_in, const int* in_sizes, int n_in,
                              void* d_out, int out_size, void* d_ws, size_t ws_size,
                              hipStream_t stream) {
  (void)in_sizes; (void)n_in; (void)out_size;
  const float* c_hf = (const float*)d_in[0];
  const float* c_lf = (const float*)d_in[1];
  const float* s_hf = (const float*)d_in[2];
  const float* s_lf = (const float*)d_in[3];
  const float* h_sw = (const float*)d_in[4];
  const float* h_sb = (const float*)d_in[5];
  const float* h_pw = (const float*)d_in[6];
  const float* h_pb = (const float*)d_in[7];
  const float* h_bw = (const float*)d_in[8];
  const float* h_bb = (const float*)d_in[9];
  const float* l_sw = (const float*)d_in[10];
  const float* l_sb = (const float*)d_in[11];
  const float* l_pw = (const float*)d_in[12];
  const float* l_pb = (const float*)d_in[13];
  const float* l_bw = (const float*)d_in[14];
  const float* l_bb = (const float*)d_in[15];
  const float* ada_h_w = (const float*)d_in[16];
  const float* ada_h_b = (const float*)d_in[17];
  const float* ada_l_w = (const float*)d_in[18];
  const float* ada_l_b = (const float*)d_in[19];
  const float* h2h = (const float*)d_in[20];
  const float* l2h = (const float*)d_in[21];
  const float* h2l = (const float*)d_in[22];
  const float* l2l = (const float*)d_in[23];

  const int B = 4, H = 128, W = 128;

  float* base;
  size_t need = (size_t)TOTAL_F * sizeof(float);
  if (ws_size >= need) {
    base = (float*)d_ws;
  } else {
    void* p = nullptr;
    hipGetSymbolAddress(&p, HIP_SYMBOL(g_scratch));
    base = (float*)p;
  }

  float* ws_hf = base + OFF_WS_HF;
  float* ws_lf = base + OFF_WS_LF;
  float* wp_hf = base + OFF_WP_HF;
  float* bs_hf = base + OFF_BS_HF;
  float* wp_lf = base + OFF_WP_LF;
  float* bs_lf = base + OFF_BS_LF;
  float* mean_hf = base + OFF_MEAN_HF;
  float* rstd_hf = base + OFF_RSTD_HF;
  float* mean_lf = base + OFF_MEAN_LF;
  float* rstd_lf = base + OFF_RSTD_LF;
  unsigned short* u16 = (unsigned short*)(base + OFF_U16);
  unsigned short* yh = u16 + U_YH;
  unsigned short* yl = u16 + U_YL;
  unsigned short* hfA = u16 + U_HFA;
  unsigned short* lfA = u16 + U_LFA;
  unsigned short* hfP = u16 + U_HFP;
  unsigned short* pk      = u16 + U_PK;
  unsigned short* pk_adah = pk + 0 * PK_SZ;
  unsigned short* pk_h2h  = pk + 1 * PK_SZ;
  unsigned short* pk_adal = pk + 3 * PK_SZ;
  unsigned short* pk_l2l  = pk + 4 * PK_SZ;
  unsigned short* pk_h2l  = pk + 5 * PK_SZ;
  unsigned short* pk_ph   = u16 + U_PKPH;
  unsigned short* phb     = u16 + U_PHB;

  float* out_hf = (float*)d_out;
  float* out_lf = (float*)d_out + 16777216;

  // weight packing (all in one launch)
  k_packall<<<dim3(4096, 6), dim3(256), 0, stream>>>(ada_h_w, h2h, ada_l_w, l2l, h2l, l2h,
                                                     pk, pk_ph);

  // kernel_predict (hf & lf fused per stage)
  k_ws<<<dim3(B * CDIM, 2), dim3(256), 0, stream>>>(s_hf, h_sw, h_sb, ws_hf,
                                                    s_lf, l_sw, l_sb, ws_lf);
  k_point<<<dim3(B, 2), dim3(256), 0, stream>>>(s_hf, h_pw, h_pb, h_bw, h_bb, wp_hf, bs_hf,
                                                s_lf, l_pw, l_pb, l_bw, l_bb, wp_lf, bs_lf);

  // instance norm stats (both freqs)
  k_istats<<<dim3(2048), dim3(256), 0, stream>>>(c_hf, mean_hf, rstd_hf,
                                                 c_lf, mean_lf, rstd_lf);

  // fused IN + depthwise + pointwise -> NHWC bf16 (vectorized)
  k_dwt<7><<<dim3(8, 128, 4), dim3(256), 0, stream>>>(c_hf, ws_hf, mean_hf, rstd_hf, wp_hf, bs_hf, yh);
  k_dwt<6><<<dim3(4, 64, 4), dim3(256), 0, stream>>>(c_lf, ws_lf, mean_lf, rstd_lf, wp_lf, bs_lf, yl);

  // ada convs (MFMA): hf uses wide pipelined kernel, lf keeps 256-thread kernel
  k_conv_w<7, false, false><<<dim3(512), dim3(512), 0, stream>>>(
      yh, pk_adah, ada_h_b, nullptr, hfA);
  k_conv_mfma<6, false, false, false, false><<<dim3(256), dim3(256), 0, stream>>>(
      yl, nullptr, pk_adal, nullptr, ada_l_b, nullptr, lfA);

  // phase-collapsed conv(up(lf), l2h) -> bf16 phase buffer
  k_conv_up<<<dim3(1024), dim3(256), 0, stream>>>(lfA, pk_ph, phb);

  // avgpool hf (vectorized)
  k_pool_nhwc<<<dim3(2048), dim3(256), 0, stream>>>(hfA, hfP);

  // hf_out = lrelu(conv(hf,h2h) + phase buffer)
  k_conv_w<7, true, true><<<dim3(512), dim3(512), 0, stream>>>(
      hfA, pk_h2h, nullptr, phb, out_hf);

  // lf_out = lrelu(conv(lf,l2l) + conv(avgpool2(hf),h2l))
  k_conv_mfma<6, true, false, true, false><<<dim3(256), dim3(256), 0, stream>>>(
      lfA, hfP, pk_l2l, pk_h2l, nullptr, nullptr, out_lf);
}

// Round 14
// 373.326 us; speedup vs baseline: 1.0611x; 1.0611x over previous
//
#include <hip/hip_runtime.h>
#include <hip/hip_bf16.h>

#define CDIM 256
#define EPS 1e-5f
#define SLOPE 0.01f

using f32x4  = __attribute__((ext_vector_type(4))) float;
typedef __bf16 bf16x8 __attribute__((ext_vector_type(8)));
typedef unsigned short u16x8 __attribute__((ext_vector_type(8)));

// ---------------- workspace layout ----------------
enum : size_t {
  OFF_WS_HF   = 0,
  OFF_WS_LF   = 9216,
  OFF_WP_HF   = 20480,
  OFF_BS_HF   = 21504,
  OFF_WP_LF   = 22528,
  OFF_BS_LF   = 23552,
  OFF_MEAN_HF = 24576,
  OFF_RSTD_HF = 25600,
  OFF_MEAN_LF = 26624,
  OFF_RSTD_LF = 27648,
  OFF_U16     = 32768,          // start of ushort region (float units)
};
// ushort offsets relative to u16 base
enum : size_t {
  U_YH  = 0,          // [4][128][128][256] bf16
  U_YL  = 16777216,   // [4][64][64][256]
  U_HFA = 20971520,   // [4][128][128][256]
  U_LFA = 37748736,   // [4][64][64][256]
  U_HFP = 41943040,   // [4][64][64][256]
  U_PK  = 46137344,   // 6 packed weight slots, each 589824 (slot2 unused)
  PK_SZ = 589824,
  U_PKPH = U_PK + 6 * PK_SZ,    // phase-packed l2h: 4ph x 4tap x 8icc x 16mf x 64 x 8
  PH_SZ  = 1048576,
  U_PHB  = U_PKPH + PH_SZ,      // phase buffer [4][256][4][64][64] bf16
  U_END  = U_PHB + 16777216,
};
enum : size_t { TOTAL_F = OFF_U16 + (U_END + 1) / 2 };

__device__ float g_scratch[TOTAL_F];

__device__ __forceinline__ int refl(int q, int n) {
  return q < 0 ? -q : (q >= n ? 2 * n - 2 - q : q);
}
__device__ __forceinline__ float lrelu(float v) { return v >= 0.f ? v : SLOPE * v; }
__device__ __forceinline__ unsigned short f2bf(float f) {
  unsigned int u = __float_as_uint(f);
  u += 0x7fffu + ((u >> 16) & 1u);
  return (unsigned short)(u >> 16);
}
__device__ __forceinline__ float bf2f(unsigned short h) {
  return __uint_as_float(((unsigned int)h) << 16);
}
__device__ __forceinline__ void gload_lds16(const void* g, void* l) {
  __builtin_amdgcn_global_load_lds(
      (const __attribute__((address_space(1))) unsigned int*)g,
      (__attribute__((address_space(3))) unsigned int*)l, 16, 0, 0);
}

// ---------------- fused pre-pass: spatial-ws [0,2048) | istats [2048,4096) | point [4096,4104) ----
__global__ __launch_bounds__(256) void k_pre(
    const float* __restrict__ s_hf, const float* __restrict__ sw_hf,
    const float* __restrict__ sb_hf, float* __restrict__ ws_hf,
    const float* __restrict__ s_lf, const float* __restrict__ sw_lf,
    const float* __restrict__ sb_lf, float* __restrict__ ws_lf,
    const float* __restrict__ pw_hf, const float* __restrict__ pb_hf,
    const float* __restrict__ bw_hf, const float* __restrict__ bb_hf,
    float* __restrict__ wp_hf, float* __restrict__ bs_hf,
    const float* __restrict__ pw_lf, const float* __restrict__ pb_lf,
    const float* __restrict__ bw_lf, const float* __restrict__ bb_lf,
    float* __restrict__ wp_lf, float* __restrict__ bs_lf,
    const float* __restrict__ c_hf, float* __restrict__ mean_hf, float* __restrict__ rstd_hf,
    const float* __restrict__ c_lf, float* __restrict__ mean_lf, float* __restrict__ rstd_lf) {
  __shared__ float sh[256 * 9];
  const int bx = blockIdx.x;
  const int t = threadIdx.x;

  if (bx < 2048) {
    // ---- spatial weights ws = conv(rpad(s,1), sw) + sb ----
    const bool lf = bx >= 1024;
    const int bo = bx & 1023;
    const float* s  = lf ? s_lf : s_hf;
    const float* sw = lf ? sw_lf : sw_hf;
    const float* sb = lf ? sb_lf : sb_hf;
    float* ws_out   = lf ? ws_lf : ws_hf;
    int o = bo & (CDIM - 1);
    int c = t;
    int b = bo >> 8;
    float sv[9], wv[9];
    const float* sp = s + (size_t)(b * CDIM + c) * 9;
    const float* wp = sw + (size_t)(o * CDIM + c) * 9;
#pragma unroll
    for (int i = 0; i < 9; i++) { sv[i] = sp[i]; wv[i] = wp[i]; }
    float out9[9];
#pragma unroll
    for (int i = 0; i < 3; i++)
#pragma unroll
      for (int j = 0; j < 3; j++) {
        float a = 0.f;
#pragma unroll
        for (int dy = 0; dy < 3; dy++) {
          int u = i + dy - 1; u = (u < 0) ? 1 : (u > 2 ? 1 : u);
#pragma unroll
          for (int dx = 0; dx < 3; dx++) {
            int v = j + dx - 1; v = (v < 0) ? 1 : (v > 2 ? 1 : v);
            a += sv[u * 3 + v] * wv[dy * 3 + dx];
          }
        }
        out9[i * 3 + j] = a;
      }
#pragma unroll
    for (int i = 0; i < 9; i++) sh[c * 9 + i] = out9[i];
    __syncthreads();
    for (int st = 128; st > 0; st >>= 1) {
      if (c < st)
#pragma unroll
        for (int i = 0; i < 9; i++) sh[c * 9 + i] += sh[(c + st) * 9 + i];
      __syncthreads();
    }
    if (c < 9) ws_out[(size_t)bo * 9 + c] = sh[c] + sb[o];

  } else if (bx < 4096) {
    // ---- instance norm stats ----
    const int idx = bx - 2048;
    const bool lf = idx >= 1024;
    int plane = lf ? idx - 1024 : idx;
    const float* x = lf ? c_lf : c_hf;
    float* mean = lf ? mean_lf : mean_hf;
    float* rstd = lf ? rstd_lf : rstd_hf;
    const int HW = lf ? 4096 : 16384;
    const float4* p = (const float4*)(x + (size_t)plane * HW);
    int n4 = HW >> 2;
    float s = 0.f, q = 0.f;
    for (int i = t; i < n4; i += 256) {
      float4 v = p[i];
      s += v.x + v.y + v.z + v.w;
      q += v.x * v.x + v.y * v.y + v.z * v.z + v.w * v.w;
    }
    float* rs = sh;
    float* rq = sh + 256;
    rs[t] = s; rq[t] = q;
    __syncthreads();
    for (int st = 128; st > 0; st >>= 1) {
      if (t < st) { rs[t] += rs[t + st]; rq[t] += rq[t + st]; }
      __syncthreads();
    }
    if (t == 0) {
      float m = rs[0] / HW;
      float v = rq[0] / HW - m * m;
      mean[plane] = m;
      rstd[plane] = rsqrtf(v + EPS);
    }

  } else {
    // ---- pooled + w_point / bias ----
    const int idx = bx - 4096;
    const bool lf = (idx >> 2) != 0;
    const int b = idx & 3;
    const float* s  = lf ? s_lf : s_hf;
    const float* pw = lf ? pw_lf : pw_hf;
    const float* pb = lf ? pb_lf : pb_hf;
    const float* bw = lf ? bw_lf : bw_hf;
    const float* bb = lf ? bb_lf : bb_hf;
    float* wp_out = lf ? wp_lf : wp_hf;
    float* bs_out = lf ? bs_lf : bs_hf;
    const int o = t;
    float* pl = sh;
    const float* sp = s + (size_t)(b * CDIM + o) * 9;
    float a9 = 0.f;
#pragma unroll
    for (int j = 0; j < 9; j++) a9 += sp[j];
    pl[o] = a9 * (1.f / 9.f);
    __syncthreads();
    float a = pb[o], d = bb[o];
    const float4* pw4 = (const float4*)(pw + (size_t)o * CDIM);
    const float4* bw4 = (const float4*)(bw + (size_t)o * CDIM);
    const float4* pl4 = (const float4*)pl;
    for (int c4 = 0; c4 < CDIM / 4; c4++) {
      float4 p = pl4[c4];
      float4 w1 = pw4[c4], w2 = bw4[c4];
      a += p.x * w1.x + p.y * w1.y + p.z * w1.z + p.w * w1.w;
      d += p.x * w2.x + p.y * w2.y + p.z * w2.z + p.w * w2.w;
    }
    wp_out[b * CDIM + o] = a;
    bs_out[b * CDIM + o] = d;
  }
}

// ---------------- all weight packing in one launch ----------------
__global__ void k_packall(const float* __restrict__ w_adah, const float* __restrict__ w_h2h,
                          const float* __restrict__ w_adal, const float* __restrict__ w_l2l,
                          const float* __restrict__ w_h2l, const float* __restrict__ w_l2h,
                          unsigned short* __restrict__ pk, unsigned short* __restrict__ pkph) {
  int seg = blockIdx.y;
  int i = blockIdx.x * 256 + threadIdx.x;
  if (seg < 5) {
    if (i >= 589824) return;
    const float* srcs[5] = {w_adah, w_h2h, w_adal, w_l2l, w_h2l};
    const int slot[5] = {0, 1, 3, 4, 5};
    const float* w = srcs[seg];
    int j = i & 7, l = (i >> 3) & 63, mf = (i >> 9) & 15, icc = (i >> 13) & 7, tap = i >> 16;
    int oc = mf * 16 + (l & 15);
    int ic = icc * 32 + (l >> 4) * 8 + j;
    pk[(size_t)slot[seg] * PK_SZ + i] = f2bf(w[((size_t)oc * 256 + ic) * 9 + tap]);
  } else {
    // phase pack: i < 1048576
    int j = i & 7, l = (i >> 3) & 63, mf = (i >> 9) & 15, icc = (i >> 13) & 7, tapph = i >> 16;
    int tap = tapph & 3, phase = tapph >> 2;
    int tx = tap & 1, ty = tap >> 1;
    int a = phase >> 1, bp = phase & 1;
    int oc = mf * 16 + (l & 15);
    int ic = icc * 32 + (l >> 4) * 8 + j;
    int ys = (a == 0) ? (ty == 0 ? 0 : 1) : (ty == 0 ? 0 : 2);
    int yc = (a == 0) ? (ty == 0 ? 1 : 2) : (ty == 0 ? 2 : 1);
    int xs = (bp == 0) ? (tx == 0 ? 0 : 1) : (tx == 0 ? 0 : 2);
    int xc = (bp == 0) ? (tx == 0 ? 1 : 2) : (tx == 0 ? 2 : 1);
    const float* wb = w_l2h + ((size_t)oc * 256 + ic) * 9;
    float acc = 0.f;
    for (int dy = ys; dy < ys + yc; dy++)
      for (int dx = xs; dx < xs + xc; dx++) acc += wb[dy * 3 + dx];
    pkph[i] = f2bf(acc);
  }
}

// ---------------- fused IN + dynamic depthwise + pointwise -> NHWC bf16 (hf+lf merged) ----------
// grid: [0,4096) hf (LW=7), [4096,5120) lf (LW=6). vectorized 4 px/thread.
__global__ __launch_bounds__(256) void k_dwt_all(
    const float* __restrict__ xh, const float* __restrict__ wsh,
    const float* __restrict__ mh, const float* __restrict__ rh,
    const float* __restrict__ wph, const float* __restrict__ bsh,
    unsigned short* __restrict__ outh,
    const float* __restrict__ xl, const float* __restrict__ wsl,
    const float* __restrict__ ml, const float* __restrict__ rl,
    const float* __restrict__ wpl, const float* __restrict__ bsl,
    unsigned short* __restrict__ outl) {
  const int bid = blockIdx.x;
  const bool lf = bid >= 4096;
  const int W = lf ? 64 : 128;
  const int H = W, HW = W * W;
  const float *x, *ws, *mean, *rstd, *wp, *bs;
  unsigned short* out;
  int xt, icb, y, b;
  if (!lf) {
    x = xh; ws = wsh; mean = mh; rstd = rh; wp = wph; bs = bsh; out = outh;
    int x8 = bid & 7; xt = x8 & 1; icb = x8 >> 1; y = (bid >> 3) & 127; b = bid >> 10;
  } else {
    int local = bid - 4096;
    x = xl; ws = wsl; mean = ml; rstd = rl; wp = wpl; bs = bsl; out = outl;
    xt = 0; icb = local & 3; y = (local >> 2) & 63; b = local >> 8;
  }
  const int t = threadIdx.x;
  __shared__ unsigned short tr[64][66];
  const int xg = t & 15;                 // 16 groups of 4 px -> 64 px
  const int chq = t >> 4;                // 0..15
  const int x0 = xt * 64 + xg * 4;
  const int sy0 = refl(y - 1, H), sy2 = refl(y + 1, H);
  const int xm = refl(x0 - 1, W);
  const int xq = refl(x0 + 4, W);
#pragma unroll
  for (int rr = 0; rr < 4; ++rr) {
    int icl = rr * 16 + chq;
    int plane = b * CDIM + icb * 64 + icl;
    const float* xpb = x + (size_t)plane * HW;
    float m = mean[plane], r = rstd[plane], sc = wp[plane], bi = bs[plane];
    const float* w9p = ws + (size_t)plane * 9;
    float w9[9];
#pragma unroll
    for (int i = 0; i < 9; i++) w9[i] = w9p[i];
    float sumw = w9[0] + w9[1] + w9[2] + w9[3] + w9[4] + w9[5] + w9[6] + w9[7] + w9[8];
    const float* r0 = xpb + sy0 * W;
    const float* r1 = xpb + y * W;
    const float* r2 = xpb + sy2 * W;
    float4 v0 = *(const float4*)(r0 + x0);
    float4 v1 = *(const float4*)(r1 + x0);
    float4 v2 = *(const float4*)(r2 + x0);
    float e0[6] = {r0[xm], v0.x, v0.y, v0.z, v0.w, r0[xq]};
    float e1[6] = {r1[xm], v1.x, v1.y, v1.z, v1.w, r1[xq]};
    float e2[6] = {r2[xm], v2.x, v2.y, v2.z, v2.w, r2[xq]};
    float mterm = m * sumw;
#pragma unroll
    for (int j = 0; j < 4; ++j) {
      float a = w9[0] * e0[j] + w9[1] * e0[j + 1] + w9[2] * e0[j + 2] +
                w9[3] * e1[j] + w9[4] * e1[j + 1] + w9[5] * e1[j + 2] +
                w9[6] * e2[j] + w9[7] * e2[j + 1] + w9[8] * e2[j + 2];
      a -= mterm;
      tr[icl][xg * 4 + j] = f2bf(a * r * sc + bi);
    }
  }
  __syncthreads();
  // vectorized NHWC store: 64 px x 64 ch, u16x8 per store
#pragma unroll
  for (int it2 = 0; it2 < 2; ++it2) {
    int s2 = it2 * 256 + t;          // 0..511
    int xl2 = s2 >> 3;               // 0..63
    int cg = s2 & 7;                 // 0..7
    u16x8 v;
#pragma unroll
    for (int j = 0; j < 8; j++) v[j] = tr[cg * 8 + j][xl2];
    *(u16x8*)&out[((size_t)((b * H + y) * W + xt * 64 + xl2)) * CDIM + icb * 64 + cg * 8] = v;
  }
}

// ---------------- 2x2 avg pool on NHWC bf16 (vectorized: 8 ch / thread) ----------------
__global__ __launch_bounds__(256) void k_pool_nhwc(const unsigned short* __restrict__ in,
                                                   unsigned short* __restrict__ out) {
  int i = blockIdx.x * 256 + threadIdx.x;   // < 4*64*64*32
  int cg = i & 31;
  int p = i >> 5;                            // (b*64+Y)*64+X
  int X = p & 63, Y = (p >> 6) & 63, b = p >> 12;
  const unsigned short* s =
      in + ((size_t)(b * 128 + 2 * Y) * 128 + 2 * X) * CDIM + cg * 8;
  u16x8 v0 = *(const u16x8*)(s);
  u16x8 v1 = *(const u16x8*)(s + CDIM);
  u16x8 v2 = *(const u16x8*)(s + 128 * CDIM);
  u16x8 v3 = *(const u16x8*)(s + 128 * CDIM + CDIM);
  u16x8 r;
#pragma unroll
  for (int j = 0; j < 8; j++)
    r[j] = f2bf(0.25f * (bf2f(v0[j]) + bf2f(v1[j]) + bf2f(v2[j]) + bf2f(v3[j])));
  *(u16x8*)(out + (size_t)p * CDIM + cg * 8) = r;
}

// ---------------- MFMA implicit-GEMM 3x3 reflect conv (R5/R11 structure + ACC) ----------------
// block 256 (4 waves), tile 64 oc x 256 pixels. Single-buffer, 2 barriers per
// icc-step, 2 blocks/CU anti-phased. ACC: fuse += bf16 phase-buffer into the
// NCHW epilogue before lrelu.
template <int LW, bool DUAL, bool UPSB, bool NCHWOUT, bool ACC>
__global__ __launch_bounds__(256, 2) void k_conv_mfma(
    const unsigned short* __restrict__ srcA, const unsigned short* __restrict__ srcB,
    const unsigned short* __restrict__ wpkA, const unsigned short* __restrict__ wpkB,
    const float* __restrict__ bias, const unsigned short* __restrict__ accsrc,
    void* __restrict__ outp) {
  constexpr int W = 1 << LW, H = W, HW = W * W;
  constexpr int ROWS = 256 >> LW;       // pixel rows per block
  constexpr int R = ROWS + 2, Cw = W + 2;
  constexpr int RC = R * Cw;
  constexpr int RCPAD = (RC + 63) & ~63;
  constexpr int NIT = RCPAD / 64;
  __shared__ __align__(16) unsigned short tin[RCPAD * 32];        // input tile, 32 ic
  __shared__ __align__(16) unsigned short wlds[9 * 4 * 64 * 8];   // 9 taps x 4 mi frags

  const int t = threadIdx.x;
  const int l = t & 63, wv = t >> 6;
  const int l15 = l & 15, l4 = l >> 4;

  // XCD-chunked bijective swizzle (nwg divisible by 8)
  const int hwid = blockIdx.x;
  const int nwg = gridDim.x;
  const int wk = (hwid & 7) * (nwg >> 3) + (hwid >> 3);
  const int mb = wk & 3;
  const int pixbase = (wk >> 2) * 256;
  const int b = pixbase >> (2 * LW);
  const int y0 = (pixbase >> LW) & (H - 1);

  f32x4 acc[4][4];
#pragma unroll
  for (int mi = 0; mi < 4; mi++)
#pragma unroll
    for (int nf = 0; nf < 4; nf++) acc[mi][nf] = (f32x4){0.f, 0.f, 0.f, 0.f};

  const int nsrc = DUAL ? 2 : 1;
  for (int src = 0; src < nsrc; ++src) {
    const unsigned short* ysrc = src ? srcB : srcA;
    const unsigned short* wpk = src ? wpkB : wpkA;
    const bool ups = UPSB && (src == 1);

    // hoist staging addresses out of the K loop
    const unsigned short* inptr[NIT];
#pragma unroll
    for (int it = 0; it < NIT; ++it) {
      int rc = it * 64 + (t >> 2);
      int rcc = rc < RC - 1 ? rc : RC - 1;
      int r = rcc / Cw, tc = rcc - r * Cw;
      int gy = refl(y0 - 1 + r, H);
      int gx = refl(tc - 1, W);
      int sy, sx, sw;
      if (ups) { sy = gy >> 1; sx = gx >> 1; sw = W >> 1; }
      else     { sy = gy;      sx = gx;      sw = W; }
      int gsrc = (t & 3) ^ (tc & 3);   // ic-slot XOR swizzle (source side)
      inptr[it] = ysrc + (((size_t)(b * sw + sy) * sw + sx) * CDIM + gsrc * 8);
    }
    const unsigned short* wsrc = wpk + ((size_t)(mb * 4 + wv) * 64 + l) * 8;

    for (int icc = 0; icc < 8; ++icc) {
      __syncthreads();
#pragma unroll
      for (int it = 0; it < NIT; ++it)
        gload_lds16(inptr[it] + icc * 32, &tin[(size_t)(it * 256 + t) * 8]);
#pragma unroll
      for (int tap = 0; tap < 9; ++tap)
        gload_lds16(wsrc + ((size_t)tap * 8 + (size_t)icc) * 8192,
                    &wlds[(size_t)(tap * 256 + t) * 8]);
      __syncthreads();

      __builtin_amdgcn_s_setprio(1);
#pragma unroll
      for (int tap = 0; tap < 9; ++tap) {
        const int dy = tap / 3, dx = tap - 3 * (tap / 3);
        bf16x8 af[4];
#pragma unroll
        for (int mi = 0; mi < 4; mi++)
          af[mi] = *(const bf16x8*)&wlds[(size_t)((tap * 4 + mi) * 64 + l) * 8];
#pragma unroll
        for (int nf = 0; nf < 4; nf++) {
          int pl = wv * 64 + nf * 16 + l15;
          int py = pl >> LW;
          int c = pl & (W - 1);
          int tcol = c + dx;
          int idx16 = ((py + dy) * Cw + tcol) * 4 + (l4 ^ (tcol & 3));
          bf16x8 bfv = *(const bf16x8*)&tin[(size_t)idx16 * 8];
#pragma unroll
          for (int mi = 0; mi < 4; mi++)
            acc[mi][nf] = __builtin_amdgcn_mfma_f32_16x16x32_bf16(af[mi], bfv, acc[mi][nf], 0, 0, 0);
        }
      }
      __builtin_amdgcn_s_setprio(0);
    }
  }

  // epilogue
#pragma unroll
  for (int mi = 0; mi < 4; mi++) {
    int oc0 = mb * 64 + mi * 16 + l4 * 4;
    float bv[4];
#pragma unroll
    for (int rr = 0; rr < 4; rr++) bv[rr] = bias ? bias[oc0 + rr] : 0.f;
#pragma unroll
    for (int nf = 0; nf < 4; nf++) {
      int p = pixbase + wv * 64 + nf * 16 + l15;
      if (NCHWOUT) {
        float* o = (float*)outp;
        int pin = p & (HW - 1);
        int bb2 = p >> (2 * LW);
        int yy = pin >> LW, xx = pin & (W - 1);
        int ph = ((yy & 1) << 1) | (xx & 1);
        int q = (yy >> 1) * (W / 2) + (xx >> 1);
#pragma unroll
        for (int rr = 0; rr < 4; rr++) {
          float v = acc[mi][nf][rr] + bv[rr];
          if (ACC)
            v += bf2f(accsrc[((size_t)(bb2 * CDIM + oc0 + rr) * 4 + ph) * (HW / 4) + q]);
          o[((size_t)(bb2 * CDIM + oc0 + rr)) * HW + pin] = lrelu(v);
        }
      } else {
        unsigned short* o = (unsigned short*)outp;
        ushort4 pk;
        pk.x = f2bf(lrelu(acc[mi][nf][0] + bv[0]));
        pk.y = f2bf(lrelu(acc[mi][nf][1] + bv[1]));
        pk.z = f2bf(lrelu(acc[mi][nf][2] + bv[2]));
        pk.w = f2bf(lrelu(acc[mi][nf][3] + bv[3]));
        *(ushort4*)&o[(size_t)p * CDIM + oc0] = pk;
      }
    }
  }
}

// ---------------- phase-collapsed upsample-conv: 4-tap GEMM on lf grid ----------------
__global__ __launch_bounds__(256, 3) void k_conv_up(
    const unsigned short* __restrict__ lf, const unsigned short* __restrict__ wph,
    unsigned short* __restrict__ phb) {
  constexpr int NIT = 5;                      // 5 rows x 64 cols staged
  __shared__ __align__(16) unsigned short tin[320 * 64 / 2];      // 320 slots x 32ic x 2B
  __shared__ __align__(16) unsigned short wlds[4 * 256 * 8];      // 4 taps

  const int t = threadIdx.x;
  const int l = t & 63, wv = t >> 6;
  const int l15 = l & 15, l4 = l >> 4;

  const int hwid = blockIdx.x;
  const int wk = (hwid & 7) * 128 + (hwid >> 3);   // nwg = 1024
  const int mb = wk & 3;
  const int phase = (wk >> 2) & 3;
  const int tile = (wk >> 4) & 15;
  const int b = wk >> 8;
  const int a = phase >> 1, bp = phase & 1;
  const int Y0 = tile * 4;

  f32x4 acc[4][4];
#pragma unroll
  for (int mi = 0; mi < 4; mi++)
#pragma unroll
    for (int nf = 0; nf < 4; nf++) acc[mi][nf] = (f32x4){0.f, 0.f, 0.f, 0.f};

  const unsigned short* inptr[NIT];
#pragma unroll
  for (int it = 0; it < NIT; ++it) {
    int s = it * 64 + (t >> 2);
    int row = s >> 6, col = s & 63;
    int ly = Y0 - 1 + a + row;
    ly = ly < 0 ? 0 : (ly > 63 ? 63 : ly);
    int gsrc = (t & 3) ^ (col & 3);
    inptr[it] = lf + (((size_t)(b * 64 + ly) * 64 + col) * CDIM + gsrc * 8);
  }
  const unsigned short* wsrc = wph + ((size_t)(mb * 4 + wv) * 64 + l) * 8;

  for (int icc = 0; icc < 8; ++icc) {
    __syncthreads();
#pragma unroll
    for (int it = 0; it < NIT; ++it)
      gload_lds16(inptr[it] + icc * 32, &tin[(size_t)(it * 256 + t) * 8]);
#pragma unroll
    for (int tap = 0; tap < 4; ++tap)
      gload_lds16(wsrc + ((size_t)(phase * 4 + tap) * 8 + (size_t)icc) * 8192,
                  &wlds[(size_t)(tap * 256 + t) * 8]);
    __syncthreads();

    __builtin_amdgcn_s_setprio(1);
#pragma unroll
    for (int tap = 0; tap < 4; ++tap) {
      const int ty = tap >> 1, tx = tap & 1;
      bf16x8 af[4];
#pragma unroll
      for (int mi = 0; mi < 4; mi++)
        af[mi] = *(const bf16x8*)&wlds[(size_t)((tap * 4 + mi) * 64 + l) * 8];
#pragma unroll
      for (int nf = 0; nf < 4; nf++) {
        int pl = wv * 64 + nf * 16 + l15;
        int py = pl >> 6;
        int col = pl & 63;
        int tcol = col - 1 + bp + tx;
        tcol = tcol < 0 ? 0 : (tcol > 63 ? 63 : tcol);
        int idx16 = ((py + ty) * 64 + tcol) * 4 + (l4 ^ (tcol & 3));
        bf16x8 bfv = *(const bf16x8*)&tin[(size_t)idx16 * 8];
#pragma unroll
        for (int mi = 0; mi < 4; mi++)
          acc[mi][nf] = __builtin_amdgcn_mfma_f32_16x16x32_bf16(af[mi], bfv, acc[mi][nf], 0, 0, 0);
      }
    }
    __builtin_amdgcn_s_setprio(0);
  }

  // coalesced write into bf16 phase buffer
#pragma unroll
  for (int mi = 0; mi < 4; mi++) {
    int oc0 = mb * 64 + mi * 16 + l4 * 4;
#pragma unroll
    for (int nf = 0; nf < 4; nf++) {
      int pl = wv * 64 + nf * 16 + l15;
      int py = pl >> 6, col = pl & 63;
      size_t base = ((size_t)(b * CDIM + oc0) * 4 + phase) * 4096 + (Y0 + py) * 64 + col;
#pragma unroll
      for (int rr = 0; rr < 4; rr++)
        phb[base + (size_t)rr * 4 * 4096] = f2bf(acc[mi][nf][rr]);
    }
  }
}

// ---------------- host ----------------
extern "C" void kernel_launch(void* const* d_in, const int* in_sizes, int n_in,
                              void* d_out, int out_size, void* d_ws, size_t ws_size,
                              hipStream_t stream) {
  (void)in_sizes; (void)n_in; (void)out_size;
  const float* c_hf = (const float*)d_in[0];
  const float* c_lf = (const float*)d_in[1];
  const float* s_hf = (const float*)d_in[2];
  const float* s_lf = (const float*)d_in[3];
  const float* h_sw = (const float*)d_in[4];
  const float* h_sb = (const float*)d_in[5];
  const float* h_pw = (const float*)d_in[6];
  const float* h_pb = (const float*)d_in[7];
  const float* h_bw = (const float*)d_in[8];
  const float* h_bb = (const float*)d_in[9];
  const float* l_sw = (const float*)d_in[10];
  const float* l_sb = (const float*)d_in[11];
  const float* l_pw = (const float*)d_in[12];
  const float* l_pb = (const float*)d_in[13];
  const float* l_bw = (const float*)d_in[14];
  const float* l_bb = (const float*)d_in[15];
  const float* ada_h_w = (const float*)d_in[16];
  const float* ada_h_b = (const float*)d_in[17];
  const float* ada_l_w = (const float*)d_in[18];
  const float* ada_l_b = (const float*)d_in[19];
  const float* h2h = (const float*)d_in[20];
  const float* l2h = (const float*)d_in[21];
  const float* h2l = (const float*)d_in[22];
  const float* l2l = (const float*)d_in[23];

  float* base;
  size_t need = (size_t)TOTAL_F * sizeof(float);
  if (ws_size >= need) {
    base = (float*)d_ws;
  } else {
    void* p = nullptr;
    hipGetSymbolAddress(&p, HIP_SYMBOL(g_scratch));
    base = (float*)p;
  }

  float* ws_hf = base + OFF_WS_HF;
  float* ws_lf = base + OFF_WS_LF;
  float* wp_hf = base + OFF_WP_HF;
  float* bs_hf = base + OFF_BS_HF;
  float* wp_lf = base + OFF_WP_LF;
  float* bs_lf = base + OFF_BS_LF;
  float* mean_hf = base + OFF_MEAN_HF;
  float* rstd_hf = base + OFF_RSTD_HF;
  float* mean_lf = base + OFF_MEAN_LF;
  float* rstd_lf = base + OFF_RSTD_LF;
  unsigned short* u16 = (unsigned short*)(base + OFF_U16);
  unsigned short* yh = u16 + U_YH;
  unsigned short* yl = u16 + U_YL;
  unsigned short* hfA = u16 + U_HFA;
  unsigned short* lfA = u16 + U_LFA;
  unsigned short* hfP = u16 + U_HFP;
  unsigned short* pk      = u16 + U_PK;
  unsigned short* pk_adah = pk + 0 * PK_SZ;
  unsigned short* pk_h2h  = pk + 1 * PK_SZ;
  unsigned short* pk_adal = pk + 3 * PK_SZ;
  unsigned short* pk_l2l  = pk + 4 * PK_SZ;
  unsigned short* pk_h2l  = pk + 5 * PK_SZ;
  unsigned short* pk_ph   = u16 + U_PKPH;
  unsigned short* phb     = u16 + U_PHB;

  float* out_hf = (float*)d_out;
  float* out_lf = (float*)d_out + 16777216;

  // weight packing (all in one launch)
  k_packall<<<dim3(4096, 6), dim3(256), 0, stream>>>(ada_h_w, h2h, ada_l_w, l2l, h2l, l2h,
                                                     pk, pk_ph);

  // fused pre-pass: spatial-ws + istats + point
  k_pre<<<dim3(4104), dim3(256), 0, stream>>>(
      s_hf, h_sw, h_sb, ws_hf, s_lf, l_sw, l_sb, ws_lf,
      h_pw, h_pb, h_bw, h_bb, wp_hf, bs_hf,
      l_pw, l_pb, l_bw, l_bb, wp_lf, bs_lf,
      c_hf, mean_hf, rstd_hf, c_lf, mean_lf, rstd_lf);

  // fused IN + depthwise + pointwise -> NHWC bf16 (hf + lf in one launch)
  k_dwt_all<<<dim3(5120), dim3(256), 0, stream>>>(
      c_hf, ws_hf, mean_hf, rstd_hf, wp_hf, bs_hf, yh,
      c_lf, ws_lf, mean_lf, rstd_lf, wp_lf, bs_lf, yl);

  // ada convs (MFMA), bf16 NHWC out, lrelu
  k_conv_mfma<7, false, false, false, false><<<dim3(1024), dim3(256), 0, stream>>>(
      yh, nullptr, pk_adah, nullptr, ada_h_b, nullptr, hfA);
  k_conv_mfma<6, false, false, false, false><<<dim3(256), dim3(256), 0, stream>>>(
      yl, nullptr, pk_adal, nullptr, ada_l_b, nullptr, lfA);

  // phase-collapsed conv(up(lf), l2h) -> bf16 phase buffer
  k_conv_up<<<dim3(1024), dim3(256), 0, stream>>>(lfA, pk_ph, phb);

  // avgpool hf (vectorized)
  k_pool_nhwc<<<dim3(2048), dim3(256), 0, stream>>>(hfA, hfP);

  // hf_out = lrelu(conv(hf,h2h) + phase buffer)
  k_conv_mfma<7, false, false, true, true><<<dim3(1024), dim3(256), 0, stream>>>(
      hfA, nullptr, pk_h2h, nullptr, nullptr, phb, out_hf);

  // lf_out = lrelu(conv(lf,l2l) + conv(avgpool2(hf),h2l))
  k_conv_mfma<6, true, false, true, false><<<dim3(256), dim3(256), 0, stream>>>(
      lfA, hfP, pk_l2l, pk_h2l, nullptr, nullptr, out_lf);
}

// Round 15
// 336.522 us; speedup vs baseline: 1.1771x; 1.1094x over previous
//
#include <hip/hip_runtime.h>
#include <hip/hip_bf16.h>

#define CDIM 256
#define EPS 1e-5f
#define SLOPE 0.01f

using f32x4  = __attribute__((ext_vector_type(4))) float;
typedef __bf16 bf16x8 __attribute__((ext_vector_type(8)));
typedef unsigned short u16x8 __attribute__((ext_vector_type(8)));

// ---------------- workspace layout ----------------
enum : size_t {
  OFF_WS_HF   = 0,
  OFF_WS_LF   = 9216,
  OFF_WP_HF   = 20480,
  OFF_BS_HF   = 21504,
  OFF_WP_LF   = 22528,
  OFF_BS_LF   = 23552,
  OFF_MEAN_HF = 24576,
  OFF_RSTD_HF = 25600,
  OFF_MEAN_LF = 26624,
  OFF_RSTD_LF = 27648,
  OFF_U16     = 32768,          // start of ushort region (float units)
};
// ushort offsets relative to u16 base
enum : size_t {
  U_YH  = 0,          // [4][128][128][256] bf16
  U_YL  = 16777216,   // [4][64][64][256]
  U_HFA = 20971520,   // [4][128][128][256]
  U_LFA = 37748736,   // [4][64][64][256]
  U_HFP = 41943040,   // [4][64][64][256]
  U_PK  = 46137344,   // 6 packed weight slots, each 589824 (slot2 unused)
  PK_SZ = 589824,
  U_PKPH = U_PK + 6 * PK_SZ,    // phase-packed l2h: 4ph x 4tap x 8icc x 16mf x 64 x 8
  PH_SZ  = 1048576,
  U_PHB  = U_PKPH + PH_SZ,      // phase buffer [4][256][4][64][64] bf16
  U_END  = U_PHB + 16777216,
};
enum : size_t { TOTAL_F = OFF_U16 + (U_END + 1) / 2 };

__device__ float g_scratch[TOTAL_F];

__device__ __forceinline__ int refl(int q, int n) {
  return q < 0 ? -q : (q >= n ? 2 * n - 2 - q : q);
}
__device__ __forceinline__ float lrelu(float v) { return v >= 0.f ? v : SLOPE * v; }
__device__ __forceinline__ unsigned short f2bf(float f) {
  unsigned int u = __float_as_uint(f);
  u += 0x7fffu + ((u >> 16) & 1u);
  return (unsigned short)(u >> 16);
}
__device__ __forceinline__ float bf2f(unsigned short h) {
  return __uint_as_float(((unsigned int)h) << 16);
}
__device__ __forceinline__ void gload_lds16(const void* g, void* l) {
  __builtin_amdgcn_global_load_lds(
      (const __attribute__((address_space(1))) unsigned int*)g,
      (__attribute__((address_space(3))) unsigned int*)l, 16, 0, 0);
}

// ---------------- fused prep: packall [0,24576) | ws [24576,26624) | istats | point ----------
__global__ __launch_bounds__(256) void k_prep(
    const float* __restrict__ w_adah, const float* __restrict__ w_h2h,
    const float* __restrict__ w_adal, const float* __restrict__ w_l2l,
    const float* __restrict__ w_h2l, const float* __restrict__ w_l2h,
    unsigned short* __restrict__ pk, unsigned short* __restrict__ pkph,
    const float* __restrict__ s_hf, const float* __restrict__ sw_hf,
    const float* __restrict__ sb_hf, float* __restrict__ ws_hf,
    const float* __restrict__ s_lf, const float* __restrict__ sw_lf,
    const float* __restrict__ sb_lf, float* __restrict__ ws_lf,
    const float* __restrict__ pw_hf, const float* __restrict__ pb_hf,
    const float* __restrict__ bw_hf, const float* __restrict__ bb_hf,
    float* __restrict__ wp_hf, float* __restrict__ bs_hf,
    const float* __restrict__ pw_lf, const float* __restrict__ pb_lf,
    const float* __restrict__ bw_lf, const float* __restrict__ bb_lf,
    float* __restrict__ wp_lf, float* __restrict__ bs_lf,
    const float* __restrict__ c_hf, float* __restrict__ mean_hf, float* __restrict__ rstd_hf,
    const float* __restrict__ c_lf, float* __restrict__ mean_lf, float* __restrict__ rstd_lf) {
  __shared__ float sh[256 * 9];
  const int bid = blockIdx.x;
  const int t = threadIdx.x;

  if (bid < 24576) {
    // ---- weight packing ----
    int seg = bid >> 12;                       // 0..5
    int i = ((bid & 4095) << 8) + t;
    if (seg < 5) {
      if (i >= 589824) return;
      const float* srcs[5] = {w_adah, w_h2h, w_adal, w_l2l, w_h2l};
      const int slot[5] = {0, 1, 3, 4, 5};
      const float* w = srcs[seg];
      int j = i & 7, l = (i >> 3) & 63, mf = (i >> 9) & 15, icc = (i >> 13) & 7, tap = i >> 16;
      int oc = mf * 16 + (l & 15);
      int ic = icc * 32 + (l >> 4) * 8 + j;
      pk[(size_t)slot[seg] * PK_SZ + i] = f2bf(w[((size_t)oc * 256 + ic) * 9 + tap]);
    } else {
      int j = i & 7, l = (i >> 3) & 63, mf = (i >> 9) & 15, icc = (i >> 13) & 7, tapph = i >> 16;
      int tap = tapph & 3, phase = tapph >> 2;
      int tx = tap & 1, ty = tap >> 1;
      int a = phase >> 1, bp = phase & 1;
      int oc = mf * 16 + (l & 15);
      int ic = icc * 32 + (l >> 4) * 8 + j;
      int ys = (a == 0) ? (ty == 0 ? 0 : 1) : (ty == 0 ? 0 : 2);
      int yc = (a == 0) ? (ty == 0 ? 1 : 2) : (ty == 0 ? 2 : 1);
      int xs = (bp == 0) ? (tx == 0 ? 0 : 1) : (tx == 0 ? 0 : 2);
      int xc = (bp == 0) ? (tx == 0 ? 1 : 2) : (tx == 0 ? 2 : 1);
      const float* wb = w_l2h + ((size_t)oc * 256 + ic) * 9;
      float acc = 0.f;
      for (int dy = ys; dy < ys + yc; dy++)
        for (int dx = xs; dx < xs + xc; dx++) acc += wb[dy * 3 + dx];
      pkph[i] = f2bf(acc);
    }
    return;
  }

  const int bx = bid - 24576;                  // 0..4103
  if (bx < 2048) {
    // ---- spatial weights ws = conv(rpad(s,1), sw) + sb ----
    const bool lf = bx >= 1024;
    const int bo = bx & 1023;
    const float* s  = lf ? s_lf : s_hf;
    const float* sw = lf ? sw_lf : sw_hf;
    const float* sb = lf ? sb_lf : sb_hf;
    float* ws_out   = lf ? ws_lf : ws_hf;
    int o = bo & (CDIM - 1);
    int c = t;
    int b = bo >> 8;
    float sv[9], wv[9];
    const float* sp = s + (size_t)(b * CDIM + c) * 9;
    const float* wp = sw + (size_t)(o * CDIM + c) * 9;
#pragma unroll
    for (int i = 0; i < 9; i++) { sv[i] = sp[i]; wv[i] = wp[i]; }
    float out9[9];
#pragma unroll
    for (int i = 0; i < 3; i++)
#pragma unroll
      for (int j = 0; j < 3; j++) {
        float a = 0.f;
#pragma unroll
        for (int dy = 0; dy < 3; dy++) {
          int u = i + dy - 1; u = (u < 0) ? 1 : (u > 2 ? 1 : u);
#pragma unroll
          for (int dx = 0; dx < 3; dx++) {
            int v = j + dx - 1; v = (v < 0) ? 1 : (v > 2 ? 1 : v);
            a += sv[u * 3 + v] * wv[dy * 3 + dx];
          }
        }
        out9[i * 3 + j] = a;
      }
#pragma unroll
    for (int i = 0; i < 9; i++) sh[c * 9 + i] = out9[i];
    __syncthreads();
    for (int st = 128; st > 0; st >>= 1) {
      if (c < st)
#pragma unroll
        for (int i = 0; i < 9; i++) sh[c * 9 + i] += sh[(c + st) * 9 + i];
      __syncthreads();
    }
    if (c < 9) ws_out[(size_t)bo * 9 + c] = sh[c] + sb[o];

  } else if (bx < 4096) {
    // ---- instance norm stats ----
    const int idx = bx - 2048;
    const bool lf = idx >= 1024;
    int plane = lf ? idx - 1024 : idx;
    const float* x = lf ? c_lf : c_hf;
    float* mean = lf ? mean_lf : mean_hf;
    float* rstd = lf ? rstd_lf : rstd_hf;
    const int HW = lf ? 4096 : 16384;
    const float4* p = (const float4*)(x + (size_t)plane * HW);
    int n4 = HW >> 2;
    float s = 0.f, q = 0.f;
    for (int i = t; i < n4; i += 256) {
      float4 v = p[i];
      s += v.x + v.y + v.z + v.w;
      q += v.x * v.x + v.y * v.y + v.z * v.z + v.w * v.w;
    }
    float* rs = sh;
    float* rq = sh + 256;
    rs[t] = s; rq[t] = q;
    __syncthreads();
    for (int st = 128; st > 0; st >>= 1) {
      if (t < st) { rs[t] += rs[t + st]; rq[t] += rq[t + st]; }
      __syncthreads();
    }
    if (t == 0) {
      float m = rs[0] / HW;
      float v = rq[0] / HW - m * m;
      mean[plane] = m;
      rstd[plane] = rsqrtf(v + EPS);
    }

  } else {
    // ---- pooled + w_point / bias ----
    const int idx = bx - 4096;
    const bool lf = (idx >> 2) != 0;
    const int b = idx & 3;
    const float* s  = lf ? s_lf : s_hf;
    const float* pw = lf ? pw_lf : pw_hf;
    const float* pb = lf ? pb_lf : pb_hf;
    const float* bw = lf ? bw_lf : bw_hf;
    const float* bb = lf ? bb_lf : bb_hf;
    float* wp_out = lf ? wp_lf : wp_hf;
    float* bs_out = lf ? bs_lf : bs_hf;
    const int o = t;
    float* pl = sh;
    const float* sp = s + (size_t)(b * CDIM + o) * 9;
    float a9 = 0.f;
#pragma unroll
    for (int j = 0; j < 9; j++) a9 += sp[j];
    pl[o] = a9 * (1.f / 9.f);
    __syncthreads();
    float a = pb[o], d = bb[o];
    const float4* pw4 = (const float4*)(pw + (size_t)o * CDIM);
    const float4* bw4 = (const float4*)(bw + (size_t)o * CDIM);
    const float4* pl4 = (const float4*)pl;
    for (int c4 = 0; c4 < CDIM / 4; c4++) {
      float4 p = pl4[c4];
      float4 w1 = pw4[c4], w2 = bw4[c4];
      a += p.x * w1.x + p.y * w1.y + p.z * w1.z + p.w * w1.w;
      d += p.x * w2.x + p.y * w2.y + p.z * w2.z + p.w * w2.w;
    }
    wp_out[b * CDIM + o] = a;
    bs_out[b * CDIM + o] = d;
  }
}

// ---------------- fused IN + dynamic depthwise + pointwise -> NHWC bf16 (hf+lf merged) ----------
__global__ __launch_bounds__(256) void k_dwt_all(
    const float* __restrict__ xh, const float* __restrict__ wsh,
    const float* __restrict__ mh, const float* __restrict__ rh,
    const float* __restrict__ wph, const float* __restrict__ bsh,
    unsigned short* __restrict__ outh,
    const float* __restrict__ xl, const float* __restrict__ wsl,
    const float* __restrict__ ml, const float* __restrict__ rl,
    const float* __restrict__ wpl, const float* __restrict__ bsl,
    unsigned short* __restrict__ outl) {
  const int bid = blockIdx.x;
  const bool lf = bid >= 4096;
  const int W = lf ? 64 : 128;
  const int H = W, HW = W * W;
  const float *x, *ws, *mean, *rstd, *wp, *bs;
  unsigned short* out;
  int xt, icb, y, b;
  if (!lf) {
    x = xh; ws = wsh; mean = mh; rstd = rh; wp = wph; bs = bsh; out = outh;
    int x8 = bid & 7; xt = x8 & 1; icb = x8 >> 1; y = (bid >> 3) & 127; b = bid >> 10;
  } else {
    int local = bid - 4096;
    x = xl; ws = wsl; mean = ml; rstd = rl; wp = wpl; bs = bsl; out = outl;
    xt = 0; icb = local & 3; y = (local >> 2) & 63; b = local >> 8;
  }
  const int t = threadIdx.x;
  __shared__ unsigned short tr[64][66];
  const int xg = t & 15;
  const int chq = t >> 4;
  const int x0 = xt * 64 + xg * 4;
  const int sy0 = refl(y - 1, H), sy2 = refl(y + 1, H);
  const int xm = refl(x0 - 1, W);
  const int xq = refl(x0 + 4, W);
#pragma unroll
  for (int rr = 0; rr < 4; ++rr) {
    int icl = rr * 16 + chq;
    int plane = b * CDIM + icb * 64 + icl;
    const float* xpb = x + (size_t)plane * HW;
    float m = mean[plane], r = rstd[plane], sc = wp[plane], bi = bs[plane];
    const float* w9p = ws + (size_t)plane * 9;
    float w9[9];
#pragma unroll
    for (int i = 0; i < 9; i++) w9[i] = w9p[i];
    float sumw = w9[0] + w9[1] + w9[2] + w9[3] + w9[4] + w9[5] + w9[6] + w9[7] + w9[8];
    const float* r0 = xpb + sy0 * W;
    const float* r1 = xpb + y * W;
    const float* r2 = xpb + sy2 * W;
    float4 v0 = *(const float4*)(r0 + x0);
    float4 v1 = *(const float4*)(r1 + x0);
    float4 v2 = *(const float4*)(r2 + x0);
    float e0[6] = {r0[xm], v0.x, v0.y, v0.z, v0.w, r0[xq]};
    float e1[6] = {r1[xm], v1.x, v1.y, v1.z, v1.w, r1[xq]};
    float e2[6] = {r2[xm], v2.x, v2.y, v2.z, v2.w, r2[xq]};
    float mterm = m * sumw;
#pragma unroll
    for (int j = 0; j < 4; ++j) {
      float a = w9[0] * e0[j] + w9[1] * e0[j + 1] + w9[2] * e0[j + 2] +
                w9[3] * e1[j] + w9[4] * e1[j + 1] + w9[5] * e1[j + 2] +
                w9[6] * e2[j] + w9[7] * e2[j + 1] + w9[8] * e2[j + 2];
      a -= mterm;
      tr[icl][xg * 4 + j] = f2bf(a * r * sc + bi);
    }
  }
  __syncthreads();
#pragma unroll
  for (int it2 = 0; it2 < 2; ++it2) {
    int s2 = it2 * 256 + t;
    int xl2 = s2 >> 3;
    int cg = s2 & 7;
    u16x8 v;
#pragma unroll
    for (int j = 0; j < 8; j++) v[j] = tr[cg * 8 + j][xl2];
    *(u16x8*)&out[((size_t)((b * H + y) * W + xt * 64 + xl2)) * CDIM + icb * 64 + cg * 8] = v;
  }
}

// ---------------- conv body (R5/R11 structure + ACC), shared by merged kernels ----------------
template <int LW, bool DUAL, bool UPSB, bool NCHWOUT, bool ACC>
__device__ __forceinline__ void conv_body(
    int wk, unsigned short* tin, unsigned short* wlds,
    const unsigned short* __restrict__ srcA, const unsigned short* __restrict__ srcB,
    const unsigned short* __restrict__ wpkA, const unsigned short* __restrict__ wpkB,
    const float* __restrict__ bias, const unsigned short* __restrict__ accsrc,
    void* __restrict__ outp) {
  constexpr int W = 1 << LW, H = W, HW = W * W;
  constexpr int ROWS = 256 >> LW;
  constexpr int R = ROWS + 2, Cw = W + 2;
  constexpr int RC = R * Cw;
  constexpr int RCPAD = (RC + 63) & ~63;
  constexpr int NIT = RCPAD / 64;

  const int t = threadIdx.x;
  const int l = t & 63, wv = t >> 6;
  const int l15 = l & 15, l4 = l >> 4;

  const int mb = wk & 3;
  const int pixbase = (wk >> 2) * 256;
  const int b = pixbase >> (2 * LW);
  const int y0 = (pixbase >> LW) & (H - 1);

  f32x4 acc[4][4];
#pragma unroll
  for (int mi = 0; mi < 4; mi++)
#pragma unroll
    for (int nf = 0; nf < 4; nf++) acc[mi][nf] = (f32x4){0.f, 0.f, 0.f, 0.f};

  const int nsrc = DUAL ? 2 : 1;
  for (int src = 0; src < nsrc; ++src) {
    const unsigned short* ysrc = src ? srcB : srcA;
    const unsigned short* wpk = src ? wpkB : wpkA;
    const bool ups = UPSB && (src == 1);

    const unsigned short* inptr[NIT];
#pragma unroll
    for (int it = 0; it < NIT; ++it) {
      int rc = it * 64 + (t >> 2);
      int rcc = rc < RC - 1 ? rc : RC - 1;
      int r = rcc / Cw, tc = rcc - r * Cw;
      int gy = refl(y0 - 1 + r, H);
      int gx = refl(tc - 1, W);
      int sy, sx, sw;
      if (ups) { sy = gy >> 1; sx = gx >> 1; sw = W >> 1; }
      else     { sy = gy;      sx = gx;      sw = W; }
      int gsrc = (t & 3) ^ (tc & 3);
      inptr[it] = ysrc + (((size_t)(b * sw + sy) * sw + sx) * CDIM + gsrc * 8);
    }
    const unsigned short* wsrc = wpk + ((size_t)(mb * 4 + wv) * 64 + l) * 8;

    for (int icc = 0; icc < 8; ++icc) {
      __syncthreads();
#pragma unroll
      for (int it = 0; it < NIT; ++it)
        gload_lds16(inptr[it] + icc * 32, &tin[(size_t)(it * 256 + t) * 8]);
#pragma unroll
      for (int tap = 0; tap < 9; ++tap)
        gload_lds16(wsrc + ((size_t)tap * 8 + (size_t)icc) * 8192,
                    &wlds[(size_t)(tap * 256 + t) * 8]);
      __syncthreads();

      __builtin_amdgcn_s_setprio(1);
#pragma unroll
      for (int tap = 0; tap < 9; ++tap) {
        const int dy = tap / 3, dx = tap - 3 * (tap / 3);
        bf16x8 af[4];
#pragma unroll
        for (int mi = 0; mi < 4; mi++)
          af[mi] = *(const bf16x8*)&wlds[(size_t)((tap * 4 + mi) * 64 + l) * 8];
#pragma unroll
        for (int nf = 0; nf < 4; nf++) {
          int pl = wv * 64 + nf * 16 + l15;
          int py = pl >> LW;
          int c = pl & (W - 1);
          int tcol = c + dx;
          int idx16 = ((py + dy) * Cw + tcol) * 4 + (l4 ^ (tcol & 3));
          bf16x8 bfv = *(const bf16x8*)&tin[(size_t)idx16 * 8];
#pragma unroll
          for (int mi = 0; mi < 4; mi++)
            acc[mi][nf] = __builtin_amdgcn_mfma_f32_16x16x32_bf16(af[mi], bfv, acc[mi][nf], 0, 0, 0);
        }
      }
      __builtin_amdgcn_s_setprio(0);
    }
  }

  // epilogue
#pragma unroll
  for (int mi = 0; mi < 4; mi++) {
    int oc0 = mb * 64 + mi * 16 + l4 * 4;
    float bv[4];
#pragma unroll
    for (int rr = 0; rr < 4; rr++) bv[rr] = bias ? bias[oc0 + rr] : 0.f;
#pragma unroll
    for (int nf = 0; nf < 4; nf++) {
      int p = pixbase + wv * 64 + nf * 16 + l15;
      if (NCHWOUT) {
        float* o = (float*)outp;
        int pin = p & (HW - 1);
        int bb2 = p >> (2 * LW);
        int yy = pin >> LW, xx = pin & (W - 1);
        int ph = ((yy & 1) << 1) | (xx & 1);
        int q = (yy >> 1) * (W / 2) + (xx >> 1);
#pragma unroll
        for (int rr = 0; rr < 4; rr++) {
          float v = acc[mi][nf][rr] + bv[rr];
          if (ACC)
            v += bf2f(accsrc[((size_t)(bb2 * CDIM + oc0 + rr) * 4 + ph) * (HW / 4) + q]);
          o[((size_t)(bb2 * CDIM + oc0 + rr)) * HW + pin] = lrelu(v);
        }
      } else {
        unsigned short* o = (unsigned short*)outp;
        ushort4 pkv;
        pkv.x = f2bf(lrelu(acc[mi][nf][0] + bv[0]));
        pkv.y = f2bf(lrelu(acc[mi][nf][1] + bv[1]));
        pkv.z = f2bf(lrelu(acc[mi][nf][2] + bv[2]));
        pkv.w = f2bf(lrelu(acc[mi][nf][3] + bv[3]));
        *(ushort4*)&o[(size_t)p * CDIM + oc0] = pkv;
      }
    }
  }
}

// ---------------- merged ada convs: lf [0,256) + hf [256,1280) ----------------
__global__ __launch_bounds__(256, 2) void k_ada(
    const unsigned short* __restrict__ yh, const unsigned short* __restrict__ yl,
    const unsigned short* __restrict__ pk_adah, const unsigned short* __restrict__ pk_adal,
    const float* __restrict__ ada_h_b, const float* __restrict__ ada_l_b,
    unsigned short* __restrict__ hfA, unsigned short* __restrict__ lfA) {
  __shared__ __align__(16) unsigned short tin[18432];   // max RCPAD*32 (LW=7: 576*32)
  __shared__ __align__(16) unsigned short wlds[18432];  // 9*4*64*8
  const int bid = blockIdx.x;
  if (bid < 256) {
    int wk = ((bid & 7) << 5) + (bid >> 3);             // nwg=256
    conv_body<6, false, false, false, false>(wk, tin, wlds, yl, nullptr, pk_adal, nullptr,
                                             ada_l_b, nullptr, lfA);
  } else {
    int h = bid - 256;
    int wk = ((h & 7) << 7) + (h >> 3);                 // nwg=1024
    conv_body<7, false, false, false, false>(wk, tin, wlds, yh, nullptr, pk_adah, nullptr,
                                             ada_h_b, nullptr, hfA);
  }
}

// ---------------- merged output convs: lf-dual [0,256) + hf-ACC [256,1280) ----------------
__global__ __launch_bounds__(256, 2) void k_out(
    const unsigned short* __restrict__ hfA, const unsigned short* __restrict__ lfA,
    const unsigned short* __restrict__ hfP,
    const unsigned short* __restrict__ pk_h2h, const unsigned short* __restrict__ pk_l2l,
    const unsigned short* __restrict__ pk_h2l, const unsigned short* __restrict__ phb,
    float* __restrict__ out_hf, float* __restrict__ out_lf) {
  __shared__ __align__(16) unsigned short tin[18432];
  __shared__ __align__(16) unsigned short wlds[18432];
  const int bid = blockIdx.x;
  if (bid < 256) {
    int wk = ((bid & 7) << 5) + (bid >> 3);
    conv_body<6, true, false, true, false>(wk, tin, wlds, lfA, hfP, pk_l2l, pk_h2l,
                                           nullptr, nullptr, out_lf);
  } else {
    int h = bid - 256;
    int wk = ((h & 7) << 7) + (h >> 3);
    conv_body<7, false, false, true, true>(wk, tin, wlds, hfA, nullptr, pk_h2h, nullptr,
                                           nullptr, phb, out_hf);
  }
}

// ---------------- merged conv_up [0,1024) + avgpool [1024,3072) ----------------
__global__ __launch_bounds__(256) void k_up_pool(
    const unsigned short* __restrict__ lf, const unsigned short* __restrict__ wph,
    unsigned short* __restrict__ phb,
    const unsigned short* __restrict__ hfA, unsigned short* __restrict__ hfP) {
  __shared__ __align__(16) unsigned short tin[10240];   // 320 slots x 32ic
  __shared__ __align__(16) unsigned short wlds[8192];   // 4 taps x 256 x 8

  const int bid = blockIdx.x;
  const int t = threadIdx.x;

  if (bid >= 1024) {
    // ---- 2x2 avg pool on NHWC bf16 ----
    int i = (bid - 1024) * 256 + t;
    int cg = i & 31;
    int p = i >> 5;
    int X = p & 63, Y = (p >> 6) & 63, b = p >> 12;
    const unsigned short* s =
        hfA + ((size_t)(b * 128 + 2 * Y) * 128 + 2 * X) * CDIM + cg * 8;
    u16x8 v0 = *(const u16x8*)(s);
    u16x8 v1 = *(const u16x8*)(s + CDIM);
    u16x8 v2 = *(const u16x8*)(s + 128 * CDIM);
    u16x8 v3 = *(const u16x8*)(s + 128 * CDIM + CDIM);
    u16x8 r;
#pragma unroll
    for (int j = 0; j < 8; j++)
      r[j] = f2bf(0.25f * (bf2f(v0[j]) + bf2f(v1[j]) + bf2f(v2[j]) + bf2f(v3[j])));
    *(u16x8*)(hfP + (size_t)p * CDIM + cg * 8) = r;
    return;
  }

  // ---- phase-collapsed upsample-conv ----
  constexpr int NIT = 5;
  const int l = t & 63, wv = t >> 6;
  const int l15 = l & 15, l4 = l >> 4;

  const int wk = ((bid & 7) << 7) + (bid >> 3);   // nwg = 1024
  const int mb = wk & 3;
  const int phase = (wk >> 2) & 3;
  const int tile = (wk >> 4) & 15;
  const int b = wk >> 8;
  const int a = phase >> 1, bp = phase & 1;
  const int Y0 = tile * 4;

  f32x4 acc[4][4];
#pragma unroll
  for (int mi = 0; mi < 4; mi++)
#pragma unroll
    for (int nf = 0; nf < 4; nf++) acc[mi][nf] = (f32x4){0.f, 0.f, 0.f, 0.f};

  const unsigned short* inptr[NIT];
#pragma unroll
  for (int it = 0; it < NIT; ++it) {
    int s = it * 64 + (t >> 2);
    int row = s >> 6, col = s & 63;
    int ly = Y0 - 1 + a + row;
    ly = ly < 0 ? 0 : (ly > 63 ? 63 : ly);
    int gsrc = (t & 3) ^ (col & 3);
    inptr[it] = lf + (((size_t)(b * 64 + ly) * 64 + col) * CDIM + gsrc * 8);
  }
  const unsigned short* wsrc = wph + ((size_t)(mb * 4 + wv) * 64 + l) * 8;

  for (int icc = 0; icc < 8; ++icc) {
    __syncthreads();
#pragma unroll
    for (int it = 0; it < NIT; ++it)
      gload_lds16(inptr[it] + icc * 32, &tin[(size_t)(it * 256 + t) * 8]);
#pragma unroll
    for (int tap = 0; tap < 4; ++tap)
      gload_lds16(wsrc + ((size_t)(phase * 4 + tap) * 8 + (size_t)icc) * 8192,
                  &wlds[(size_t)(tap * 256 + t) * 8]);
    __syncthreads();

    __builtin_amdgcn_s_setprio(1);
#pragma unroll
    for (int tap = 0; tap < 4; ++tap) {
      const int ty = tap >> 1, tx = tap & 1;
      bf16x8 af[4];
#pragma unroll
      for (int mi = 0; mi < 4; mi++)
        af[mi] = *(const bf16x8*)&wlds[(size_t)((tap * 4 + mi) * 64 + l) * 8];
#pragma unroll
      for (int nf = 0; nf < 4; nf++) {
        int pl = wv * 64 + nf * 16 + l15;
        int py = pl >> 6;
        int col = pl & 63;
        int tcol = col - 1 + bp + tx;
        tcol = tcol < 0 ? 0 : (tcol > 63 ? 63 : tcol);
        int idx16 = ((py + ty) * 64 + tcol) * 4 + (l4 ^ (tcol & 3));
        bf16x8 bfv = *(const bf16x8*)&tin[(size_t)idx16 * 8];
#pragma unroll
        for (int mi = 0; mi < 4; mi++)
          acc[mi][nf] = __builtin_amdgcn_mfma_f32_16x16x32_bf16(af[mi], bfv, acc[mi][nf], 0, 0, 0);
      }
    }
    __builtin_amdgcn_s_setprio(0);
  }

#pragma unroll
  for (int mi = 0; mi < 4; mi++) {
    int oc0 = mb * 64 + mi * 16 + l4 * 4;
#pragma unroll
    for (int nf = 0; nf < 4; nf++) {
      int pl = wv * 64 + nf * 16 + l15;
      int py = pl >> 6, col = pl & 63;
      size_t base = ((size_t)(b * CDIM + oc0) * 4 + phase) * 4096 + (Y0 + py) * 64 + col;
#pragma unroll
      for (int rr = 0; rr < 4; rr++)
        phb[base + (size_t)rr * 4 * 4096] = f2bf(acc[mi][nf][rr]);
    }
  }
}

// ---------------- host ----------------
extern "C" void kernel_launch(void* const* d_in, const int* in_sizes, int n_in,
                              void* d_out, int out_size, void* d_ws, size_t ws_size,
                              hipStream_t stream) {
  (void)in_sizes; (void)n_in; (void)out_size;
  const float* c_hf = (const float*)d_in[0];
  const float* c_lf = (const float*)d_in[1];
  const float* s_hf = (const float*)d_in[2];
  const float* s_lf = (const float*)d_in[3];
  const float* h_sw = (const float*)d_in[4];
  const float* h_sb = (const float*)d_in[5];
  const float* h_pw = (const float*)d_in[6];
  const float* h_pb = (const float*)d_in[7];
  const float* h_bw = (const float*)d_in[8];
  const float* h_bb = (const float*)d_in[9];
  const float* l_sw = (const float*)d_in[10];
  const float* l_sb = (const float*)d_in[11];
  const float* l_pw = (const float*)d_in[12];
  const float* l_pb = (const float*)d_in[13];
  const float* l_bw = (const float*)d_in[14];
  const float* l_bb = (const float*)d_in[15];
  const float* ada_h_w = (const float*)d_in[16];
  const float* ada_h_b = (const float*)d_in[17];
  const float* ada_l_w = (const float*)d_in[18];
  const float* ada_l_b = (const float*)d_in[19];
  const float* h2h = (const float*)d_in[20];
  const float* l2h = (const float*)d_in[21];
  const float* h2l = (const float*)d_in[22];
  const float* l2l = (const float*)d_in[23];

  float* base;
  size_t need = (size_t)TOTAL_F * sizeof(float);
  if (ws_size >= need) {
    base = (float*)d_ws;
  } else {
    void* p = nullptr;
    hipGetSymbolAddress(&p, HIP_SYMBOL(g_scratch));
    base = (float*)p;
  }

  float* ws_hf = base + OFF_WS_HF;
  float* ws_lf = base + OFF_WS_LF;
  float* wp_hf = base + OFF_WP_HF;
  float* bs_hf = base + OFF_BS_HF;
  float* wp_lf = base + OFF_WP_LF;
  float* bs_lf = base + OFF_BS_LF;
  float* mean_hf = base + OFF_MEAN_HF;
  float* rstd_hf = base + OFF_RSTD_HF;
  float* mean_lf = base + OFF_MEAN_LF;
  float* rstd_lf = base + OFF_RSTD_LF;
  unsigned short* u16 = (unsigned short*)(base + OFF_U16);
  unsigned short* yh = u16 + U_YH;
  unsigned short* yl = u16 + U_YL;
  unsigned short* hfA = u16 + U_HFA;
  unsigned short* lfA = u16 + U_LFA;
  unsigned short* hfP = u16 + U_HFP;
  unsigned short* pk      = u16 + U_PK;
  unsigned short* pk_adah = pk + 0 * PK_SZ;
  unsigned short* pk_h2h  = pk + 1 * PK_SZ;
  unsigned short* pk_adal = pk + 3 * PK_SZ;
  unsigned short* pk_l2l  = pk + 4 * PK_SZ;
  unsigned short* pk_h2l  = pk + 5 * PK_SZ;
  unsigned short* pk_ph   = u16 + U_PKPH;
  unsigned short* phb     = u16 + U_PHB;

  float* out_hf = (float*)d_out;
  float* out_lf = (float*)d_out + 16777216;

  // prep: all weight packing + ws + istats + point in one launch
  k_prep<<<dim3(28680), dim3(256), 0, stream>>>(
      ada_h_w, h2h, ada_l_w, l2l, h2l, l2h, pk, pk_ph,
      s_hf, h_sw, h_sb, ws_hf, s_lf, l_sw, l_sb, ws_lf,
      h_pw, h_pb, h_bw, h_bb, wp_hf, bs_hf,
      l_pw, l_pb, l_bw, l_bb, wp_lf, bs_lf,
      c_hf, mean_hf, rstd_hf, c_lf, mean_lf, rstd_lf);

  // fused IN + depthwise + pointwise -> NHWC bf16 (hf + lf)
  k_dwt_all<<<dim3(5120), dim3(256), 0, stream>>>(
      c_hf, ws_hf, mean_hf, rstd_hf, wp_hf, bs_hf, yh,
      c_lf, ws_lf, mean_lf, rstd_lf, wp_lf, bs_lf, yl);

  // ada convs (lf + hf merged)
  k_ada<<<dim3(1280), dim3(256), 0, stream>>>(yh, yl, pk_adah, pk_adal, ada_h_b, ada_l_b,
                                              hfA, lfA);

  // conv_up + avgpool merged
  k_up_pool<<<dim3(3072), dim3(256), 0, stream>>>(lfA, pk_ph, phb, hfA, hfP);

  // output convs (lf-dual + hf-ACC merged)
  k_out<<<dim3(1280), dim3(256), 0, stream>>>(hfA, lfA, hfP, pk_h2h, pk_l2l, pk_h2l, phb,
                                              out_hf, out_lf);
}

// Round 16
// 334.123 us; speedup vs baseline: 1.1856x; 1.0072x over previous
//
#include <hip/hip_runtime.h>
#include <hip/hip_bf16.h>

#define CDIM 256
#define EPS 1e-5f
#define SLOPE 0.01f

using f32x4  = __attribute__((ext_vector_type(4))) float;
typedef __bf16 bf16x8 __attribute__((ext_vector_type(8)));
typedef unsigned short u16x8 __attribute__((ext_vector_type(8)));

// ---------------- workspace layout ----------------
enum : size_t {
  OFF_WS_HF   = 0,
  OFF_WS_LF   = 9216,
  OFF_WP_HF   = 20480,
  OFF_BS_HF   = 21504,
  OFF_WP_LF   = 22528,
  OFF_BS_LF   = 23552,
  OFF_MEAN_HF = 24576,
  OFF_RSTD_HF = 25600,
  OFF_MEAN_LF = 26624,
  OFF_RSTD_LF = 27648,
  OFF_U16     = 32768,          // start of ushort region (float units)
};
// ushort offsets relative to u16 base
enum : size_t {
  U_YH  = 0,          // [4][128][128][256] bf16
  U_YL  = 16777216,   // [4][64][64][256]
  U_HFA = 20971520,   // [4][128][128][256]
  U_LFA = 37748736,   // [4][64][64][256]
  U_HFP = 41943040,   // [4][64][64][256]
  U_PK  = 46137344,   // 6 packed weight slots, each 589824 (slot2 unused)
  PK_SZ = 589824,
  U_PKPH = U_PK + 6 * PK_SZ,    // phase-packed l2h: 4ph x 4tap x 8icc x 16mf x 64 x 8
  PH_SZ  = 1048576,
  U_PHB  = U_PKPH + PH_SZ,      // phase buffer [4][256][4][64][64] bf16
  U_END  = U_PHB + 16777216,
};
enum : size_t { TOTAL_F = OFF_U16 + (U_END + 1) / 2 };

__device__ float g_scratch[TOTAL_F];

__device__ __forceinline__ int refl(int q, int n) {
  return q < 0 ? -q : (q >= n ? 2 * n - 2 - q : q);
}
__device__ __forceinline__ float lrelu(float v) { return v >= 0.f ? v : SLOPE * v; }
__device__ __forceinline__ unsigned short f2bf(float f) {
  unsigned int u = __float_as_uint(f);
  u += 0x7fffu + ((u >> 16) & 1u);
  return (unsigned short)(u >> 16);
}
__device__ __forceinline__ float bf2f(unsigned short h) {
  return __uint_as_float(((unsigned int)h) << 16);
}
__device__ __forceinline__ void gload_lds16(const void* g, void* l) {
  __builtin_amdgcn_global_load_lds(
      (const __attribute__((address_space(1))) unsigned int*)g,
      (__attribute__((address_space(3))) unsigned int*)l, 16, 0, 0);
}

// ---------------- fused prep: packall [0,24576) | ws | istats | point ----------
__global__ __launch_bounds__(256) void k_prep(
    const float* __restrict__ w_adah, const float* __restrict__ w_h2h,
    const float* __restrict__ w_adal, const float* __restrict__ w_l2l,
    const float* __restrict__ w_h2l, const float* __restrict__ w_l2h,
    unsigned short* __restrict__ pk, unsigned short* __restrict__ pkph,
    const float* __restrict__ s_hf, const float* __restrict__ sw_hf,
    const float* __restrict__ sb_hf, float* __restrict__ ws_hf,
    const float* __restrict__ s_lf, const float* __restrict__ sw_lf,
    const float* __restrict__ sb_lf, float* __restrict__ ws_lf,
    const float* __restrict__ pw_hf, const float* __restrict__ pb_hf,
    const float* __restrict__ bw_hf, const float* __restrict__ bb_hf,
    float* __restrict__ wp_hf, float* __restrict__ bs_hf,
    const float* __restrict__ pw_lf, const float* __restrict__ pb_lf,
    const float* __restrict__ bw_lf, const float* __restrict__ bb_lf,
    float* __restrict__ wp_lf, float* __restrict__ bs_lf,
    const float* __restrict__ c_hf, float* __restrict__ mean_hf, float* __restrict__ rstd_hf,
    const float* __restrict__ c_lf, float* __restrict__ mean_lf, float* __restrict__ rstd_lf) {
  __shared__ float sh[256 * 9];
  const int bid = blockIdx.x;
  const int t = threadIdx.x;

  if (bid < 24576) {
    // ---- weight packing ----
    int seg = bid >> 12;                       // 0..5
    int i = ((bid & 4095) << 8) + t;
    if (seg < 5) {
      if (i >= 589824) return;
      const float* srcs[5] = {w_adah, w_h2h, w_adal, w_l2l, w_h2l};
      const int slot[5] = {0, 1, 3, 4, 5};
      const float* w = srcs[seg];
      int j = i & 7, l = (i >> 3) & 63, mf = (i >> 9) & 15, icc = (i >> 13) & 7, tap = i >> 16;
      int oc = mf * 16 + (l & 15);
      int ic = icc * 32 + (l >> 4) * 8 + j;
      pk[(size_t)slot[seg] * PK_SZ + i] = f2bf(w[((size_t)oc * 256 + ic) * 9 + tap]);
    } else {
      int j = i & 7, l = (i >> 3) & 63, mf = (i >> 9) & 15, icc = (i >> 13) & 7, tapph = i >> 16;
      int tap = tapph & 3, phase = tapph >> 2;
      int tx = tap & 1, ty = tap >> 1;
      int a = phase >> 1, bp = phase & 1;
      int oc = mf * 16 + (l & 15);
      int ic = icc * 32 + (l >> 4) * 8 + j;
      int ys = (a == 0) ? (ty == 0 ? 0 : 1) : (ty == 0 ? 0 : 2);
      int yc = (a == 0) ? (ty == 0 ? 1 : 2) : (ty == 0 ? 2 : 1);
      int xs = (bp == 0) ? (tx == 0 ? 0 : 1) : (tx == 0 ? 0 : 2);
      int xc = (bp == 0) ? (tx == 0 ? 1 : 2) : (tx == 0 ? 2 : 1);
      const float* wb = w_l2h + ((size_t)oc * 256 + ic) * 9;
      float acc = 0.f;
      for (int dy = ys; dy < ys + yc; dy++)
        for (int dx = xs; dx < xs + xc; dx++) acc += wb[dy * 3 + dx];
      pkph[i] = f2bf(acc);
    }
    return;
  }

  const int bx = bid - 24576;                  // 0..4103
  if (bx < 2048) {
    // ---- spatial weights ws = conv(rpad(s,1), sw) + sb ----
    const bool lf = bx >= 1024;
    const int bo = bx & 1023;
    const float* s  = lf ? s_lf : s_hf;
    const float* sw = lf ? sw_lf : sw_hf;
    const float* sb = lf ? sb_lf : sb_hf;
    float* ws_out   = lf ? ws_lf : ws_hf;
    int o = bo & (CDIM - 1);
    int c = t;
    int b = bo >> 8;
    float sv[9], wv[9];
    const float* sp = s + (size_t)(b * CDIM + c) * 9;
    const float* wp = sw + (size_t)(o * CDIM + c) * 9;
#pragma unroll
    for (int i = 0; i < 9; i++) { sv[i] = sp[i]; wv[i] = wp[i]; }
    float out9[9];
#pragma unroll
    for (int i = 0; i < 3; i++)
#pragma unroll
      for (int j = 0; j < 3; j++) {
        float a = 0.f;
#pragma unroll
        for (int dy = 0; dy < 3; dy++) {
          int u = i + dy - 1; u = (u < 0) ? 1 : (u > 2 ? 1 : u);
#pragma unroll
          for (int dx = 0; dx < 3; dx++) {
            int v = j + dx - 1; v = (v < 0) ? 1 : (v > 2 ? 1 : v);
            a += sv[u * 3 + v] * wv[dy * 3 + dx];
          }
        }
        out9[i * 3 + j] = a;
      }
#pragma unroll
    for (int i = 0; i < 9; i++) sh[c * 9 + i] = out9[i];
    __syncthreads();
    for (int st = 128; st > 0; st >>= 1) {
      if (c < st)
#pragma unroll
        for (int i = 0; i < 9; i++) sh[c * 9 + i] += sh[(c + st) * 9 + i];
      __syncthreads();
    }
    if (c < 9) ws_out[(size_t)bo * 9 + c] = sh[c] + sb[o];

  } else if (bx < 4096) {
    // ---- instance norm stats ----
    const int idx = bx - 2048;
    const bool lf = idx >= 1024;
    int plane = lf ? idx - 1024 : idx;
    const float* x = lf ? c_lf : c_hf;
    float* mean = lf ? mean_lf : mean_hf;
    float* rstd = lf ? rstd_lf : rstd_hf;
    const int HW = lf ? 4096 : 16384;
    const float4* p = (const float4*)(x + (size_t)plane * HW);
    int n4 = HW >> 2;
    float s = 0.f, q = 0.f;
    for (int i = t; i < n4; i += 256) {
      float4 v = p[i];
      s += v.x + v.y + v.z + v.w;
      q += v.x * v.x + v.y * v.y + v.z * v.z + v.w * v.w;
    }
    float* rs = sh;
    float* rq = sh + 256;
    rs[t] = s; rq[t] = q;
    __syncthreads();
    for (int st = 128; st > 0; st >>= 1) {
      if (t < st) { rs[t] += rs[t + st]; rq[t] += rq[t + st]; }
      __syncthreads();
    }
    if (t == 0) {
      float m = rs[0] / HW;
      float v = rq[0] / HW - m * m;
      mean[plane] = m;
      rstd[plane] = rsqrtf(v + EPS);
    }

  } else {
    // ---- pooled + w_point / bias ----
    const int idx = bx - 4096;
    const bool lf = (idx >> 2) != 0;
    const int b = idx & 3;
    const float* s  = lf ? s_lf : s_hf;
    const float* pw = lf ? pw_lf : pw_hf;
    const float* pb = lf ? pb_lf : pb_hf;
    const float* bw = lf ? bw_lf : bw_hf;
    const float* bb = lf ? bb_lf : bb_hf;
    float* wp_out = lf ? wp_lf : wp_hf;
    float* bs_out = lf ? bs_lf : bs_hf;
    const int o = t;
    float* pl = sh;
    const float* sp = s + (size_t)(b * CDIM + o) * 9;
    float a9 = 0.f;
#pragma unroll
    for (int j = 0; j < 9; j++) a9 += sp[j];
    pl[o] = a9 * (1.f / 9.f);
    __syncthreads();
    float a = pb[o], d = bb[o];
    const float4* pw4 = (const float4*)(pw + (size_t)o * CDIM);
    const float4* bw4 = (const float4*)(bw + (size_t)o * CDIM);
    const float4* pl4 = (const float4*)pl;
    for (int c4 = 0; c4 < CDIM / 4; c4++) {
      float4 p = pl4[c4];
      float4 w1 = pw4[c4], w2 = bw4[c4];
      a += p.x * w1.x + p.y * w1.y + p.z * w1.z + p.w * w1.w;
      d += p.x * w2.x + p.y * w2.y + p.z * w2.z + p.w * w2.w;
    }
    wp_out[b * CDIM + o] = a;
    bs_out[b * CDIM + o] = d;
  }
}

// ---------------- fused IN + dynamic depthwise + pointwise -> NHWC bf16 (hf+lf merged) ----------
__global__ __launch_bounds__(256) void k_dwt_all(
    const float* __restrict__ xh, const float* __restrict__ wsh,
    const float* __restrict__ mh, const float* __restrict__ rh,
    const float* __restrict__ wph, const float* __restrict__ bsh,
    unsigned short* __restrict__ outh,
    const float* __restrict__ xl, const float* __restrict__ wsl,
    const float* __restrict__ ml, const float* __restrict__ rl,
    const float* __restrict__ wpl, const float* __restrict__ bsl,
    unsigned short* __restrict__ outl) {
  const int bid = blockIdx.x;
  const bool lf = bid >= 4096;
  const int W = lf ? 64 : 128;
  const int H = W, HW = W * W;
  const float *x, *ws, *mean, *rstd, *wp, *bs;
  unsigned short* out;
  int xt, icb, y, b;
  if (!lf) {
    x = xh; ws = wsh; mean = mh; rstd = rh; wp = wph; bs = bsh; out = outh;
    int x8 = bid & 7; xt = x8 & 1; icb = x8 >> 1; y = (bid >> 3) & 127; b = bid >> 10;
  } else {
    int local = bid - 4096;
    x = xl; ws = wsl; mean = ml; rstd = rl; wp = wpl; bs = bsl; out = outl;
    xt = 0; icb = local & 3; y = (local >> 2) & 63; b = local >> 8;
  }
  const int t = threadIdx.x;
  __shared__ unsigned short tr[64][66];
  const int xg = t & 15;
  const int chq = t >> 4;
  const int x0 = xt * 64 + xg * 4;
  const int sy0 = refl(y - 1, H), sy2 = refl(y + 1, H);
  const int xm = refl(x0 - 1, W);
  const int xq = refl(x0 + 4, W);
#pragma unroll
  for (int rr = 0; rr < 4; ++rr) {
    int icl = rr * 16 + chq;
    int plane = b * CDIM + icb * 64 + icl;
    const float* xpb = x + (size_t)plane * HW;
    float m = mean[plane], r = rstd[plane], sc = wp[plane], bi = bs[plane];
    const float* w9p = ws + (size_t)plane * 9;
    float w9[9];
#pragma unroll
    for (int i = 0; i < 9; i++) w9[i] = w9p[i];
    float sumw = w9[0] + w9[1] + w9[2] + w9[3] + w9[4] + w9[5] + w9[6] + w9[7] + w9[8];
    const float* r0 = xpb + sy0 * W;
    const float* r1 = xpb + y * W;
    const float* r2 = xpb + sy2 * W;
    float4 v0 = *(const float4*)(r0 + x0);
    float4 v1 = *(const float4*)(r1 + x0);
    float4 v2 = *(const float4*)(r2 + x0);
    float e0[6] = {r0[xm], v0.x, v0.y, v0.z, v0.w, r0[xq]};
    float e1[6] = {r1[xm], v1.x, v1.y, v1.z, v1.w, r1[xq]};
    float e2[6] = {r2[xm], v2.x, v2.y, v2.z, v2.w, r2[xq]};
    float mterm = m * sumw;
#pragma unroll
    for (int j = 0; j < 4; ++j) {
      float a = w9[0] * e0[j] + w9[1] * e0[j + 1] + w9[2] * e0[j + 2] +
                w9[3] * e1[j] + w9[4] * e1[j + 1] + w9[5] * e1[j + 2] +
                w9[6] * e2[j] + w9[7] * e2[j + 1] + w9[8] * e2[j + 2];
      a -= mterm;
      tr[icl][xg * 4 + j] = f2bf(a * r * sc + bi);
    }
  }
  __syncthreads();
#pragma unroll
  for (int it2 = 0; it2 < 2; ++it2) {
    int s2 = it2 * 256 + t;
    int xl2 = s2 >> 3;
    int cg = s2 & 7;
    u16x8 v;
#pragma unroll
    for (int j = 0; j < 8; j++) v[j] = tr[cg * 8 + j][xl2];
    *(u16x8*)&out[((size_t)((b * H + y) * W + xt * 64 + xl2)) * CDIM + icb * 64 + cg * 8] = v;
  }
}

// ---------------- conv body (R5/R11 structure + ACC + optional fused 2x2 pool) ----------------
template <int LW, bool DUAL, bool UPSB, bool NCHWOUT, bool ACC, bool POOL>
__device__ __forceinline__ void conv_body(
    int wk, unsigned short* tin, unsigned short* wlds,
    const unsigned short* __restrict__ srcA, const unsigned short* __restrict__ srcB,
    const unsigned short* __restrict__ wpkA, const unsigned short* __restrict__ wpkB,
    const float* __restrict__ bias, const unsigned short* __restrict__ accsrc,
    void* __restrict__ outp, unsigned short* __restrict__ pool_dst) {
  constexpr int W = 1 << LW, H = W, HW = W * W;
  constexpr int ROWS = 256 >> LW;
  constexpr int R = ROWS + 2, Cw = W + 2;
  constexpr int RC = R * Cw;
  constexpr int RCPAD = (RC + 63) & ~63;
  constexpr int NIT = RCPAD / 64;

  const int t = threadIdx.x;
  const int l = t & 63, wv = t >> 6;
  const int l15 = l & 15, l4 = l >> 4;

  const int mb = wk & 3;
  const int pixbase = (wk >> 2) * 256;
  const int b = pixbase >> (2 * LW);
  const int y0 = (pixbase >> LW) & (H - 1);

  f32x4 acc[4][4];
#pragma unroll
  for (int mi = 0; mi < 4; mi++)
#pragma unroll
    for (int nf = 0; nf < 4; nf++) acc[mi][nf] = (f32x4){0.f, 0.f, 0.f, 0.f};

  const int nsrc = DUAL ? 2 : 1;
  for (int src = 0; src < nsrc; ++src) {
    const unsigned short* ysrc = src ? srcB : srcA;
    const unsigned short* wpk = src ? wpkB : wpkA;
    const bool ups = UPSB && (src == 1);

    const unsigned short* inptr[NIT];
#pragma unroll
    for (int it = 0; it < NIT; ++it) {
      int rc = it * 64 + (t >> 2);
      int rcc = rc < RC - 1 ? rc : RC - 1;
      int r = rcc / Cw, tc = rcc - r * Cw;
      int gy = refl(y0 - 1 + r, H);
      int gx = refl(tc - 1, W);
      int sy, sx, sw;
      if (ups) { sy = gy >> 1; sx = gx >> 1; sw = W >> 1; }
      else     { sy = gy;      sx = gx;      sw = W; }
      int gsrc = (t & 3) ^ (tc & 3);
      inptr[it] = ysrc + (((size_t)(b * sw + sy) * sw + sx) * CDIM + gsrc * 8);
    }
    const unsigned short* wsrc = wpk + ((size_t)(mb * 4 + wv) * 64 + l) * 8;

    for (int icc = 0; icc < 8; ++icc) {
      __syncthreads();
#pragma unroll
      for (int it = 0; it < NIT; ++it)
        gload_lds16(inptr[it] + icc * 32, &tin[(size_t)(it * 256 + t) * 8]);
#pragma unroll
      for (int tap = 0; tap < 9; ++tap)
        gload_lds16(wsrc + ((size_t)tap * 8 + (size_t)icc) * 8192,
                    &wlds[(size_t)(tap * 256 + t) * 8]);
      __syncthreads();

      __builtin_amdgcn_s_setprio(1);
#pragma unroll
      for (int tap = 0; tap < 9; ++tap) {
        const int dy = tap / 3, dx = tap - 3 * (tap / 3);
        bf16x8 af[4];
#pragma unroll
        for (int mi = 0; mi < 4; mi++)
          af[mi] = *(const bf16x8*)&wlds[(size_t)((tap * 4 + mi) * 64 + l) * 8];
#pragma unroll
        for (int nf = 0; nf < 4; nf++) {
          int pl = wv * 64 + nf * 16 + l15;
          int py = pl >> LW;
          int c = pl & (W - 1);
          int tcol = c + dx;
          int idx16 = ((py + dy) * Cw + tcol) * 4 + (l4 ^ (tcol & 3));
          bf16x8 bfv = *(const bf16x8*)&tin[(size_t)idx16 * 8];
#pragma unroll
          for (int mi = 0; mi < 4; mi++)
            acc[mi][nf] = __builtin_amdgcn_mfma_f32_16x16x32_bf16(af[mi], bfv, acc[mi][nf], 0, 0, 0);
        }
      }
      __builtin_amdgcn_s_setprio(0);
    }
  }

  if (POOL) __syncthreads();   // all waves done reading tin before reuse as pool stage

  // epilogue
#pragma unroll
  for (int mi = 0; mi < 4; mi++) {
    int oc0 = mb * 64 + mi * 16 + l4 * 4;
    float bv[4];
#pragma unroll
    for (int rr = 0; rr < 4; rr++) bv[rr] = bias ? bias[oc0 + rr] : 0.f;
#pragma unroll
    for (int nf = 0; nf < 4; nf++) {
      int p = pixbase + wv * 64 + nf * 16 + l15;
      if (NCHWOUT) {
        float* o = (float*)outp;
        int pin = p & (HW - 1);
        int bb2 = p >> (2 * LW);
        int yy = pin >> LW, xx = pin & (W - 1);
        int ph = ((yy & 1) << 1) | (xx & 1);
        int q = (yy >> 1) * (W / 2) + (xx >> 1);
#pragma unroll
        for (int rr = 0; rr < 4; rr++) {
          float v = acc[mi][nf][rr] + bv[rr];
          if (ACC)
            v += bf2f(accsrc[((size_t)(bb2 * CDIM + oc0 + rr) * 4 + ph) * (HW / 4) + q]);
          o[((size_t)(bb2 * CDIM + oc0 + rr)) * HW + pin] = lrelu(v);
        }
      } else {
        unsigned short* o = (unsigned short*)outp;
        ushort4 pkv;
        pkv.x = f2bf(lrelu(acc[mi][nf][0] + bv[0]));
        pkv.y = f2bf(lrelu(acc[mi][nf][1] + bv[1]));
        pkv.z = f2bf(lrelu(acc[mi][nf][2] + bv[2]));
        pkv.w = f2bf(lrelu(acc[mi][nf][3] + bv[3]));
        *(ushort4*)&o[(size_t)p * CDIM + oc0] = pkv;
        if (POOL) {
          // stage into LDS [py][col][64 oc_local] for fused 2x2 pool
          int pl = wv * 64 + nf * 16 + l15;
          int py = pl >> LW, col = pl & (W - 1);
          int ocl = mi * 16 + l4 * 4;
          *(ushort4*)&tin[(size_t)((py * W + col) * 64 + ocl)] = pkv;
        }
      }
    }
  }

  if (POOL) {
    __syncthreads();
    const int Y = y0 >> 1;
#pragma unroll
    for (int j = 0; j < 16; ++j) {
      int f = j * 256 + t;              // 0..4095
      int X = f >> 6, ocl = f & 63;
      float v = 0.25f * (bf2f(tin[((0 * W + 2 * X) * 64 + ocl)]) +
                         bf2f(tin[((0 * W + 2 * X + 1) * 64 + ocl)]) +
                         bf2f(tin[((1 * W + 2 * X) * 64 + ocl)]) +
                         bf2f(tin[((1 * W + 2 * X + 1) * 64 + ocl)]));
      pool_dst[((size_t)((b * 64 + Y) * 64 + X)) * CDIM + mb * 64 + ocl] = f2bf(v);
    }
  }
}

// ---------------- merged ada convs: lf [0,256) + hf(+fused pool) [256,1280) ----------------
__global__ __launch_bounds__(256, 2) void k_ada(
    const unsigned short* __restrict__ yh, const unsigned short* __restrict__ yl,
    const unsigned short* __restrict__ pk_adah, const unsigned short* __restrict__ pk_adal,
    const float* __restrict__ ada_h_b, const float* __restrict__ ada_l_b,
    unsigned short* __restrict__ hfA, unsigned short* __restrict__ lfA,
    unsigned short* __restrict__ hfP) {
  __shared__ __align__(16) unsigned short tin[18432];   // max RCPAD*32 (LW=7: 576*32)
  __shared__ __align__(16) unsigned short wlds[18432];  // 9*4*64*8
  const int bid = blockIdx.x;
  if (bid < 256) {
    int wk = ((bid & 7) << 5) + (bid >> 3);             // nwg=256
    conv_body<6, false, false, false, false, false>(wk, tin, wlds, yl, nullptr, pk_adal,
                                                    nullptr, ada_l_b, nullptr, lfA, nullptr);
  } else {
    int h = bid - 256;
    int wk = ((h & 7) << 7) + (h >> 3);                 // nwg=1024
    conv_body<7, false, false, false, false, true>(wk, tin, wlds, yh, nullptr, pk_adah,
                                                   nullptr, ada_h_b, nullptr, hfA, hfP);
  }
}

// ---------------- merged output convs: lf-dual [0,256) + hf-ACC [256,1280) ----------------
__global__ __launch_bounds__(256, 2) void k_out(
    const unsigned short* __restrict__ hfA, const unsigned short* __restrict__ lfA,
    const unsigned short* __restrict__ hfP,
    const unsigned short* __restrict__ pk_h2h, const unsigned short* __restrict__ pk_l2l,
    const unsigned short* __restrict__ pk_h2l, const unsigned short* __restrict__ phb,
    float* __restrict__ out_hf, float* __restrict__ out_lf) {
  __shared__ __align__(16) unsigned short tin[18432];
  __shared__ __align__(16) unsigned short wlds[18432];
  const int bid = blockIdx.x;
  if (bid < 256) {
    int wk = ((bid & 7) << 5) + (bid >> 3);
    conv_body<6, true, false, true, false, false>(wk, tin, wlds, lfA, hfP, pk_l2l, pk_h2l,
                                                  nullptr, nullptr, out_lf, nullptr);
  } else {
    int h = bid - 256;
    int wk = ((h & 7) << 7) + (h >> 3);
    conv_body<7, false, false, true, true, false>(wk, tin, wlds, hfA, nullptr, pk_h2h,
                                                  nullptr, nullptr, phb, out_hf, nullptr);
  }
}

// ---------------- phase-collapsed upsample-conv: 4-tap GEMM on lf grid ----------------
__global__ __launch_bounds__(256, 3) void k_up(
    const unsigned short* __restrict__ lf, const unsigned short* __restrict__ wph,
    unsigned short* __restrict__ phb) {
  constexpr int NIT = 5;
  __shared__ __align__(16) unsigned short tin[10240];   // 320 slots x 32ic
  __shared__ __align__(16) unsigned short wlds[8192];   // 4 taps x 256 x 8

  const int t = threadIdx.x;
  const int l = t & 63, wv = t >> 6;
  const int l15 = l & 15, l4 = l >> 4;

  const int hwid = blockIdx.x;
  const int wk = ((hwid & 7) << 7) + (hwid >> 3);   // nwg = 1024
  const int mb = wk & 3;
  const int phase = (wk >> 2) & 3;
  const int tile = (wk >> 4) & 15;
  const int b = wk >> 8;
  const int a = phase >> 1, bp = phase & 1;
  const int Y0 = tile * 4;

  f32x4 acc[4][4];
#pragma unroll
  for (int mi = 0; mi < 4; mi++)
#pragma unroll
    for (int nf = 0; nf < 4; nf++) acc[mi][nf] = (f32x4){0.f, 0.f, 0.f, 0.f};

  const unsigned short* inptr[NIT];
#pragma unroll
  for (int it = 0; it < NIT; ++it) {
    int s = it * 64 + (t >> 2);
    int row = s >> 6, col = s & 63;
    int ly = Y0 - 1 + a + row;
    ly = ly < 0 ? 0 : (ly > 63 ? 63 : ly);
    int gsrc = (t & 3) ^ (col & 3);
    inptr[it] = lf + (((size_t)(b * 64 + ly) * 64 + col) * CDIM + gsrc * 8);
  }
  const unsigned short* wsrc = wph + ((size_t)(mb * 4 + wv) * 64 + l) * 8;

  for (int icc = 0; icc < 8; ++icc) {
    __syncthreads();
#pragma unroll
    for (int it = 0; it < NIT; ++it)
      gload_lds16(inptr[it] + icc * 32, &tin[(size_t)(it * 256 + t) * 8]);
#pragma unroll
    for (int tap = 0; tap < 4; ++tap)
      gload_lds16(wsrc + ((size_t)(phase * 4 + tap) * 8 + (size_t)icc) * 8192,
                  &wlds[(size_t)(tap * 256 + t) * 8]);
    __syncthreads();

    __builtin_amdgcn_s_setprio(1);
#pragma unroll
    for (int tap = 0; tap < 4; ++tap) {
      const int ty = tap >> 1, tx = tap & 1;
      bf16x8 af[4];
#pragma unroll
      for (int mi = 0; mi < 4; mi++)
        af[mi] = *(const bf16x8*)&wlds[(size_t)((tap * 4 + mi) * 64 + l) * 8];
#pragma unroll
      for (int nf = 0; nf < 4; nf++) {
        int pl = wv * 64 + nf * 16 + l15;
        int py = pl >> 6;
        int col = pl & 63;
        int tcol = col - 1 + bp + tx;
        tcol = tcol < 0 ? 0 : (tcol > 63 ? 63 : tcol);
        int idx16 = ((py + ty) * 64 + tcol) * 4 + (l4 ^ (tcol & 3));
        bf16x8 bfv = *(const bf16x8*)&tin[(size_t)idx16 * 8];
#pragma unroll
        for (int mi = 0; mi < 4; mi++)
          acc[mi][nf] = __builtin_amdgcn_mfma_f32_16x16x32_bf16(af[mi], bfv, acc[mi][nf], 0, 0, 0);
      }
    }
    __builtin_amdgcn_s_setprio(0);
  }

#pragma unroll
  for (int mi = 0; mi < 4; mi++) {
    int oc0 = mb * 64 + mi * 16 + l4 * 4;
#pragma unroll
    for (int nf = 0; nf < 4; nf++) {
      int pl = wv * 64 + nf * 16 + l15;
      int py = pl >> 6, col = pl & 63;
      size_t base = ((size_t)(b * CDIM + oc0) * 4 + phase) * 4096 + (Y0 + py) * 64 + col;
#pragma unroll
      for (int rr = 0; rr < 4; rr++)
        phb[base + (size_t)rr * 4 * 4096] = f2bf(acc[mi][nf][rr]);
    }
  }
}

// ---------------- host ----------------
extern "C" void kernel_launch(void* const* d_in, const int* in_sizes, int n_in,
                              void* d_out, int out_size, void* d_ws, size_t ws_size,
                              hipStream_t stream) {
  (void)in_sizes; (void)n_in; (void)out_size;
  const float* c_hf = (const float*)d_in[0];
  const float* c_lf = (const float*)d_in[1];
  const float* s_hf = (const float*)d_in[2];
  const float* s_lf = (const float*)d_in[3];
  const float* h_sw = (const float*)d_in[4];
  const float* h_sb = (const float*)d_in[5];
  const float* h_pw = (const float*)d_in[6];
  const float* h_pb = (const float*)d_in[7];
  const float* h_bw = (const float*)d_in[8];
  const float* h_bb = (const float*)d_in[9];
  const float* l_sw = (const float*)d_in[10];
  const float* l_sb = (const float*)d_in[11];
  const float* l_pw = (const float*)d_in[12];
  const float* l_pb = (const float*)d_in[13];
  const float* l_bw = (const float*)d_in[14];
  const float* l_bb = (const float*)d_in[15];
  const float* ada_h_w = (const float*)d_in[16];
  const float* ada_h_b = (const float*)d_in[17];
  const float* ada_l_w = (const float*)d_in[18];
  const float* ada_l_b = (const float*)d_in[19];
  const float* h2h = (const float*)d_in[20];
  const float* l2h = (const float*)d_in[21];
  const float* h2l = (const float*)d_in[22];
  const float* l2l = (const float*)d_in[23];

  float* base;
  size_t need = (size_t)TOTAL_F * sizeof(float);
  if (ws_size >= need) {
    base = (float*)d_ws;
  } else {
    void* p = nullptr;
    hipGetSymbolAddress(&p, HIP_SYMBOL(g_scratch));
    base = (float*)p;
  }

  float* ws_hf = base + OFF_WS_HF;
  float* ws_lf = base + OFF_WS_LF;
  float* wp_hf = base + OFF_WP_HF;
  float* bs_hf = base + OFF_BS_HF;
  float* wp_lf = base + OFF_WP_LF;
  float* bs_lf = base + OFF_BS_LF;
  float* mean_hf = base + OFF_MEAN_HF;
  float* rstd_hf = base + OFF_RSTD_HF;
  float* mean_lf = base + OFF_MEAN_LF;
  float* rstd_lf = base + OFF_RSTD_LF;
  unsigned short* u16 = (unsigned short*)(base + OFF_U16);
  unsigned short* yh = u16 + U_YH;
  unsigned short* yl = u16 + U_YL;
  unsigned short* hfA = u16 + U_HFA;
  unsigned short* lfA = u16 + U_LFA;
  unsigned short* hfP = u16 + U_HFP;
  unsigned short* pk      = u16 + U_PK;
  unsigned short* pk_adah = pk + 0 * PK_SZ;
  unsigned short* pk_h2h  = pk + 1 * PK_SZ;
  unsigned short* pk_adal = pk + 3 * PK_SZ;
  unsigned short* pk_l2l  = pk + 4 * PK_SZ;
  unsigned short* pk_h2l  = pk + 5 * PK_SZ;
  unsigned short* pk_ph   = u16 + U_PKPH;
  unsigned short* phb     = u16 + U_PHB;

  float* out_hf = (float*)d_out;
  float* out_lf = (float*)d_out + 16777216;

  // prep: all weight packing + ws + istats + point in one launch
  k_prep<<<dim3(28680), dim3(256), 0, stream>>>(
      ada_h_w, h2h, ada_l_w, l2l, h2l, l2h, pk, pk_ph,
      s_hf, h_sw, h_sb, ws_hf, s_lf, l_sw, l_sb, ws_lf,
      h_pw, h_pb, h_bw, h_bb, wp_hf, bs_hf,
      l_pw, l_pb, l_bw, l_bb, wp_lf, bs_lf,
      c_hf, mean_hf, rstd_hf, c_lf, mean_lf, rstd_lf);

  // fused IN + depthwise + pointwise -> NHWC bf16 (hf + lf)
  k_dwt_all<<<dim3(5120), dim3(256), 0, stream>>>(
      c_hf, ws_hf, mean_hf, rstd_hf, wp_hf, bs_hf, yh,
      c_lf, ws_lf, mean_lf, rstd_lf, wp_lf, bs_lf, yl);

  // ada convs (lf + hf merged; hf fuses the 2x2 pool into its epilogue)
  k_ada<<<dim3(1280), dim3(256), 0, stream>>>(yh, yl, pk_adah, pk_adal, ada_h_b, ada_l_b,
                                              hfA, lfA, hfP);

  // phase-collapsed conv(up(lf), l2h) -> bf16 phase buffer
  k_up<<<dim3(1024), dim3(256), 0, stream>>>(lfA, pk_ph, phb);

  // output convs (lf-dual + hf-ACC merged)
  k_out<<<dim3(1280), dim3(256), 0, stream>>>(hfA, lfA, hfP, pk_h2h, pk_l2l, pk_h2l, phb,
                                              out_hf, out_lf);
}

// Round 17
// 315.078 us; speedup vs baseline: 1.2572x; 1.0604x over previous
//
#include <hip/hip_runtime.h>
#include <hip/hip_bf16.h>

#define CDIM 256
#define EPS 1e-5f
#define SLOPE 0.01f

using f32x4  = __attribute__((ext_vector_type(4))) float;
typedef __bf16 bf16x8 __attribute__((ext_vector_type(8)));
typedef unsigned short u16x8 __attribute__((ext_vector_type(8)));

// ---------------- workspace layout ----------------
enum : size_t {
  OFF_WS_HF   = 0,
  OFF_WS_LF   = 9216,
  OFF_WP_HF   = 20480,
  OFF_BS_HF   = 21504,
  OFF_WP_LF   = 22528,
  OFF_BS_LF   = 23552,
  OFF_MEAN_HF = 24576,
  OFF_RSTD_HF = 25600,
  OFF_MEAN_LF = 26624,
  OFF_RSTD_LF = 27648,
  OFF_U16     = 32768,          // start of ushort region (float units)
};
// ushort offsets relative to u16 base
enum : size_t {
  U_YH  = 0,          // [4][128][128][256] bf16
  U_YL  = 16777216,   // [4][64][64][256]
  U_HFA = 20971520,   // [4][128][128][256]
  U_LFA = 37748736,   // [4][64][64][256]
  U_HFP = 41943040,   // [4][64][64][256]
  U_PK  = 46137344,   // 6 packed weight slots, each 589824 (slot2 unused)
  PK_SZ = 589824,
  U_PKPH = U_PK + 6 * PK_SZ,    // phase-packed l2h: 4ph x 4tap x 8icc x 16mf x 64 x 8
  PH_SZ  = 1048576,
  U_PHB  = U_PKPH + PH_SZ,      // phase buffer [4][256][4][64][64] bf16
  U_END  = U_PHB + 16777216,
};
enum : size_t { TOTAL_F = OFF_U16 + (U_END + 1) / 2 };

__device__ float g_scratch[TOTAL_F];

__device__ __forceinline__ int refl(int q, int n) {
  return q < 0 ? -q : (q >= n ? 2 * n - 2 - q : q);
}
__device__ __forceinline__ float lrelu(float v) { return v >= 0.f ? v : SLOPE * v; }
__device__ __forceinline__ unsigned short f2bf(float f) {
  unsigned int u = __float_as_uint(f);
  u += 0x7fffu + ((u >> 16) & 1u);
  return (unsigned short)(u >> 16);
}
__device__ __forceinline__ float bf2f(unsigned short h) {
  return __uint_as_float(((unsigned int)h) << 16);
}
__device__ __forceinline__ void gload_lds16(const void* g, void* l) {
  __builtin_amdgcn_global_load_lds(
      (const __attribute__((address_space(1))) unsigned int*)g,
      (__attribute__((address_space(3))) unsigned int*)l, 16, 0, 0);
}

// ---------------- fused prep: packall [0,24576) | ws | istats | point ----------
__global__ __launch_bounds__(256) void k_prep(
    const float* __restrict__ w_adah, const float* __restrict__ w_h2h,
    const float* __restrict__ w_adal, const float* __restrict__ w_l2l,
    const float* __restrict__ w_h2l, const float* __restrict__ w_l2h,
    unsigned short* __restrict__ pk, unsigned short* __restrict__ pkph,
    const float* __restrict__ s_hf, const float* __restrict__ sw_hf,
    const float* __restrict__ sb_hf, float* __restrict__ ws_hf,
    const float* __restrict__ s_lf, const float* __restrict__ sw_lf,
    const float* __restrict__ sb_lf, float* __restrict__ ws_lf,
    const float* __restrict__ pw_hf, const float* __restrict__ pb_hf,
    const float* __restrict__ bw_hf, const float* __restrict__ bb_hf,
    float* __restrict__ wp_hf, float* __restrict__ bs_hf,
    const float* __restrict__ pw_lf, const float* __restrict__ pb_lf,
    const float* __restrict__ bw_lf, const float* __restrict__ bb_lf,
    float* __restrict__ wp_lf, float* __restrict__ bs_lf,
    const float* __restrict__ c_hf, float* __restrict__ mean_hf, float* __restrict__ rstd_hf,
    const float* __restrict__ c_lf, float* __restrict__ mean_lf, float* __restrict__ rstd_lf) {
  __shared__ float sh[256 * 9];
  const int bid = blockIdx.x;
  const int t = threadIdx.x;

  if (bid < 24576) {
    // ---- weight packing ----
    int seg = bid >> 12;                       // 0..5
    int i = ((bid & 4095) << 8) + t;
    if (seg < 5) {
      if (i >= 589824) return;
      const float* srcs[5] = {w_adah, w_h2h, w_adal, w_l2l, w_h2l};
      const int slot[5] = {0, 1, 3, 4, 5};
      const float* w = srcs[seg];
      int j = i & 7, l = (i >> 3) & 63, mf = (i >> 9) & 15, icc = (i >> 13) & 7, tap = i >> 16;
      int oc = mf * 16 + (l & 15);
      int ic = icc * 32 + (l >> 4) * 8 + j;
      pk[(size_t)slot[seg] * PK_SZ + i] = f2bf(w[((size_t)oc * 256 + ic) * 9 + tap]);
    } else {
      int j = i & 7, l = (i >> 3) & 63, mf = (i >> 9) & 15, icc = (i >> 13) & 7, tapph = i >> 16;
      int tap = tapph & 3, phase = tapph >> 2;
      int tx = tap & 1, ty = tap >> 1;
      int a = phase >> 1, bp = phase & 1;
      int oc = mf * 16 + (l & 15);
      int ic = icc * 32 + (l >> 4) * 8 + j;
      int ys = (a == 0) ? (ty == 0 ? 0 : 1) : (ty == 0 ? 0 : 2);
      int yc = (a == 0) ? (ty == 0 ? 1 : 2) : (ty == 0 ? 2 : 1);
      int xs = (bp == 0) ? (tx == 0 ? 0 : 1) : (tx == 0 ? 0 : 2);
      int xc = (bp == 0) ? (tx == 0 ? 1 : 2) : (tx == 0 ? 2 : 1);
      const float* wb = w_l2h + ((size_t)oc * 256 + ic) * 9;
      float acc = 0.f;
      for (int dy = ys; dy < ys + yc; dy++)
        for (int dx = xs; dx < xs + xc; dx++) acc += wb[dy * 3 + dx];
      pkph[i] = f2bf(acc);
    }
    return;
  }

  const int bx = bid - 24576;                  // 0..4103
  if (bx < 2048) {
    // ---- spatial weights ws = conv(rpad(s,1), sw) + sb ----
    const bool lf = bx >= 1024;
    const int bo = bx & 1023;
    const float* s  = lf ? s_lf : s_hf;
    const float* sw = lf ? sw_lf : sw_hf;
    const float* sb = lf ? sb_lf : sb_hf;
    float* ws_out   = lf ? ws_lf : ws_hf;
    int o = bo & (CDIM - 1);
    int c = t;
    int b = bo >> 8;
    float sv[9], wv[9];
    const float* sp = s + (size_t)(b * CDIM + c) * 9;
    const float* wp = sw + (size_t)(o * CDIM + c) * 9;
#pragma unroll
    for (int i = 0; i < 9; i++) { sv[i] = sp[i]; wv[i] = wp[i]; }
    float out9[9];
#pragma unroll
    for (int i = 0; i < 3; i++)
#pragma unroll
      for (int j = 0; j < 3; j++) {
        float a = 0.f;
#pragma unroll
        for (int dy = 0; dy < 3; dy++) {
          int u = i + dy - 1; u = (u < 0) ? 1 : (u > 2 ? 1 : u);
#pragma unroll
          for (int dx = 0; dx < 3; dx++) {
            int v = j + dx - 1; v = (v < 0) ? 1 : (v > 2 ? 1 : v);
            a += sv[u * 3 + v] * wv[dy * 3 + dx];
          }
        }
        out9[i * 3 + j] = a;
      }
#pragma unroll
    for (int i = 0; i < 9; i++) sh[c * 9 + i] = out9[i];
    __syncthreads();
    for (int st = 128; st > 0; st >>= 1) {
      if (c < st)
#pragma unroll
        for (int i = 0; i < 9; i++) sh[c * 9 + i] += sh[(c + st) * 9 + i];
      __syncthreads();
    }
    if (c < 9) ws_out[(size_t)bo * 9 + c] = sh[c] + sb[o];

  } else if (bx < 4096) {
    // ---- instance norm stats ----
    const int idx = bx - 2048;
    const bool lf = idx >= 1024;
    int plane = lf ? idx - 1024 : idx;
    const float* x = lf ? c_lf : c_hf;
    float* mean = lf ? mean_lf : mean_hf;
    float* rstd = lf ? rstd_lf : rstd_hf;
    const int HW = lf ? 4096 : 16384;
    const float4* p = (const float4*)(x + (size_t)plane * HW);
    int n4 = HW >> 2;
    float s = 0.f, q = 0.f;
    for (int i = t; i < n4; i += 256) {
      float4 v = p[i];
      s += v.x + v.y + v.z + v.w;
      q += v.x * v.x + v.y * v.y + v.z * v.z + v.w * v.w;
    }
    float* rs = sh;
    float* rq = sh + 256;
    rs[t] = s; rq[t] = q;
    __syncthreads();
    for (int st = 128; st > 0; st >>= 1) {
      if (t < st) { rs[t] += rs[t + st]; rq[t] += rq[t + st]; }
      __syncthreads();
    }
    if (t == 0) {
      float m = rs[0] / HW;
      float v = rq[0] / HW - m * m;
      mean[plane] = m;
      rstd[plane] = rsqrtf(v + EPS);
    }

  } else {
    // ---- pooled + w_point / bias ----
    const int idx = bx - 4096;
    const bool lf = (idx >> 2) != 0;
    const int b = idx & 3;
    const float* s  = lf ? s_lf : s_hf;
    const float* pw = lf ? pw_lf : pw_hf;
    const float* pb = lf ? pb_lf : pb_hf;
    const float* bw = lf ? bw_lf : bw_hf;
    const float* bb = lf ? bb_lf : bb_hf;
    float* wp_out = lf ? wp_lf : wp_hf;
    float* bs_out = lf ? bs_lf : bs_hf;
    const int o = t;
    float* pl = sh;
    const float* sp = s + (size_t)(b * CDIM + o) * 9;
    float a9 = 0.f;
#pragma unroll
    for (int j = 0; j < 9; j++) a9 += sp[j];
    pl[o] = a9 * (1.f / 9.f);
    __syncthreads();
    float a = pb[o], d = bb[o];
    const float4* pw4 = (const float4*)(pw + (size_t)o * CDIM);
    const float4* bw4 = (const float4*)(bw + (size_t)o * CDIM);
    const float4* pl4 = (const float4*)pl;
    for (int c4 = 0; c4 < CDIM / 4; c4++) {
      float4 p = pl4[c4];
      float4 w1 = pw4[c4], w2 = bw4[c4];
      a += p.x * w1.x + p.y * w1.y + p.z * w1.z + p.w * w1.w;
      d += p.x * w2.x + p.y * w2.y + p.z * w2.z + p.w * w2.w;
    }
    wp_out[b * CDIM + o] = a;
    bs_out[b * CDIM + o] = d;
  }
}

// ---------------- fused IN + dynamic depthwise + pointwise -> NHWC bf16 ----------------
// 4 output rows per block: reads 6 input rows for 4 outputs (1.5x over-read vs 3x).
// grid: [0,1024) hf (32 y-blocks x 2 xt x 4 icb x 4 b), [1024,1280) lf.
__global__ __launch_bounds__(256) void k_dwt_all(
    const float* __restrict__ xh, const float* __restrict__ wsh,
    const float* __restrict__ mh, const float* __restrict__ rh,
    const float* __restrict__ wph, const float* __restrict__ bsh,
    unsigned short* __restrict__ outh,
    const float* __restrict__ xl, const float* __restrict__ wsl,
    const float* __restrict__ ml, const float* __restrict__ rl,
    const float* __restrict__ wpl, const float* __restrict__ bsl,
    unsigned short* __restrict__ outl) {
  const int bid = blockIdx.x;
  const bool lf = bid >= 1024;
  const int W = lf ? 64 : 128;
  const int H = W, HW = W * W;
  const float *x, *ws, *mean, *rstd, *wp, *bs;
  unsigned short* out;
  int xt, icb, yb, b;
  if (!lf) {
    x = xh; ws = wsh; mean = mh; rstd = rh; wp = wph; bs = bsh; out = outh;
    int x8 = bid & 7; xt = x8 & 1; icb = x8 >> 1; yb = (bid >> 3) & 31; b = bid >> 8;
  } else {
    int local = bid - 1024;
    x = xl; ws = wsl; mean = ml; rstd = rl; wp = wpl; bs = bsl; out = outl;
    xt = 0; icb = local & 3; yb = (local >> 2) & 15; b = local >> 6;
  }
  const int t = threadIdx.x;
  const int y0 = yb * 4;
  __shared__ unsigned short tr[4][64][66];
  const int xg = t & 15;                 // 16 groups of 4 px -> 64 px
  const int chq = t >> 4;                // 0..15
  const int x0 = xt * 64 + xg * 4;
  int iy[6];
#pragma unroll
  for (int r = 0; r < 6; r++) iy[r] = refl(y0 - 1 + r, H);
  const int xm = refl(x0 - 1, W);
  const int xq = refl(x0 + 4, W);
#pragma unroll
  for (int rr = 0; rr < 4; ++rr) {
    int icl = rr * 16 + chq;
    int plane = b * CDIM + icb * 64 + icl;
    const float* xpb = x + (size_t)plane * HW;
    float m = mean[plane], r = rstd[plane], sc = wp[plane], bi = bs[plane];
    const float* w9p = ws + (size_t)plane * 9;
    float w9[9];
#pragma unroll
    for (int i = 0; i < 9; i++) w9[i] = w9p[i];
    float sumw = w9[0] + w9[1] + w9[2] + w9[3] + w9[4] + w9[5] + w9[6] + w9[7] + w9[8];
    float mterm = m * sumw;
    float e[6][6];
#pragma unroll
    for (int r6 = 0; r6 < 6; ++r6) {
      const float* rp = xpb + iy[r6] * W;
      float4 v = *(const float4*)(rp + x0);
      e[r6][0] = rp[xm]; e[r6][1] = v.x; e[r6][2] = v.y;
      e[r6][3] = v.z; e[r6][4] = v.w; e[r6][5] = rp[xq];
    }
#pragma unroll
    for (int orow = 0; orow < 4; ++orow) {
#pragma unroll
      for (int j = 0; j < 4; ++j) {
        float a = w9[0] * e[orow][j]     + w9[1] * e[orow][j + 1]     + w9[2] * e[orow][j + 2] +
                  w9[3] * e[orow + 1][j] + w9[4] * e[orow + 1][j + 1] + w9[5] * e[orow + 1][j + 2] +
                  w9[6] * e[orow + 2][j] + w9[7] * e[orow + 2][j + 1] + w9[8] * e[orow + 2][j + 2];
        a -= mterm;
        tr[orow][icl][xg * 4 + j] = f2bf(a * r * sc + bi);
      }
    }
  }
  __syncthreads();
#pragma unroll
  for (int orow = 0; orow < 4; ++orow) {
#pragma unroll
    for (int it2 = 0; it2 < 2; ++it2) {
      int s2 = it2 * 256 + t;
      int xl2 = s2 >> 3;
      int cg = s2 & 7;
      u16x8 v;
#pragma unroll
      for (int j = 0; j < 8; j++) v[j] = tr[orow][cg * 8 + j][xl2];
      *(u16x8*)&out[((size_t)((b * H + y0 + orow) * W + xt * 64 + xl2)) * CDIM +
                    icb * 64 + cg * 8] = v;
    }
  }
}

// ---------------- conv body (R5/R11 structure + ACC + optional fused 2x2 pool) ----------------
template <int LW, bool DUAL, bool UPSB, bool NCHWOUT, bool ACC, bool POOL>
__device__ __forceinline__ void conv_body(
    int wk, unsigned short* tin, unsigned short* wlds,
    const unsigned short* __restrict__ srcA, const unsigned short* __restrict__ srcB,
    const unsigned short* __restrict__ wpkA, const unsigned short* __restrict__ wpkB,
    const float* __restrict__ bias, const unsigned short* __restrict__ accsrc,
    void* __restrict__ outp, unsigned short* __restrict__ pool_dst) {
  constexpr int W = 1 << LW, H = W, HW = W * W;
  constexpr int ROWS = 256 >> LW;
  constexpr int R = ROWS + 2, Cw = W + 2;
  constexpr int RC = R * Cw;
  constexpr int RCPAD = (RC + 63) & ~63;
  constexpr int NIT = RCPAD / 64;

  const int t = threadIdx.x;
  const int l = t & 63, wv = t >> 6;
  const int l15 = l & 15, l4 = l >> 4;

  const int mb = wk & 3;
  const int pixbase = (wk >> 2) * 256;
  const int b = pixbase >> (2 * LW);
  const int y0 = (pixbase >> LW) & (H - 1);

  f32x4 acc[4][4];
#pragma unroll
  for (int mi = 0; mi < 4; mi++)
#pragma unroll
    for (int nf = 0; nf < 4; nf++) acc[mi][nf] = (f32x4){0.f, 0.f, 0.f, 0.f};

  const int nsrc = DUAL ? 2 : 1;
  for (int src = 0; src < nsrc; ++src) {
    const unsigned short* ysrc = src ? srcB : srcA;
    const unsigned short* wpk = src ? wpkB : wpkA;
    const bool ups = UPSB && (src == 1);

    const unsigned short* inptr[NIT];
#pragma unroll
    for (int it = 0; it < NIT; ++it) {
      int rc = it * 64 + (t >> 2);
      int rcc = rc < RC - 1 ? rc : RC - 1;
      int r = rcc / Cw, tc = rcc - r * Cw;
      int gy = refl(y0 - 1 + r, H);
      int gx = refl(tc - 1, W);
      int sy, sx, sw;
      if (ups) { sy = gy >> 1; sx = gx >> 1; sw = W >> 1; }
      else     { sy = gy;      sx = gx;      sw = W; }
      int gsrc = (t & 3) ^ (tc & 3);
      inptr[it] = ysrc + (((size_t)(b * sw + sy) * sw + sx) * CDIM + gsrc * 8);
    }
    const unsigned short* wsrc = wpk + ((size_t)(mb * 4 + wv) * 64 + l) * 8;

    for (int icc = 0; icc < 8; ++icc) {
      __syncthreads();
#pragma unroll
      for (int it = 0; it < NIT; ++it)
        gload_lds16(inptr[it] + icc * 32, &tin[(size_t)(it * 256 + t) * 8]);
#pragma unroll
      for (int tap = 0; tap < 9; ++tap)
        gload_lds16(wsrc + ((size_t)tap * 8 + (size_t)icc) * 8192,
                    &wlds[(size_t)(tap * 256 + t) * 8]);
      __syncthreads();

      __builtin_amdgcn_s_setprio(1);
#pragma unroll
      for (int tap = 0; tap < 9; ++tap) {
        const int dy = tap / 3, dx = tap - 3 * (tap / 3);
        bf16x8 af[4];
#pragma unroll
        for (int mi = 0; mi < 4; mi++)
          af[mi] = *(const bf16x8*)&wlds[(size_t)((tap * 4 + mi) * 64 + l) * 8];
#pragma unroll
        for (int nf = 0; nf < 4; nf++) {
          int pl = wv * 64 + nf * 16 + l15;
          int py = pl >> LW;
          int c = pl & (W - 1);
          int tcol = c + dx;
          int idx16 = ((py + dy) * Cw + tcol) * 4 + (l4 ^ (tcol & 3));
          bf16x8 bfv = *(const bf16x8*)&tin[(size_t)idx16 * 8];
#pragma unroll
          for (int mi = 0; mi < 4; mi++)
            acc[mi][nf] = __builtin_amdgcn_mfma_f32_16x16x32_bf16(af[mi], bfv, acc[mi][nf], 0, 0, 0);
        }
      }
      __builtin_amdgcn_s_setprio(0);
    }
  }

  if (POOL) __syncthreads();   // all waves done reading tin before reuse as pool stage

  // epilogue
#pragma unroll
  for (int mi = 0; mi < 4; mi++) {
    int oc0 = mb * 64 + mi * 16 + l4 * 4;
    float bv[4];
#pragma unroll
    for (int rr = 0; rr < 4; rr++) bv[rr] = bias ? bias[oc0 + rr] : 0.f;
#pragma unroll
    for (int nf = 0; nf < 4; nf++) {
      int p = pixbase + wv * 64 + nf * 16 + l15;
      if (NCHWOUT) {
        float* o = (float*)outp;
        int pin = p & (HW - 1);
        int bb2 = p >> (2 * LW);
        int yy = pin >> LW, xx = pin & (W - 1);
        int ph = ((yy & 1) << 1) | (xx & 1);
        int q = (yy >> 1) * (W / 2) + (xx >> 1);
#pragma unroll
        for (int rr = 0; rr < 4; rr++) {
          float v = acc[mi][nf][rr] + bv[rr];
          if (ACC)
            v += bf2f(accsrc[((size_t)(bb2 * CDIM + oc0 + rr) * 4 + ph) * (HW / 4) + q]);
          o[((size_t)(bb2 * CDIM + oc0 + rr)) * HW + pin] = lrelu(v);
        }
      } else {
        unsigned short* o = (unsigned short*)outp;
        ushort4 pkv;
        pkv.x = f2bf(lrelu(acc[mi][nf][0] + bv[0]));
        pkv.y = f2bf(lrelu(acc[mi][nf][1] + bv[1]));
        pkv.z = f2bf(lrelu(acc[mi][nf][2] + bv[2]));
        pkv.w = f2bf(lrelu(acc[mi][nf][3] + bv[3]));
        *(ushort4*)&o[(size_t)p * CDIM + oc0] = pkv;
        if (POOL) {
          int pl = wv * 64 + nf * 16 + l15;
          int py = pl >> LW, col = pl & (W - 1);
          int ocl = mi * 16 + l4 * 4;
          *(ushort4*)&tin[(size_t)((py * W + col) * 64 + ocl)] = pkv;
        }
      }
    }
  }

  if (POOL) {
    __syncthreads();
    const int Y = y0 >> 1;
#pragma unroll
    for (int j = 0; j < 16; ++j) {
      int f = j * 256 + t;              // 0..4095
      int X = f >> 6, ocl = f & 63;
      float v = 0.25f * (bf2f(tin[((0 * W + 2 * X) * 64 + ocl)]) +
                         bf2f(tin[((0 * W + 2 * X + 1) * 64 + ocl)]) +
                         bf2f(tin[((1 * W + 2 * X) * 64 + ocl)]) +
                         bf2f(tin[((1 * W + 2 * X + 1) * 64 + ocl)]));
      pool_dst[((size_t)((b * 64 + Y) * 64 + X)) * CDIM + mb * 64 + ocl] = f2bf(v);
    }
  }
}

// ---------------- merged ada convs: lf [0,256) + hf(+fused pool) [256,1280) ----------------
__global__ __launch_bounds__(256, 2) void k_ada(
    const unsigned short* __restrict__ yh, const unsigned short* __restrict__ yl,
    const unsigned short* __restrict__ pk_adah, const unsigned short* __restrict__ pk_adal,
    const float* __restrict__ ada_h_b, const float* __restrict__ ada_l_b,
    unsigned short* __restrict__ hfA, unsigned short* __restrict__ lfA,
    unsigned short* __restrict__ hfP) {
  __shared__ __align__(16) unsigned short tin[18432];   // max RCPAD*32 (LW=7: 576*32)
  __shared__ __align__(16) unsigned short wlds[18432];  // 9*4*64*8
  const int bid = blockIdx.x;
  if (bid < 256) {
    int wk = ((bid & 7) << 5) + (bid >> 3);             // nwg=256
    conv_body<6, false, false, false, false, false>(wk, tin, wlds, yl, nullptr, pk_adal,
                                                    nullptr, ada_l_b, nullptr, lfA, nullptr);
  } else {
    int h = bid - 256;
    int wk = ((h & 7) << 7) + (h >> 3);                 // nwg=1024
    conv_body<7, false, false, false, false, true>(wk, tin, wlds, yh, nullptr, pk_adah,
                                                   nullptr, ada_h_b, nullptr, hfA, hfP);
  }
}

// ---------------- merged output convs: lf-dual [0,256) + hf-ACC [256,1280) ----------------
__global__ __launch_bounds__(256, 2) void k_out(
    const unsigned short* __restrict__ hfA, const unsigned short* __restrict__ lfA,
    const unsigned short* __restrict__ hfP,
    const unsigned short* __restrict__ pk_h2h, const unsigned short* __restrict__ pk_l2l,
    const unsigned short* __restrict__ pk_h2l, const unsigned short* __restrict__ phb,
    float* __restrict__ out_hf, float* __restrict__ out_lf) {
  __shared__ __align__(16) unsigned short tin[18432];
  __shared__ __align__(16) unsigned short wlds[18432];
  const int bid = blockIdx.x;
  if (bid < 256) {
    int wk = ((bid & 7) << 5) + (bid >> 3);
    conv_body<6, true, false, true, false, false>(wk, tin, wlds, lfA, hfP, pk_l2l, pk_h2l,
                                                  nullptr, nullptr, out_lf, nullptr);
  } else {
    int h = bid - 256;
    int wk = ((h & 7) << 7) + (h >> 3);
    conv_body<7, false, false, true, true, false>(wk, tin, wlds, hfA, nullptr, pk_h2h,
                                                  nullptr, nullptr, phb, out_hf, nullptr);
  }
}

// ---------------- phase-collapsed upsample-conv: 4-tap GEMM on lf grid ----------------
__global__ __launch_bounds__(256, 3) void k_up(
    const unsigned short* __restrict__ lf, const unsigned short* __restrict__ wph,
    unsigned short* __restrict__ phb) {
  constexpr int NIT = 5;
  __shared__ __align__(16) unsigned short tin[10240];   // 320 slots x 32ic
  __shared__ __align__(16) unsigned short wlds[8192];   // 4 taps x 256 x 8

  const int t = threadIdx.x;
  const int l = t & 63, wv = t >> 6;
  const int l15 = l & 15, l4 = l >> 4;

  const int hwid = blockIdx.x;
  const int wk = ((hwid & 7) << 7) + (hwid >> 3);   // nwg = 1024
  const int mb = wk & 3;
  const int phase = (wk >> 2) & 3;
  const int tile = (wk >> 4) & 15;
  const int b = wk >> 8;
  const int a = phase >> 1, bp = phase & 1;
  const int Y0 = tile * 4;

  f32x4 acc[4][4];
#pragma unroll
  for (int mi = 0; mi < 4; mi++)
#pragma unroll
    for (int nf = 0; nf < 4; nf++) acc[mi][nf] = (f32x4){0.f, 0.f, 0.f, 0.f};

  const unsigned short* inptr[NIT];
#pragma unroll
  for (int it = 0; it < NIT; ++it) {
    int s = it * 64 + (t >> 2);
    int row = s >> 6, col = s & 63;
    int ly = Y0 - 1 + a + row;
    ly = ly < 0 ? 0 : (ly > 63 ? 63 : ly);
    int gsrc = (t & 3) ^ (col & 3);
    inptr[it] = lf + (((size_t)(b * 64 + ly) * 64 + col) * CDIM + gsrc * 8);
  }
  const unsigned short* wsrc = wph + ((size_t)(mb * 4 + wv) * 64 + l) * 8;

  for (int icc = 0; icc < 8; ++icc) {
    __syncthreads();
#pragma unroll
    for (int it = 0; it < NIT; ++it)
      gload_lds16(inptr[it] + icc * 32, &tin[(size_t)(it * 256 + t) * 8]);
#pragma unroll
    for (int tap = 0; tap < 4; ++tap)
      gload_lds16(wsrc + ((size_t)(phase * 4 + tap) * 8 + (size_t)icc) * 8192,
                  &wlds[(size_t)(tap * 256 + t) * 8]);
    __syncthreads();

    __builtin_amdgcn_s_setprio(1);
#pragma unroll
    for (int tap = 0; tap < 4; ++tap) {
      const int ty = tap >> 1, tx = tap & 1;
      bf16x8 af[4];
#pragma unroll
      for (int mi = 0; mi < 4; mi++)
        af[mi] = *(const bf16x8*)&wlds[(size_t)((tap * 4 + mi) * 64 + l) * 8];
#pragma unroll
      for (int nf = 0; nf < 4; nf++) {
        int pl = wv * 64 + nf * 16 + l15;
        int py = pl >> 6;
        int col = pl & 63;
        int tcol = col - 1 + bp + tx;
        tcol = tcol < 0 ? 0 : (tcol > 63 ? 63 : tcol);
        int idx16 = ((py + ty) * 64 + tcol) * 4 + (l4 ^ (tcol & 3));
        bf16x8 bfv = *(const bf16x8*)&tin[(size_t)idx16 * 8];
#pragma unroll
        for (int mi = 0; mi < 4; mi++)
          acc[mi][nf] = __builtin_amdgcn_mfma_f32_16x16x32_bf16(af[mi], bfv, acc[mi][nf], 0, 0, 0);
      }
    }
    __builtin_amdgcn_s_setprio(0);
  }

#pragma unroll
  for (int mi = 0; mi < 4; mi++) {
    int oc0 = mb * 64 + mi * 16 + l4 * 4;
#pragma unroll
    for (int nf = 0; nf < 4; nf++) {
      int pl = wv * 64 + nf * 16 + l15;
      int py = pl >> 6, col = pl & 63;
      size_t base = ((size_t)(b * CDIM + oc0) * 4 + phase) * 4096 + (Y0 + py) * 64 + col;
#pragma unroll
      for (int rr = 0; rr < 4; rr++)
        phb[base + (size_t)rr * 4 * 4096] = f2bf(acc[mi][nf][rr]);
    }
  }
}

// ---------------- host ----------------
extern "C" void kernel_launch(void* const* d_in, const int* in_sizes, int n_in,
                              void* d_out, int out_size, void* d_ws, size_t ws_size,
                              hipStream_t stream) {
  (void)in_sizes; (void)n_in; (void)out_size;
  const float* c_hf = (const float*)d_in[0];
  const float* c_lf = (const float*)d_in[1];
  const float* s_hf = (const float*)d_in[2];
  const float* s_lf = (const float*)d_in[3];
  const float* h_sw = (const float*)d_in[4];
  const float* h_sb = (const float*)d_in[5];
  const float* h_pw = (const float*)d_in[6];
  const float* h_pb = (const float*)d_in[7];
  const float* h_bw = (const float*)d_in[8];
  const float* h_bb = (const float*)d_in[9];
  const float* l_sw = (const float*)d_in[10];
  const float* l_sb = (const float*)d_in[11];
  const float* l_pw = (const float*)d_in[12];
  const float* l_pb = (const float*)d_in[13];
  const float* l_bw = (const float*)d_in[14];
  const float* l_bb = (const float*)d_in[15];
  const float* ada_h_w = (const float*)d_in[16];
  const float* ada_h_b = (const float*)d_in[17];
  const float* ada_l_w = (const float*)d_in[18];
  const float* ada_l_b = (const float*)d_in[19];
  const float* h2h = (const float*)d_in[20];
  const float* l2h = (const float*)d_in[21];
  const float* h2l = (const float*)d_in[22];
  const float* l2l = (const float*)d_in[23];

  float* base;
  size_t need = (size_t)TOTAL_F * sizeof(float);
  if (ws_size >= need) {
    base = (float*)d_ws;
  } else {
    void* p = nullptr;
    hipGetSymbolAddress(&p, HIP_SYMBOL(g_scratch));
    base = (float*)p;
  }

  float* ws_hf = base + OFF_WS_HF;
  float* ws_lf = base + OFF_WS_LF;
  float* wp_hf = base + OFF_WP_HF;
  float* bs_hf = base + OFF_BS_HF;
  float* wp_lf = base + OFF_WP_LF;
  float* bs_lf = base + OFF_BS_LF;
  float* mean_hf = base + OFF_MEAN_HF;
  float* rstd_hf = base + OFF_RSTD_HF;
  float* mean_lf = base + OFF_MEAN_LF;
  float* rstd_lf = base + OFF_RSTD_LF;
  unsigned short* u16 = (unsigned short*)(base + OFF_U16);
  unsigned short* yh = u16 + U_YH;
  unsigned short* yl = u16 + U_YL;
  unsigned short* hfA = u16 + U_HFA;
  unsigned short* lfA = u16 + U_LFA;
  unsigned short* hfP = u16 + U_HFP;
  unsigned short* pk      = u16 + U_PK;
  unsigned short* pk_adah = pk + 0 * PK_SZ;
  unsigned short* pk_h2h  = pk + 1 * PK_SZ;
  unsigned short* pk_adal = pk + 3 * PK_SZ;
  unsigned short* pk_l2l  = pk + 4 * PK_SZ;
  unsigned short* pk_h2l  = pk + 5 * PK_SZ;
  unsigned short* pk_ph   = u16 + U_PKPH;
  unsigned short* phb     = u16 + U_PHB;

  float* out_hf = (float*)d_out;
  float* out_lf = (float*)d_out + 16777216;

  // prep: all weight packing + ws + istats + point in one launch
  k_prep<<<dim3(28680), dim3(256), 0, stream>>>(
      ada_h_w, h2h, ada_l_w, l2l, h2l, l2h, pk, pk_ph,
      s_hf, h_sw, h_sb, ws_hf, s_lf, l_sw, l_sb, ws_lf,
      h_pw, h_pb, h_bw, h_bb, wp_hf, bs_hf,
      l_pw, l_pb, l_bw, l_bb, wp_lf, bs_lf,
      c_hf, mean_hf, rstd_hf, c_lf, mean_lf, rstd_lf);

  // fused IN + depthwise + pointwise -> NHWC bf16 (4 rows/block)
  k_dwt_all<<<dim3(1280), dim3(256), 0, stream>>>(
      c_hf, ws_hf, mean_hf, rstd_hf, wp_hf, bs_hf, yh,
      c_lf, ws_lf, mean_lf, rstd_lf, wp_lf, bs_lf, yl);

  // ada convs (lf + hf merged; hf fuses the 2x2 pool into its epilogue)
  k_ada<<<dim3(1280), dim3(256), 0, stream>>>(yh, yl, pk_adah, pk_adal, ada_h_b, ada_l_b,
                                              hfA, lfA, hfP);

  // phase-collapsed conv(up(lf), l2h) -> bf16 phase buffer
  k_up<<<dim3(1024), dim3(256), 0, stream>>>(lfA, pk_ph, phb);

  // output convs (lf-dual + hf-ACC merged)
  k_out<<<dim3(1280), dim3(256), 0, stream>>>(hfA, lfA, hfP, pk_h2h, pk_l2l, pk_h2l, phb,
                                              out_hf, out_lf);
}

// Round 18
// 315.058 us; speedup vs baseline: 1.2573x; 1.0001x over previous
//
#include <hip/hip_runtime.h>
#include <hip/hip_bf16.h>

#define CDIM 256
#define EPS 1e-5f
#define SLOPE 0.01f

using f32x4  = __attribute__((ext_vector_type(4))) float;
typedef __bf16 bf16x8 __attribute__((ext_vector_type(8)));
typedef unsigned short u16x8 __attribute__((ext_vector_type(8)));

// ---------------- workspace layout ----------------
enum : size_t {
  OFF_WS_HF   = 0,
  OFF_WS_LF   = 9216,
  OFF_WP_HF   = 20480,
  OFF_BS_HF   = 21504,
  OFF_WP_LF   = 22528,
  OFF_BS_LF   = 23552,
  OFF_MEAN_HF = 24576,
  OFF_RSTD_HF = 25600,
  OFF_MEAN_LF = 26624,
  OFF_RSTD_LF = 27648,
  OFF_U16     = 32768,          // start of ushort region (float units)
};
// ushort offsets relative to u16 base
enum : size_t {
  U_YH  = 0,          // [4][128][128][256] bf16
  U_YL  = 16777216,   // [4][64][64][256]
  U_HFA = 20971520,   // [4][128][128][256]
  U_LFA = 37748736,   // [4][64][64][256]
  U_HFP = 41943040,   // [4][64][64][256]
  U_PK  = 46137344,   // 6 packed weight slots, each 589824 (slot2 unused)
  PK_SZ = 589824,
  U_PKPH = U_PK + 6 * PK_SZ,    // phase-packed l2h: 4ph x 4tap x 8icc x 16mf x 64 x 8
  PH_SZ  = 1048576,
  U_PHB  = U_PKPH + PH_SZ,      // phase buffer [4][256][4][64][64] bf16
  U_END  = U_PHB + 16777216,
};
enum : size_t { TOTAL_F = OFF_U16 + (U_END + 1) / 2 };

__device__ float g_scratch[TOTAL_F];

__device__ __forceinline__ int refl(int q, int n) {
  return q < 0 ? -q : (q >= n ? 2 * n - 2 - q : q);
}
__device__ __forceinline__ float lrelu(float v) { return v >= 0.f ? v : SLOPE * v; }
__device__ __forceinline__ unsigned short f2bf(float f) {
  unsigned int u = __float_as_uint(f);
  u += 0x7fffu + ((u >> 16) & 1u);
  return (unsigned short)(u >> 16);
}
__device__ __forceinline__ float bf2f(unsigned short h) {
  return __uint_as_float(((unsigned int)h) << 16);
}
__device__ __forceinline__ void gload_lds16(const void* g, void* l) {
  __builtin_amdgcn_global_load_lds(
      (const __attribute__((address_space(1))) unsigned int*)g,
      (__attribute__((address_space(3))) unsigned int*)l, 16, 0, 0);
}

// ---------------- fused prep: packall [0,24576) | ws | istats | point ----------
__global__ __launch_bounds__(256) void k_prep(
    const float* __restrict__ w_adah, const float* __restrict__ w_h2h,
    const float* __restrict__ w_adal, const float* __restrict__ w_l2l,
    const float* __restrict__ w_h2l, const float* __restrict__ w_l2h,
    unsigned short* __restrict__ pk, unsigned short* __restrict__ pkph,
    const float* __restrict__ s_hf, const float* __restrict__ sw_hf,
    const float* __restrict__ sb_hf, float* __restrict__ ws_hf,
    const float* __restrict__ s_lf, const float* __restrict__ sw_lf,
    const float* __restrict__ sb_lf, float* __restrict__ ws_lf,
    const float* __restrict__ pw_hf, const float* __restrict__ pb_hf,
    const float* __restrict__ bw_hf, const float* __restrict__ bb_hf,
    float* __restrict__ wp_hf, float* __restrict__ bs_hf,
    const float* __restrict__ pw_lf, const float* __restrict__ pb_lf,
    const float* __restrict__ bw_lf, const float* __restrict__ bb_lf,
    float* __restrict__ wp_lf, float* __restrict__ bs_lf,
    const float* __restrict__ c_hf, float* __restrict__ mean_hf, float* __restrict__ rstd_hf,
    const float* __restrict__ c_lf, float* __restrict__ mean_lf, float* __restrict__ rstd_lf) {
  __shared__ float sh[256 * 9];
  const int bid = blockIdx.x;
  const int t = threadIdx.x;

  if (bid < 24576) {
    // ---- weight packing ----
    int seg = bid >> 12;                       // 0..5
    int i = ((bid & 4095) << 8) + t;
    if (seg < 5) {
      if (i >= 589824) return;
      const float* srcs[5] = {w_adah, w_h2h, w_adal, w_l2l, w_h2l};
      const int slot[5] = {0, 1, 3, 4, 5};
      const float* w = srcs[seg];
      int j = i & 7, l = (i >> 3) & 63, mf = (i >> 9) & 15, icc = (i >> 13) & 7, tap = i >> 16;
      int oc = mf * 16 + (l & 15);
      int ic = icc * 32 + (l >> 4) * 8 + j;
      pk[(size_t)slot[seg] * PK_SZ + i] = f2bf(w[((size_t)oc * 256 + ic) * 9 + tap]);
    } else {
      int j = i & 7, l = (i >> 3) & 63, mf = (i >> 9) & 15, icc = (i >> 13) & 7, tapph = i >> 16;
      int tap = tapph & 3, phase = tapph >> 2;
      int tx = tap & 1, ty = tap >> 1;
      int a = phase >> 1, bp = phase & 1;
      int oc = mf * 16 + (l & 15);
      int ic = icc * 32 + (l >> 4) * 8 + j;
      int ys = (a == 0) ? (ty == 0 ? 0 : 1) : (ty == 0 ? 0 : 2);
      int yc = (a == 0) ? (ty == 0 ? 1 : 2) : (ty == 0 ? 2 : 1);
      int xs = (bp == 0) ? (tx == 0 ? 0 : 1) : (tx == 0 ? 0 : 2);
      int xc = (bp == 0) ? (tx == 0 ? 1 : 2) : (tx == 0 ? 2 : 1);
      const float* wb = w_l2h + ((size_t)oc * 256 + ic) * 9;
      float acc = 0.f;
      for (int dy = ys; dy < ys + yc; dy++)
        for (int dx = xs; dx < xs + xc; dx++) acc += wb[dy * 3 + dx];
      pkph[i] = f2bf(acc);
    }
    return;
  }

  const int bx = bid - 24576;                  // 0..4103
  if (bx < 2048) {
    // ---- spatial weights ws = conv(rpad(s,1), sw) + sb ----
    const bool lf = bx >= 1024;
    const int bo = bx & 1023;
    const float* s  = lf ? s_lf : s_hf;
    const float* sw = lf ? sw_lf : sw_hf;
    const float* sb = lf ? sb_lf : sb_hf;
    float* ws_out   = lf ? ws_lf : ws_hf;
    int o = bo & (CDIM - 1);
    int c = t;
    int b = bo >> 8;
    float sv[9], wv[9];
    const float* sp = s + (size_t)(b * CDIM + c) * 9;
    const float* wp = sw + (size_t)(o * CDIM + c) * 9;
#pragma unroll
    for (int i = 0; i < 9; i++) { sv[i] = sp[i]; wv[i] = wp[i]; }
    float out9[9];
#pragma unroll
    for (int i = 0; i < 3; i++)
#pragma unroll
      for (int j = 0; j < 3; j++) {
        float a = 0.f;
#pragma unroll
        for (int dy = 0; dy < 3; dy++) {
          int u = i + dy - 1; u = (u < 0) ? 1 : (u > 2 ? 1 : u);
#pragma unroll
          for (int dx = 0; dx < 3; dx++) {
            int v = j + dx - 1; v = (v < 0) ? 1 : (v > 2 ? 1 : v);
            a += sv[u * 3 + v] * wv[dy * 3 + dx];
          }
        }
        out9[i * 3 + j] = a;
      }
#pragma unroll
    for (int i = 0; i < 9; i++) sh[c * 9 + i] = out9[i];
    __syncthreads();
    for (int st = 128; st > 0; st >>= 1) {
      if (c < st)
#pragma unroll
        for (int i = 0; i < 9; i++) sh[c * 9 + i] += sh[(c + st) * 9 + i];
      __syncthreads();
    }
    if (c < 9) ws_out[(size_t)bo * 9 + c] = sh[c] + sb[o];

  } else if (bx < 4096) {
    // ---- instance norm stats ----
    const int idx = bx - 2048;
    const bool lf = idx >= 1024;
    int plane = lf ? idx - 1024 : idx;
    const float* x = lf ? c_lf : c_hf;
    float* mean = lf ? mean_lf : mean_hf;
    float* rstd = lf ? rstd_lf : rstd_hf;
    const int HW = lf ? 4096 : 16384;
    const float4* p = (const float4*)(x + (size_t)plane * HW);
    int n4 = HW >> 2;
    float s = 0.f, q = 0.f;
    for (int i = t; i < n4; i += 256) {
      float4 v = p[i];
      s += v.x + v.y + v.z + v.w;
      q += v.x * v.x + v.y * v.y + v.z * v.z + v.w * v.w;
    }
    float* rs = sh;
    float* rq = sh + 256;
    rs[t] = s; rq[t] = q;
    __syncthreads();
    for (int st = 128; st > 0; st >>= 1) {
      if (t < st) { rs[t] += rs[t + st]; rq[t] += rq[t + st]; }
      __syncthreads();
    }
    if (t == 0) {
      float m = rs[0] / HW;
      float v = rq[0] / HW - m * m;
      mean[plane] = m;
      rstd[plane] = rsqrtf(v + EPS);
    }

  } else {
    // ---- pooled + w_point / bias ----
    const int idx = bx - 4096;
    const bool lf = (idx >> 2) != 0;
    const int b = idx & 3;
    const float* s  = lf ? s_lf : s_hf;
    const float* pw = lf ? pw_lf : pw_hf;
    const float* pb = lf ? pb_lf : pb_hf;
    const float* bw = lf ? bw_lf : bw_hf;
    const float* bb = lf ? bb_lf : bb_hf;
    float* wp_out = lf ? wp_lf : wp_hf;
    float* bs_out = lf ? bs_lf : bs_hf;
    const int o = t;
    float* pl = sh;
    const float* sp = s + (size_t)(b * CDIM + o) * 9;
    float a9 = 0.f;
#pragma unroll
    for (int j = 0; j < 9; j++) a9 += sp[j];
    pl[o] = a9 * (1.f / 9.f);
    __syncthreads();
    float a = pb[o], d = bb[o];
    const float4* pw4 = (const float4*)(pw + (size_t)o * CDIM);
    const float4* bw4 = (const float4*)(bw + (size_t)o * CDIM);
    const float4* pl4 = (const float4*)pl;
    for (int c4 = 0; c4 < CDIM / 4; c4++) {
      float4 p = pl4[c4];
      float4 w1 = pw4[c4], w2 = bw4[c4];
      a += p.x * w1.x + p.y * w1.y + p.z * w1.z + p.w * w1.w;
      d += p.x * w2.x + p.y * w2.y + p.z * w2.z + p.w * w2.w;
    }
    wp_out[b * CDIM + o] = a;
    bs_out[b * CDIM + o] = d;
  }
}

// ---------------- fused IN + dynamic depthwise + pointwise -> NHWC bf16 ----------------
// 4 output rows per block: reads 6 input rows for 4 outputs (1.5x over-read vs 3x).
// grid: [0,1024) hf (32 y-blocks x 2 xt x 4 icb x 4 b), [1024,1280) lf.
__global__ __launch_bounds__(256) void k_dwt_all(
    const float* __restrict__ xh, const float* __restrict__ wsh,
    const float* __restrict__ mh, const float* __restrict__ rh,
    const float* __restrict__ wph, const float* __restrict__ bsh,
    unsigned short* __restrict__ outh,
    const float* __restrict__ xl, const float* __restrict__ wsl,
    const float* __restrict__ ml, const float* __restrict__ rl,
    const float* __restrict__ wpl, const float* __restrict__ bsl,
    unsigned short* __restrict__ outl) {
  const int bid = blockIdx.x;
  const bool lf = bid >= 1024;
  const int W = lf ? 64 : 128;
  const int H = W, HW = W * W;
  const float *x, *ws, *mean, *rstd, *wp, *bs;
  unsigned short* out;
  int xt, icb, yb, b;
  if (!lf) {
    x = xh; ws = wsh; mean = mh; rstd = rh; wp = wph; bs = bsh; out = outh;
    int x8 = bid & 7; xt = x8 & 1; icb = x8 >> 1; yb = (bid >> 3) & 31; b = bid >> 8;
  } else {
    int local = bid - 1024;
    x = xl; ws = wsl; mean = ml; rstd = rl; wp = wpl; bs = bsl; out = outl;
    xt = 0; icb = local & 3; yb = (local >> 2) & 15; b = local >> 6;
  }
  const int t = threadIdx.x;
  const int y0 = yb * 4;
  __shared__ unsigned short tr[4][64][66];
  const int xg = t & 15;                 // 16 groups of 4 px -> 64 px
  const int chq = t >> 4;                // 0..15
  const int x0 = xt * 64 + xg * 4;
  int iy[6];
#pragma unroll
  for (int r = 0; r < 6; r++) iy[r] = refl(y0 - 1 + r, H);
  const int xm = refl(x0 - 1, W);
  const int xq = refl(x0 + 4, W);
#pragma unroll
  for (int rr = 0; rr < 4; ++rr) {
    int icl = rr * 16 + chq;
    int plane = b * CDIM + icb * 64 + icl;
    const float* xpb = x + (size_t)plane * HW;
    float m = mean[plane], r = rstd[plane], sc = wp[plane], bi = bs[plane];
    const float* w9p = ws + (size_t)plane * 9;
    float w9[9];
#pragma unroll
    for (int i = 0; i < 9; i++) w9[i] = w9p[i];
    float sumw = w9[0] + w9[1] + w9[2] + w9[3] + w9[4] + w9[5] + w9[6] + w9[7] + w9[8];
    float mterm = m * sumw;
    float e[6][6];
#pragma unroll
    for (int r6 = 0; r6 < 6; ++r6) {
      const float* rp = xpb + iy[r6] * W;
      float4 v = *(const float4*)(rp + x0);
      e[r6][0] = rp[xm]; e[r6][1] = v.x; e[r6][2] = v.y;
      e[r6][3] = v.z; e[r6][4] = v.w; e[r6][5] = rp[xq];
    }
#pragma unroll
    for (int orow = 0; orow < 4; ++orow) {
#pragma unroll
      for (int j = 0; j < 4; ++j) {
        float a = w9[0] * e[orow][j]     + w9[1] * e[orow][j + 1]     + w9[2] * e[orow][j + 2] +
                  w9[3] * e[orow + 1][j] + w9[4] * e[orow + 1][j + 1] + w9[5] * e[orow + 1][j + 2] +
                  w9[6] * e[orow + 2][j] + w9[7] * e[orow + 2][j + 1] + w9[8] * e[orow + 2][j + 2];
        a -= mterm;
        tr[orow][icl][xg * 4 + j] = f2bf(a * r * sc + bi);
      }
    }
  }
  __syncthreads();
#pragma unroll
  for (int orow = 0; orow < 4; ++orow) {
#pragma unroll
    for (int it2 = 0; it2 < 2; ++it2) {
      int s2 = it2 * 256 + t;
      int xl2 = s2 >> 3;
      int cg = s2 & 7;
      u16x8 v;
#pragma unroll
      for (int j = 0; j < 8; j++) v[j] = tr[orow][cg * 8 + j][xl2];
      *(u16x8*)&out[((size_t)((b * H + y0 + orow) * W + xt * 64 + xl2)) * CDIM +
                    icb * 64 + cg * 8] = v;
    }
  }
}

// ---------------- conv body (x-halo-free tin; reflect-x resolved at read) ----------------
template <int LW, bool DUAL, bool UPSB, bool NCHWOUT, bool ACC, bool POOL>
__device__ __forceinline__ void conv_body(
    int wk, unsigned short* tin, unsigned short* wlds,
    const unsigned short* __restrict__ srcA, const unsigned short* __restrict__ srcB,
    const unsigned short* __restrict__ wpkA, const unsigned short* __restrict__ wpkB,
    const float* __restrict__ bias, const unsigned short* __restrict__ accsrc,
    void* __restrict__ outp, unsigned short* __restrict__ pool_dst) {
  constexpr int W = 1 << LW, H = W, HW = W * W;
  constexpr int ROWS = 256 >> LW;
  constexpr int R = ROWS + 2;
  constexpr int SLOTS = R * W;         // x-halo-free: pad cols are interior cols
  constexpr int NIT = SLOTS / 64;      // hf: 8, lf: 6
  static_assert(SLOTS % 64 == 0, "slots");

  const int t = threadIdx.x;
  const int l = t & 63, wv = t >> 6;
  const int l15 = l & 15, l4 = l >> 4;

  const int mb = wk & 3;
  const int pixbase = (wk >> 2) * 256;
  const int b = pixbase >> (2 * LW);
  const int y0 = (pixbase >> LW) & (H - 1);

  f32x4 acc[4][4];
#pragma unroll
  for (int mi = 0; mi < 4; mi++)
#pragma unroll
    for (int nf = 0; nf < 4; nf++) acc[mi][nf] = (f32x4){0.f, 0.f, 0.f, 0.f};

  const int nsrc = DUAL ? 2 : 1;
  for (int src = 0; src < nsrc; ++src) {
    const unsigned short* ysrc = src ? srcB : srcA;
    const unsigned short* wpk = src ? wpkB : wpkA;
    const bool ups = UPSB && (src == 1);

    const unsigned short* inptr[NIT];
#pragma unroll
    for (int it = 0; it < NIT; ++it) {
      int s = it * 64 + (t >> 2);
      int row = s >> LW;
      int col = s & (W - 1);
      int gy = refl(y0 - 1 + row, H);
      int sy, sx, sw;
      if (ups) { sy = gy >> 1; sx = col >> 1; sw = W >> 1; }
      else     { sy = gy;      sx = col;      sw = W; }
      int gsrc = (t & 3) ^ (col & 3);
      inptr[it] = ysrc + (((size_t)(b * sw + sy) * sw + sx) * CDIM + gsrc * 8);
    }
    const unsigned short* wsrc = wpk + ((size_t)(mb * 4 + wv) * 64 + l) * 8;

    for (int icc = 0; icc < 8; ++icc) {
      __syncthreads();
#pragma unroll
      for (int it = 0; it < NIT; ++it)
        gload_lds16(inptr[it] + icc * 32, &tin[(size_t)(it * 256 + t) * 8]);
#pragma unroll
      for (int tap = 0; tap < 9; ++tap)
        gload_lds16(wsrc + ((size_t)tap * 8 + (size_t)icc) * 8192,
                    &wlds[(size_t)(tap * 256 + t) * 8]);
      __syncthreads();

      __builtin_amdgcn_s_setprio(1);
#pragma unroll
      for (int tap = 0; tap < 9; ++tap) {
        const int dy = tap / 3, dx = tap - 3 * (tap / 3);
        bf16x8 af[4];
#pragma unroll
        for (int mi = 0; mi < 4; mi++)
          af[mi] = *(const bf16x8*)&wlds[(size_t)((tap * 4 + mi) * 64 + l) * 8];
#pragma unroll
        for (int nf = 0; nf < 4; nf++) {
          int pl = wv * 64 + nf * 16 + l15;
          int py = pl >> LW;
          int c = pl & (W - 1);
          int col = c + dx - 1;                       // reflect-pad in x
          col = col < 0 ? 1 : (col > W - 1 ? W - 2 : col);
          int idx16 = ((py + dy) * W + col) * 4 + (l4 ^ (col & 3));
          bf16x8 bfv = *(const bf16x8*)&tin[(size_t)idx16 * 8];
#pragma unroll
          for (int mi = 0; mi < 4; mi++)
            acc[mi][nf] = __builtin_amdgcn_mfma_f32_16x16x32_bf16(af[mi], bfv, acc[mi][nf], 0, 0, 0);
        }
      }
      __builtin_amdgcn_s_setprio(0);
    }
  }

  if (POOL) __syncthreads();   // all waves done reading tin before reuse as pool stage

  // epilogue
#pragma unroll
  for (int mi = 0; mi < 4; mi++) {
    int oc0 = mb * 64 + mi * 16 + l4 * 4;
    float bv[4];
#pragma unroll
    for (int rr = 0; rr < 4; rr++) bv[rr] = bias ? bias[oc0 + rr] : 0.f;
#pragma unroll
    for (int nf = 0; nf < 4; nf++) {
      int p = pixbase + wv * 64 + nf * 16 + l15;
      if (NCHWOUT) {
        float* o = (float*)outp;
        int pin = p & (HW - 1);
        int bb2 = p >> (2 * LW);
        int yy = pin >> LW, xx = pin & (W - 1);
        int ph = ((yy & 1) << 1) | (xx & 1);
        int q = (yy >> 1) * (W / 2) + (xx >> 1);
#pragma unroll
        for (int rr = 0; rr < 4; rr++) {
          float v = acc[mi][nf][rr] + bv[rr];
          if (ACC)
            v += bf2f(accsrc[((size_t)(bb2 * CDIM + oc0 + rr) * 4 + ph) * (HW / 4) + q]);
          o[((size_t)(bb2 * CDIM + oc0 + rr)) * HW + pin] = lrelu(v);
        }
      } else {
        unsigned short* o = (unsigned short*)outp;
        ushort4 pkv;
        pkv.x = f2bf(lrelu(acc[mi][nf][0] + bv[0]));
        pkv.y = f2bf(lrelu(acc[mi][nf][1] + bv[1]));
        pkv.z = f2bf(lrelu(acc[mi][nf][2] + bv[2]));
        pkv.w = f2bf(lrelu(acc[mi][nf][3] + bv[3]));
        *(ushort4*)&o[(size_t)p * CDIM + oc0] = pkv;
        if (POOL) {
          int pl = wv * 64 + nf * 16 + l15;
          int py = pl >> LW, col = pl & (W - 1);
          int ocl = mi * 16 + l4 * 4;
          *(ushort4*)&tin[(size_t)((py * W + col) * 64 + ocl)] = pkv;
        }
      }
    }
  }

  if (POOL) {
    __syncthreads();
    const int Y = y0 >> 1;
#pragma unroll
    for (int j = 0; j < 16; ++j) {
      int f = j * 256 + t;              // 0..4095
      int X = f >> 6, ocl = f & 63;
      float v = 0.25f * (bf2f(tin[((0 * W + 2 * X) * 64 + ocl)]) +
                         bf2f(tin[((0 * W + 2 * X + 1) * 64 + ocl)]) +
                         bf2f(tin[((1 * W + 2 * X) * 64 + ocl)]) +
                         bf2f(tin[((1 * W + 2 * X + 1) * 64 + ocl)]));
      pool_dst[((size_t)((b * 64 + Y) * 64 + X)) * CDIM + mb * 64 + ocl] = f2bf(v);
    }
  }
}

// ---------------- merged ada convs: lf [0,256) + hf(+fused pool) [256,1280) ----------------
__global__ __launch_bounds__(256, 2) void k_ada(
    const unsigned short* __restrict__ yh, const unsigned short* __restrict__ yl,
    const unsigned short* __restrict__ pk_adah, const unsigned short* __restrict__ pk_adal,
    const float* __restrict__ ada_h_b, const float* __restrict__ ada_l_b,
    unsigned short* __restrict__ hfA, unsigned short* __restrict__ lfA,
    unsigned short* __restrict__ hfP) {
  __shared__ __align__(16) unsigned short tin[16384];   // hf: 512 slots x 32ic (32 KB)
  __shared__ __align__(16) unsigned short wlds[18432];  // 9*4*64*8
  const int bid = blockIdx.x;
  if (bid < 256) {
    int wk = ((bid & 7) << 5) + (bid >> 3);             // nwg=256
    conv_body<6, false, false, false, false, false>(wk, tin, wlds, yl, nullptr, pk_adal,
                                                    nullptr, ada_l_b, nullptr, lfA, nullptr);
  } else {
    int h = bid - 256;
    int wk = ((h & 7) << 7) + (h >> 3);                 // nwg=1024
    conv_body<7, false, false, false, false, true>(wk, tin, wlds, yh, nullptr, pk_adah,
                                                   nullptr, ada_h_b, nullptr, hfA, hfP);
  }
}

// ---------------- merged output convs: lf-dual [0,256) + hf-ACC [256,1280) ----------------
__global__ __launch_bounds__(256, 2) void k_out(
    const unsigned short* __restrict__ hfA, const unsigned short* __restrict__ lfA,
    const unsigned short* __restrict__ hfP,
    const unsigned short* __restrict__ pk_h2h, const unsigned short* __restrict__ pk_l2l,
    const unsigned short* __restrict__ pk_h2l, const unsigned short* __restrict__ phb,
    float* __restrict__ out_hf, float* __restrict__ out_lf) {
  __shared__ __align__(16) unsigned short tin[16384];
  __shared__ __align__(16) unsigned short wlds[18432];
  const int bid = blockIdx.x;
  if (bid < 256) {
    int wk = ((bid & 7) << 5) + (bid >> 3);
    conv_body<6, true, false, true, false, false>(wk, tin, wlds, lfA, hfP, pk_l2l, pk_h2l,
                                                  nullptr, nullptr, out_lf, nullptr);
  } else {
    int h = bid - 256;
    int wk = ((h & 7) << 7) + (h >> 3);
    conv_body<7, false, false, true, true, false>(wk, tin, wlds, hfA, nullptr, pk_h2h,
                                                  nullptr, nullptr, phb, out_hf, nullptr);
  }
}

// ---------------- phase-collapsed upsample-conv: 4-tap GEMM on lf grid ----------------
__global__ __launch_bounds__(256, 3) void k_up(
    const unsigned short* __restrict__ lf, const unsigned short* __restrict__ wph,
    unsigned short* __restrict__ phb) {
  constexpr int NIT = 5;
  __shared__ __align__(16) unsigned short tin[10240];   // 320 slots x 32ic
  __shared__ __align__(16) unsigned short wlds[8192];   // 4 taps x 256 x 8

  const int t = threadIdx.x;
  const int l = t & 63, wv = t >> 6;
  const int l15 = l & 15, l4 = l >> 4;

  const int hwid = blockIdx.x;
  const int wk = ((hwid & 7) << 7) + (hwid >> 3);   // nwg = 1024
  const int mb = wk & 3;
  const int phase = (wk >> 2) & 3;
  const int tile = (wk >> 4) & 15;
  const int b = wk >> 8;
  const int a = phase >> 1, bp = phase & 1;
  const int Y0 = tile * 4;

  f32x4 acc[4][4];
#pragma unroll
  for (int mi = 0; mi < 4; mi++)
#pragma unroll
    for (int nf = 0; nf < 4; nf++) acc[mi][nf] = (f32x4){0.f, 0.f, 0.f, 0.f};

  const unsigned short* inptr[NIT];
#pragma unroll
  for (int it = 0; it < NIT; ++it) {
    int s = it * 64 + (t >> 2);
    int row = s >> 6, col = s & 63;
    int ly = Y0 - 1 + a + row;
    ly = ly < 0 ? 0 : (ly > 63 ? 63 : ly);
    int gsrc = (t & 3) ^ (col & 3);
    inptr[it] = lf + (((size_t)(b * 64 + ly) * 64 + col) * CDIM + gsrc * 8);
  }
  const unsigned short* wsrc = wph + ((size_t)(mb * 4 + wv) * 64 + l) * 8;

  for (int icc = 0; icc < 8; ++icc) {
    __syncthreads();
#pragma unroll
    for (int it = 0; it < NIT; ++it)
      gload_lds16(inptr[it] + icc * 32, &tin[(size_t)(it * 256 + t) * 8]);
#pragma unroll
    for (int tap = 0; tap < 4; ++tap)
      gload_lds16(wsrc + ((size_t)(phase * 4 + tap) * 8 + (size_t)icc) * 8192,
                  &wlds[(size_t)(tap * 256 + t) * 8]);
    __syncthreads();

    __builtin_amdgcn_s_setprio(1);
#pragma unroll
    for (int tap = 0; tap < 4; ++tap) {
      const int ty = tap >> 1, tx = tap & 1;
      bf16x8 af[4];
#pragma unroll
      for (int mi = 0; mi < 4; mi++)
        af[mi] = *(const bf16x8*)&wlds[(size_t)((tap * 4 + mi) * 64 + l) * 8];
#pragma unroll
      for (int nf = 0; nf < 4; nf++) {
        int pl = wv * 64 + nf * 16 + l15;
        int py = pl >> 6;
        int col = pl & 63;
        int tcol = col - 1 + bp + tx;
        tcol = tcol < 0 ? 0 : (tcol > 63 ? 63 : tcol);
        int idx16 = ((py + ty) * 64 + tcol) * 4 + (l4 ^ (tcol & 3));
        bf16x8 bfv = *(const bf16x8*)&tin[(size_t)idx16 * 8];
#pragma unroll
        for (int mi = 0; mi < 4; mi++)
          acc[mi][nf] = __builtin_amdgcn_mfma_f32_16x16x32_bf16(af[mi], bfv, acc[mi][nf], 0, 0, 0);
      }
    }
    __builtin_amdgcn_s_setprio(0);
  }

#pragma unroll
  for (int mi = 0; mi < 4; mi++) {
    int oc0 = mb * 64 + mi * 16 + l4 * 4;
#pragma unroll
    for (int nf = 0; nf < 4; nf++) {
      int pl = wv * 64 + nf * 16 + l15;
      int py = pl >> 6, col = pl & 63;
      size_t base = ((size_t)(b * CDIM + oc0) * 4 + phase) * 4096 + (Y0 + py) * 64 + col;
#pragma unroll
      for (int rr = 0; rr < 4; rr++)
        phb[base + (size_t)rr * 4 * 4096] = f2bf(acc[mi][nf][rr]);
    }
  }
}

// ---------------- host ----------------
extern "C" void kernel_launch(void* const* d_in, const int* in_sizes, int n_in,
                              void* d_out, int out_size, void* d_ws, size_t ws_size,
                              hipStream_t stream) {
  (void)in_sizes; (void)n_in; (void)out_size;
  const float* c_hf = (const float*)d_in[0];
  const float* c_lf = (const float*)d_in[1];
  const float* s_hf = (const float*)d_in[2];
  const float* s_lf = (const float*)d_in[3];
  const float* h_sw = (const float*)d_in[4];
  const float* h_sb = (const float*)d_in[5];
  const float* h_pw = (const float*)d_in[6];
  const float* h_pb = (const float*)d_in[7];
  const float* h_bw = (const float*)d_in[8];
  const float* h_bb = (const float*)d_in[9];
  const float* l_sw = (const float*)d_in[10];
  const float* l_sb = (const float*)d_in[11];
  const float* l_pw = (const float*)d_in[12];
  const float* l_pb = (const float*)d_in[13];
  const float* l_bw = (const float*)d_in[14];
  const float* l_bb = (const float*)d_in[15];
  const float* ada_h_w = (const float*)d_in[16];
  const float* ada_h_b = (const float*)d_in[17];
  const float* ada_l_w = (const float*)d_in[18];
  const float* ada_l_b = (const float*)d_in[19];
  const float* h2h = (const float*)d_in[20];
  const float* l2h = (const float*)d_in[21];
  const float* h2l = (const float*)d_in[22];
  const float* l2l = (const float*)d_in[23];

  float* base;
  size_t need = (size_t)TOTAL_F * sizeof(float);
  if (ws_size >= need) {
    base = (float*)d_ws;
  } else {
    void* p = nullptr;
    hipGetSymbolAddress(&p, HIP_SYMBOL(g_scratch));
    base = (float*)p;
  }

  float* ws_hf = base + OFF_WS_HF;
  float* ws_lf = base + OFF_WS_LF;
  float* wp_hf = base + OFF_WP_HF;
  float* bs_hf = base + OFF_BS_HF;
  float* wp_lf = base + OFF_WP_LF;
  float* bs_lf = base + OFF_BS_LF;
  float* mean_hf = base + OFF_MEAN_HF;
  float* rstd_hf = base + OFF_RSTD_HF;
  float* mean_lf = base + OFF_MEAN_LF;
  float* rstd_lf = base + OFF_RSTD_LF;
  unsigned short* u16 = (unsigned short*)(base + OFF_U16);
  unsigned short* yh = u16 + U_YH;
  unsigned short* yl = u16 + U_YL;
  unsigned short* hfA = u16 + U_HFA;
  unsigned short* lfA = u16 + U_LFA;
  unsigned short* hfP = u16 + U_HFP;
  unsigned short* pk      = u16 + U_PK;
  unsigned short* pk_adah = pk + 0 * PK_SZ;
  unsigned short* pk_h2h  = pk + 1 * PK_SZ;
  unsigned short* pk_adal = pk + 3 * PK_SZ;
  unsigned short* pk_l2l  = pk + 4 * PK_SZ;
  unsigned short* pk_h2l  = pk + 5 * PK_SZ;
  unsigned short* pk_ph   = u16 + U_PKPH;
  unsigned short* phb     = u16 + U_PHB;

  float* out_hf = (float*)d_out;
  float* out_lf = (float*)d_out + 16777216;

  // prep: all weight packing + ws + istats + point in one launch
  k_prep<<<dim3(28680), dim3(256), 0, stream>>>(
      ada_h_w, h2h, ada_l_w, l2l, h2l, l2h, pk, pk_ph,
      s_hf, h_sw, h_sb, ws_hf, s_lf, l_sw, l_sb, ws_lf,
      h_pw, h_pb, h_bw, h_bb, wp_hf, bs_hf,
      l_pw, l_pb, l_bw, l_bb, wp_lf, bs_lf,
      c_hf, mean_hf, rstd_hf, c_lf, mean_lf, rstd_lf);

  // fused IN + depthwise + pointwise -> NHWC bf16 (4 rows/block)
  k_dwt_all<<<dim3(1280), dim3(256), 0, stream>>>(
      c_hf, ws_hf, mean_hf, rstd_hf, wp_hf, bs_hf, yh,
      c_lf, ws_lf, mean_lf, rstd_lf, wp_lf, bs_lf, yl);

  // ada convs (lf + hf merged; hf fuses the 2x2 pool into its epilogue)
  k_ada<<<dim3(1280), dim3(256), 0, stream>>>(yh, yl, pk_adah, pk_adal, ada_h_b, ada_l_b,
                                              hfA, lfA, hfP);

  // phase-collapsed conv(up(lf), l2h) -> bf16 phase buffer
  k_up<<<dim3(1024), dim3(256), 0, stream>>>(lfA, pk_ph, phb);

  // output convs (lf-dual + hf-ACC merged)
  k_out<<<dim3(1280), dim3(256), 0, stream>>>(hfA, lfA, hfP, pk_h2h, pk_l2l, pk_h2l, phb,
                                              out_hf, out_lf);
}